// Round 7
// baseline (645.484 us; speedup 1.0000x reference)
//
#include <hip/hip_runtime.h>
#include <math.h>

#define NN 50000
#define EE 800000
#define BB 500
#define LL 42
#define NHEAD 10
#define FH 35
#define FG 350
#define ETOT (EE + NN)
#define NCHUNK ((NN + 511) / 512)

#define KPAD 384         // bf16 row stride for Z / xg1 / h2
#define MPAD 50048       // M padded to multiple of 128
#define MB2  512         // padded batch rows for FC MFMA

typedef unsigned short ushort_t;
typedef __attribute__((ext_vector_type(8))) short short8v;
typedef __attribute__((ext_vector_type(4))) float float4v;

__device__ __forceinline__ float lrelu(float x) { return x > 0.f ? x : 0.2f * x; }

__device__ __forceinline__ ushort_t f2bf(float f) {
    unsigned int u = __float_as_uint(f);
    u += 0x7fffu + ((u >> 16) & 1u);      // round-to-nearest-even
    return (ushort_t)(u >> 16);
}
__device__ __forceinline__ float bflo(unsigned u) { return __uint_as_float(u << 16); }
__device__ __forceinline__ float bfhi(unsigned u) { return __uint_as_float(u & 0xffff0000u); }

__device__ __forceinline__ void async_cp16(const void* g, void* l) {
    __builtin_amdgcn_global_load_lds((const __attribute__((address_space(1))) unsigned int*)g,
                                     (__attribute__((address_space(3))) unsigned int*)l, 16, 0, 0);
}

// ---------------- graph prep ----------------
__global__ __launch_bounds__(256) void k_init(int* deg, int* cur) {
    int i = blockIdx.x * 256 + threadIdx.x;
    if (i < NN) { deg[i] = 1; cur[i] = 0; }   // deg=1 accounts for the self-loop
}

__global__ __launch_bounds__(256) void k_deg(const int* __restrict__ ei, int* deg) {
    int i = blockIdx.x * 256 + threadIdx.x;
    if (i < EE) atomicAdd(&deg[ei[EE + i]], 1);
}

__global__ __launch_bounds__(512) void k_scan1(const int* __restrict__ deg, int* part) {
    int i = blockIdx.x * 512 + threadIdx.x;
    int lane = threadIdx.x & 63, wv = threadIdx.x >> 6;
    int x = (i < NN) ? deg[i] : 0;
    #pragma unroll
    for (int d = 32; d; d >>= 1) x += __shfl_xor(x, d);
    __shared__ int wsum[8];
    if (lane == 0) wsum[wv] = x;
    __syncthreads();
    if (threadIdx.x == 0) {
        int s = 0;
        #pragma unroll
        for (int w = 0; w < 8; w++) s += wsum[w];
        part[blockIdx.x] = s;
    }
}

__global__ __launch_bounds__(64) void k_scan2(const int* __restrict__ part, int* pscan) {
    int l = threadIdx.x;
    int v0 = (l < NCHUNK) ? part[l] : 0;
    #pragma unroll
    for (int d = 1; d < 64; d <<= 1) { int t = __shfl_up(v0, d); if (l >= d) v0 += t; }
    int tot0 = __shfl(v0, 63);
    int v1 = (64 + l < NCHUNK) ? part[64 + l] : 0;
    #pragma unroll
    for (int d = 1; d < 64; d <<= 1) { int t = __shfl_up(v1, d); if (l >= d) v1 += t; }
    v1 += tot0;
    if (l < NCHUNK) pscan[l] = v0;
    if (64 + l < NCHUNK) pscan[64 + l] = v1;
}

__global__ __launch_bounds__(512) void k_scan3(const int* __restrict__ deg, const int* __restrict__ pscan,
                                               int* offs) {
    int i = blockIdx.x * 512 + threadIdx.x;
    int lane = threadIdx.x & 63, wv = threadIdx.x >> 6;
    int x = (i < NN) ? deg[i] : 0;
    int incl = x;
    #pragma unroll
    for (int d = 1; d < 64; d <<= 1) { int t = __shfl_up(incl, d); if (lane >= d) incl += t; }
    __shared__ int wtot[8];
    if (lane == 63) wtot[wv] = incl;
    __syncthreads();
    int woff = 0;
    for (int w = 0; w < wv; w++) woff += wtot[w];
    int base = (blockIdx.x == 0) ? 0 : pscan[blockIdx.x - 1];
    if (i < NN) offs[i] = base + woff + incl - x;   // exclusive prefix
}

__global__ __launch_bounds__(256) void k_scatter(const int* __restrict__ ei, const int* __restrict__ offs,
                                                 int* cur, int* csr_src) {
    int i = blockIdx.x * 256 + threadIdx.x;
    if (i < EE) {
        int s = ei[i], d = ei[EE + i];
        int slot = atomicAdd(&cur[d], 1);
        csr_src[offs[d] + slot] = s;
    } else if (i < ETOT) {
        int v = i - EE;
        int slot = atomicAdd(&cur[v], 1);
        csr_src[offs[v] + slot] = v;
    }
}

__global__ __launch_bounds__(256) void k_dinv(const int* __restrict__ deg, float* dinv) {
    int i = blockIdx.x * 256 + threadIdx.x;
    if (i < NN) dinv[i] = rsqrtf((float)deg[i]);
}

// ---------------- prep kernels ----------------
// xf[n][40] f32: padded copy of x rows (gather target for GAT aggregate)
__global__ __launch_bounds__(256) void k_prep_xf(const float* __restrict__ x, float* __restrict__ xf) {
    int i = blockIdx.x * 256 + threadIdx.x;
    if (i >= NN * 40) return;
    int n = i / 40, c = i % 40;
    xf[i] = (c < 35) ? x[n * 35 + c] : 0.f;
}

// w~_s[hd,c] = sum_cc W_gat[c, hd*35+cc] * att_s[hd,cc]  (and same for d)
__global__ __launch_bounds__(256) void k_prep_att(const float* __restrict__ W_gat, const float* __restrict__ att_s,
                                                  const float* __restrict__ att_d,
                                                  float* __restrict__ wS, float* __restrict__ wD) {
    int i = blockIdx.x * 256 + threadIdx.x;
    if (i >= FG) return;
    int hd = i / 35, c = i % 35;
    float ss = 0.f, dd = 0.f;
    for (int cc = 0; cc < 35; cc++) {
        float w = W_gat[c * FG + hd * 35 + cc];
        ss += w * att_s[hd * 35 + cc];
        dd += w * att_d[hd * 35 + cc];
    }
    wS[i] = ss;
    wD[i] = dd;
}

// block-diagonal W_gat as n-major bf16 [384][384]: Wt[n][k] = (k/35==n/35) ? W_gat[k%35, n] : 0
__global__ __launch_bounds__(256) void k_prep_wbd(const float* __restrict__ W_gat, ushort_t* __restrict__ Wt) {
    int i = blockIdx.x * 256 + threadIdx.x;
    if (i >= KPAD * KPAD) return;
    int n = i / KPAD, k = i % KPAD;
    float v = 0.f;
    if (n < FG && k < FG && (k / 35) == (n / 35)) v = W_gat[(k % 35) * FG + n];
    Wt[i] = f2bf(v);
}

__global__ __launch_bounds__(256) void k_prep_wgcn(const float* __restrict__ W, ushort_t* __restrict__ Wt) {
    int i = blockIdx.x * 256 + threadIdx.x;
    if (i >= KPAD * KPAD) return;
    int n = i / KPAD, k = i % KPAD;
    float v = (n < FG && k < FG) ? W[k * FG + n] : 0.f;
    Wt[i] = f2bf(v);
}

// generic: Wt[n*KP+k] = bf16(W[k*N+n]), zero-padded
__global__ __launch_bounds__(256) void k_prep_w(const float* __restrict__ W, ushort_t* __restrict__ Wt,
                                                int K, int N, int KP, int NP) {
    int i = blockIdx.x * 256 + threadIdx.x;
    if (i >= KP * NP) return;
    int k = i / NP, n = i % NP;
    float v = (k < K && n < N) ? W[(size_t)k * N + n] : 0.f;
    Wt[(size_t)n * KP + k] = f2bf(v);
}

// generic: dst[r*KP+k] = bf16(src[r*K+k]), zero-padded
__global__ __launch_bounds__(256) void k_cast_pad(const float* __restrict__ src, ushort_t* __restrict__ dst,
                                                  int M, int K, int MP, int KP) {
    int i = blockIdx.x * 256 + threadIdx.x;
    if (i >= MP * KP) return;
    int r = i / KP, k = i % KP;
    dst[i] = (r < M && k < K) ? f2bf(src[(size_t)r * K + k]) : (ushort_t)0;
}

// ---------------- bf16 MFMA GEMM: C = act(A[Mp,lda] @ Bt[Np,lda] + bias) ----------------
// tile 128x64, BK=64, 4 waves 2x2. bdiag=1: K-window limited to heads overlapping this col-tile.
__global__ __launch_bounds__(256) void k_mfma(const ushort_t* __restrict__ A, const ushort_t* __restrict__ Bt,
                                              void* __restrict__ C, int M, int Nv, int ldc, int lda,
                                              int ksteps, const float* __restrict__ bias, int act, int bf16out,
                                              int bdiag) {
    __shared__ ushort_t As[128 * 64];
    __shared__ ushort_t Bs[64 * 64];
    int tid = threadIdx.x;
    int wid = tid >> 6, lane = tid & 63;
    int m0 = blockIdx.y * 128, n0 = blockIdx.x * 64;
    int wm0 = (wid >> 1) * 64, wn0 = (wid & 1) * 32;
    int srow = tid >> 3;              // staging: 8 lanes x 16B per row(128B)
    int scol = (tid & 7) * 8;
    float4v acc[4][2] = {{{0.f,0.f,0.f,0.f},{0.f,0.f,0.f,0.f}},
                         {{0.f,0.f,0.f,0.f},{0.f,0.f,0.f,0.f}},
                         {{0.f,0.f,0.f,0.f},{0.f,0.f,0.f,0.f}},
                         {{0.f,0.f,0.f,0.f},{0.f,0.f,0.f,0.f}}};
    int a_off = (wm0 + (lane & 15)) * 64 + (lane >> 4) * 8;
    int b_off = (wn0 + (lane & 15)) * 64 + (lane >> 4) * 8;
    int ks0 = 0, ks1 = ksteps;
    if (bdiag) {
        int hlo = n0 / 35;
        int hhi = (n0 + 63) / 35; if (hhi > 9) hhi = 9;
        ks0 = (hlo * 35) >> 6;
        ks1 = ((hhi + 1) * 35 + 63) >> 6;
    }
    for (int ks = ks0; ks < ks1; ks++) {
        int k0 = ks * 64;
        #pragma unroll
        for (int r = 0; r < 4; r++) {
            const ushort_t* g = A + (size_t)(m0 + r * 32 + srow) * lda + k0 + scol;
            async_cp16(g, As + (r * 256 + tid) * 8);
        }
        #pragma unroll
        for (int r = 0; r < 2; r++) {
            const ushort_t* g = Bt + (size_t)(n0 + r * 32 + srow) * lda + k0 + scol;
            async_cp16(g, Bs + (r * 256 + tid) * 8);
        }
        __syncthreads();
        #pragma unroll
        for (int kh = 0; kh < 2; kh++) {
            short8v b0 = *(const short8v*)&Bs[b_off + kh * 32];
            short8v b1 = *(const short8v*)&Bs[b_off + 16 * 64 + kh * 32];
            #pragma unroll
            for (int mi = 0; mi < 4; mi++) {
                short8v a = *(const short8v*)&As[a_off + mi * 16 * 64 + kh * 32];
                acc[mi][0] = __builtin_amdgcn_mfma_f32_16x16x32_bf16(a, b0, acc[mi][0], 0, 0, 0);
                acc[mi][1] = __builtin_amdgcn_mfma_f32_16x16x32_bf16(a, b1, acc[mi][1], 0, 0, 0);
            }
        }
        __syncthreads();
    }
    int lm = m0 + wm0 + (lane >> 4) * 4;
    int lc = n0 + wn0 + (lane & 15);
    #pragma unroll
    for (int mi = 0; mi < 4; mi++) {
        #pragma unroll
        for (int ni = 0; ni < 2; ni++) {
            int col = lc + ni * 16;
            float bv = (bias != nullptr && col < Nv) ? bias[col] : 0.f;
            #pragma unroll
            for (int r = 0; r < 4; r++) {
                int row = lm + mi * 16 + r;
                if (row >= M) continue;
                float v = acc[mi][ni][r] + bv;
                if (act) v = fmaxf(v, 0.f);
                if (col >= Nv) v = 0.f;
                if (bf16out) ((ushort_t*)C)[(size_t)row * ldc + col] = f2bf(v);
                else         ((float*)C)[(size_t)row * ldc + col] = v;
            }
        }
    }
}

// ---------------- GAT attention logits from x directly: a = x @ w~ ----------------
__global__ __launch_bounds__(256) void k_att2(const float* __restrict__ x, const float* __restrict__ wS,
                                              const float* __restrict__ wD, float* __restrict__ a_s,
                                              float* __restrict__ a_d) {
    int tid = blockIdx.x * 256 + threadIdx.x;
    if (tid >= NN * NHEAD) return;
    int n = tid / NHEAD, hd = tid % NHEAD;
    const float* xr = x + (size_t)n * 35;
    const float* ws = wS + hd * 35;
    const float* wd = wD + hd * 35;
    float as = 0.f, ad = 0.f;
    #pragma unroll
    for (int c = 0; c < 35; c++) { float v = xr[c]; as += v * ws[c]; ad += v * wd[c]; }
    a_s[tid] = as;
    a_d[tid] = ad;
}

// ---------------- GAT aggregate on x: Z[dst, hd*35+c] = sum_e alpha_e,hd * x[src_e, c] ----------------
// wave per node; lane owns features f = lane + 64j (j=0..5); gathers 160B x-rows (not 768B h-rows)
__global__ __launch_bounds__(256) void k_gat_agg(const float* __restrict__ xf, const float* __restrict__ a_s,
                                                 const float* __restrict__ a_d,
                                                 const int* __restrict__ csr_src,
                                                 const int* __restrict__ offs, const int* __restrict__ deg,
                                                 ushort_t* __restrict__ Zb, float* __restrict__ denArr) {
    int wid = (blockIdx.x * blockDim.x + threadIdx.x) >> 6;
    int lane = threadIdx.x & 63;
    if (wid >= NN) return;
    int o0 = offs[wid], d = deg[wid];
    bool mine = (lane < NHEAD);
    float adv = mine ? a_d[wid * NHEAD + lane] : 0.f;
    int f0 = lane, f1 = lane + 64, f2 = lane + 128, f3 = lane + 192, f4 = lane + 256, f5 = lane + 320;
    int h0 = f0 / 35, h1 = f1 / 35, h2 = f2 / 35, h3 = f3 / 35, h4 = f4 / 35;
    int h5 = (f5 < FG) ? f5 / 35 : 0;
    int c0 = f0 % 35, c1 = f1 % 35, c2 = f2 % 35, c3 = f3 % 35, c4 = f4 % 35;
    int c5 = (f5 < FG) ? f5 % 35 : 0;
    float den = 0.f;
    float ac0 = 0.f, ac1 = 0.f, ac2 = 0.f, ac3 = 0.f, ac4 = 0.f, ac5 = 0.f;
    int i = 0;
    for (; i + 2 <= d; i += 2) {
        int s0 = csr_src[o0 + i], s1 = csr_src[o0 + i + 1];
        const float* x0 = xf + (size_t)s0 * 40;
        const float* x1 = xf + (size_t)s1 * 40;
        float as0 = mine ? a_s[s0 * NHEAD + lane] : 0.f;
        float as1 = mine ? a_s[s1 * NHEAD + lane] : 0.f;
        float ex0 = __expf(lrelu(as0 + adv));
        float ex1 = __expf(lrelu(as1 + adv));
        den += ex0 + ex1;
        ac0 += __shfl(ex0, h0) * x0[c0] + __shfl(ex1, h0) * x1[c0];
        ac1 += __shfl(ex0, h1) * x0[c1] + __shfl(ex1, h1) * x1[c1];
        ac2 += __shfl(ex0, h2) * x0[c2] + __shfl(ex1, h2) * x1[c2];
        ac3 += __shfl(ex0, h3) * x0[c3] + __shfl(ex1, h3) * x1[c3];
        ac4 += __shfl(ex0, h4) * x0[c4] + __shfl(ex1, h4) * x1[c4];
        ac5 += __shfl(ex0, h5) * x0[c5] + __shfl(ex1, h5) * x1[c5];
    }
    for (; i < d; i++) {
        int s = csr_src[o0 + i];
        const float* xr = xf + (size_t)s * 40;
        float asv = mine ? a_s[s * NHEAD + lane] : 0.f;
        float ex = __expf(lrelu(asv + adv));
        den += ex;
        ac0 += __shfl(ex, h0) * xr[c0];
        ac1 += __shfl(ex, h1) * xr[c1];
        ac2 += __shfl(ex, h2) * xr[c2];
        ac3 += __shfl(ex, h3) * xr[c3];
        ac4 += __shfl(ex, h4) * xr[c4];
        ac5 += __shfl(ex, h5) * xr[c5];
    }
    float rden = 1.f / (den + 1e-16f);
    if (mine) denArr[wid * NHEAD + lane] = den;
    ushort_t* zr = Zb + (size_t)wid * KPAD;
    zr[f0] = f2bf(ac0 * __shfl(rden, h0));
    zr[f1] = f2bf(ac1 * __shfl(rden, h1));
    zr[f2] = f2bf(ac2 * __shfl(rden, h2));
    zr[f3] = f2bf(ac3 * __shfl(rden, h3));
    zr[f4] = f2bf(ac4 * __shfl(rden, h4));
    zr[f5] = (f5 < FG) ? f2bf(ac5 * __shfl(rden, h5)) : (ushort_t)0;
}

// ---------------- alpha in original edge order (coalesced writes; inputs L2-resident) ----------------
__global__ __launch_bounds__(256) void k_alpha(const int* __restrict__ ei, const float* __restrict__ a_s,
                                               const float* __restrict__ a_d, const float* __restrict__ den,
                                               float* __restrict__ alphaOut) {
    int i = blockIdx.x * 256 + threadIdx.x;
    if (i >= ETOT * NHEAD) return;
    int e = i / NHEAD, hd = i % NHEAD;
    int s, dst;
    if (e < EE) { s = ei[e]; dst = ei[EE + e]; }
    else { s = dst = e - EE; }
    float ex = __expf(lrelu(a_s[s * NHEAD + hd] + a_d[dst * NHEAD + hd]));
    alphaOut[i] = ex / (den[dst * NHEAD + hd] + 1e-16f);
}

// ---------------- GCN aggregate: wave per node (bf16 h2 gathers), unrolled x2 ----------------
__global__ __launch_bounds__(256) void k_gcn_agg(const ushort_t* __restrict__ h2b,
                                                 const int* __restrict__ csr_src,
                                                 const int* __restrict__ offs, const int* __restrict__ deg,
                                                 const float* __restrict__ dinv, const float* __restrict__ b_gcn,
                                                 float* __restrict__ xg2) {
    int wid = (blockIdx.x * blockDim.x + threadIdx.x) >> 6;
    int lane = threadIdx.x & 63;
    if (wid >= NN) return;
    int o0 = offs[wid], d = deg[wid];
    float wv = dinv[wid];
    float aL0 = 0.f, aH0 = 0.f, aL1 = 0.f, aH1 = 0.f, aL2 = 0.f, aH2 = 0.f;
    const unsigned* h32 = (const unsigned*)h2b;
    int i = 0;
    for (; i + 2 <= d; i += 2) {
        int s0 = csr_src[o0 + i], s1 = csr_src[o0 + i + 1];
        float w0 = dinv[s0], w1 = dinv[s1];
        const unsigned* h0 = h32 + (size_t)s0 * (KPAD / 2);
        const unsigned* h1 = h32 + (size_t)s1 * (KPAD / 2);
        unsigned u00 = h0[lane], u01 = h0[lane + 64], u02 = h0[lane + 128];
        unsigned u10 = h1[lane], u11 = h1[lane + 64], u12 = h1[lane + 128];
        aL0 += w0 * bflo(u00) + w1 * bflo(u10);
        aH0 += w0 * bfhi(u00) + w1 * bfhi(u10);
        aL1 += w0 * bflo(u01) + w1 * bflo(u11);
        aH1 += w0 * bfhi(u01) + w1 * bfhi(u11);
        aL2 += w0 * bflo(u02) + w1 * bflo(u12);
        aH2 += w0 * bfhi(u02) + w1 * bfhi(u12);
    }
    for (; i < d; i++) {
        int s = csr_src[o0 + i];
        float ws = dinv[s];
        const unsigned* hr = h32 + (size_t)s * (KPAD / 2);
        unsigned u0 = hr[lane], u1 = hr[lane + 64], u2 = hr[lane + 128];
        aL0 += ws * bflo(u0);  aH0 += ws * bfhi(u0);
        aL1 += ws * bflo(u1);  aH1 += ws * bfhi(u1);
        aL2 += ws * bflo(u2);  aH2 += ws * bfhi(u2);
    }
    float* orow = xg2 + (size_t)wid * FG;
    {
        int f = 2 * lane;
        float2 v = { fmaxf(wv * aL0 + b_gcn[f], 0.f), fmaxf(wv * aH0 + b_gcn[f + 1], 0.f) };
        *(float2*)&orow[f] = v;
    }
    {
        int f = 128 + 2 * lane;
        float2 v = { fmaxf(wv * aL1 + b_gcn[f], 0.f), fmaxf(wv * aH1 + b_gcn[f + 1], 0.f) };
        *(float2*)&orow[f] = v;
    }
    {
        int f = 256 + 2 * lane;
        if (f < FG) {
            float2 v = { fmaxf(wv * aL2 + b_gcn[f], 0.f), fmaxf(wv * aH2 + b_gcn[f + 1], 0.f) };
            *(float2*)&orow[f] = v;
        }
    }
}

// ---------------- per-graph max+mean pool ----------------
__device__ __forceinline__ int lowerB(const int* a, int n, int key) {
    int lo = 0, hi = n;
    while (lo < hi) { int mid = (lo + hi) >> 1; if (a[mid] < key) lo = mid + 1; else hi = mid; }
    return lo;
}

__global__ __launch_bounds__(384) void k_pool(const float* __restrict__ xg2, const int* __restrict__ batch,
                                              float* __restrict__ pooled) {
    int g = blockIdx.x;
    int f = threadIdx.x;
    int s = lowerB(batch, NN, g);
    int e = lowerB(batch, NN, g + 1);
    if (f >= FG) return;
    float mx = -INFINITY, sm = 0.f;
    int n = s;
    for (; n + 4 <= e; n += 4) {
        float v0 = xg2[(size_t)(n + 0) * FG + f];
        float v1 = xg2[(size_t)(n + 1) * FG + f];
        float v2 = xg2[(size_t)(n + 2) * FG + f];
        float v3 = xg2[(size_t)(n + 3) * FG + f];
        mx = fmaxf(fmaxf(mx, v0), fmaxf(fmaxf(v1, v2), v3));
        sm += v0 + v1 + v2 + v3;
    }
    for (; n < e; n++) {
        float v = xg2[(size_t)n * FG + f];
        mx = fmaxf(mx, v);
        sm += v;
    }
    int cnt = e - s;
    pooled[g * 700 + f] = mx;
    pooled[g * 700 + FG + f] = sm / fmaxf((float)cnt, 1.f);
}

// ---------------- protein conv branch: LDS-resident, 2 proteins per block ----------------
__global__ __launch_bounds__(256) void k_conv(const int* __restrict__ target, const float* __restrict__ emb,
                                              const float* __restrict__ Wc, const float* __restrict__ bc,
                                              float* __restrict__ xt) {
    __shared__ float embL[26 * 132];        // rows padded to 132 floats
    __shared__ float WL[16 * 8 * 128];      // WL[f][k][e] = Wc[f][e][k]
    __shared__ int   tgL[2 * LL];
    int tid = threadIdx.x;
    int b0 = blockIdx.x * 2;
    for (int i = tid; i < 26 * 128; i += 256) {
        int r = i >> 7, e = i & 127;
        embL[r * 132 + e] = emb[i];
    }
    for (int i = tid; i < 16384; i += 256) {
        int f = i >> 10, rem = i & 1023, k = rem >> 7, e = rem & 127;
        WL[i] = Wc[f * 1024 + e * 8 + k];
    }
    if (tid < 2 * LL) tgL[tid] = target[b0 * LL + tid];
    __syncthreads();
    #pragma unroll
    for (int pass = 0; pass < 2; pass++) {
        int r = tid + pass * 256;
        if (r >= 280) break;
        int bl = r / 140, rem = r % 140;
        int fq = rem / 35, t = rem % 35;
        const int* tg = &tgL[bl * LL];
        float ac0 = 0.f, ac1 = 0.f, ac2 = 0.f, ac3 = 0.f;
        for (int k = 0; k < 8; k++) {
            const float* er = &embL[tg[t + k] * 132];
            const float* w0 = &WL[((fq * 4 + 0) * 8 + k) * 128];
            const float* w1 = &WL[((fq * 4 + 1) * 8 + k) * 128];
            const float* w2 = &WL[((fq * 4 + 2) * 8 + k) * 128];
            const float* w3 = &WL[((fq * 4 + 3) * 8 + k) * 128];
            #pragma unroll 8
            for (int e = 0; e < 128; e += 4) {
                float4 a = *(const float4*)&er[e];
                float4 q0 = *(const float4*)&w0[e];
                float4 q1 = *(const float4*)&w1[e];
                float4 q2 = *(const float4*)&w2[e];
                float4 q3 = *(const float4*)&w3[e];
                ac0 += a.x * q0.x + a.y * q0.y + a.z * q0.z + a.w * q0.w;
                ac1 += a.x * q1.x + a.y * q1.y + a.z * q1.z + a.w * q1.w;
                ac2 += a.x * q2.x + a.y * q2.y + a.z * q2.z + a.w * q2.w;
                ac3 += a.x * q3.x + a.y * q3.y + a.z * q3.z + a.w * q3.w;
            }
        }
        int b = b0 + bl, fb = fq * 4;
        xt[b * 560 + (fb + 0) * 35 + t] = ac0 + bc[fb + 0];
        xt[b * 560 + (fb + 1) * 35 + t] = ac1 + bc[fb + 1];
        xt[b * 560 + (fb + 2) * 35 + t] = ac2 + bc[fb + 2];
        xt[b * 560 + (fb + 3) * 35 + t] = ac3 + bc[fb + 3];
    }
}

// ---------------- final dot + sigmoid ----------------
__global__ __launch_bounds__(256) void k_out(const float* __restrict__ f1, const float* __restrict__ W_out,
                                             const float* __restrict__ b_out, float* __restrict__ out) {
    int wid = (blockIdx.x * blockDim.x + threadIdx.x) >> 6;
    int lane = threadIdx.x & 63;
    if (wid >= BB) return;
    const float* xr = f1 + (size_t)wid * 512;
    float acc = 0.f;
    #pragma unroll
    for (int k = 0; k < 8; k++) acc += xr[lane + k * 64] * W_out[lane + k * 64];
    #pragma unroll
    for (int d = 32; d; d >>= 1) acc += __shfl_xor(acc, d);
    if (lane == 0) out[wid] = 1.f / (1.f + __expf(-(acc + b_out[0])));
}

// ---------------- host launcher ----------------
extern "C" void kernel_launch(void* const* d_in, const int* in_sizes, int n_in,
                              void* d_out, int out_size, void* d_ws, size_t ws_size,
                              hipStream_t stream) {
    const float* x      = (const float*)d_in[0];
    const int*   ei     = (const int*)d_in[1];
    const int*   batch  = (const int*)d_in[2];
    const int*   target = (const int*)d_in[3];
    const float* W_gat  = (const float*)d_in[4];
    const float* att_s  = (const float*)d_in[5];
    const float* att_d  = (const float*)d_in[6];
    const float* b_gat  = (const float*)d_in[7];
    const float* W_gcn  = (const float*)d_in[8];
    const float* b_gcn  = (const float*)d_in[9];
    const float* W_fcg1 = (const float*)d_in[10];
    const float* b_fcg1 = (const float*)d_in[11];
    const float* W_fcg2 = (const float*)d_in[12];
    const float* b_fcg2 = (const float*)d_in[13];
    const float* embxt  = (const float*)d_in[14];
    const float* W_conv = (const float*)d_in[15];
    const float* b_conv = (const float*)d_in[16];
    const float* W_fcxt = (const float*)d_in[17];
    const float* b_fcxt = (const float*)d_in[18];
    const float* W_fc1  = (const float*)d_in[19];
    const float* b_fc1  = (const float*)d_in[20];
    const float* W_out  = (const float*)d_in[21];
    const float* b_out  = (const float*)d_in[22];

    float* out_sig  = (float*)d_out;          // [500]
    float* alphaOut = (float*)d_out + BB;     // [850000 * 10]

    size_t o = 0;
    auto alloc = [&](size_t bytes) -> void* {
        o = (o + 255) & ~(size_t)255;
        void* p = (char*)d_ws + o;
        o += bytes;
        return p;
    };
    int*   deg     = (int*)alloc((size_t)NN * 4);
    int*   cur     = (int*)alloc((size_t)NN * 4);
    int*   offs    = (int*)alloc((size_t)NN * 4);
    int*   part    = (int*)alloc(128 * 4);
    int*   pscan   = (int*)alloc(128 * 4);
    int*   csr_src = (int*)alloc((size_t)ETOT * 4);
    float* dinv    = (float*)alloc((size_t)NN * 4);
    float* a_s     = (float*)alloc((size_t)NN * NHEAD * 4);
    float* a_d     = (float*)alloc((size_t)NN * NHEAD * 4);
    float* denArr  = (float*)alloc((size_t)NN * NHEAD * 4);
    float* xf      = (float*)alloc((size_t)NN * 40 * 4);          // padded f32 x rows (8 MB)
    float* wS      = (float*)alloc((size_t)FG * 4);
    float* wD      = (float*)alloc((size_t)FG * 4);
    ushort_t* WtBD = (ushort_t*)alloc((size_t)KPAD * KPAD * 2);   // block-diag W_gat^T
    ushort_t* WtGC = (ushort_t*)alloc((size_t)KPAD * KPAD * 2);
    ushort_t* WtF1 = (ushort_t*)alloc((size_t)1536 * 704 * 2);
    ushort_t* WtF2 = (ushort_t*)alloc((size_t)128 * 1536 * 2);
    ushort_t* WtFX = (ushort_t*)alloc((size_t)128 * 576 * 2);
    ushort_t* WtFC = (ushort_t*)alloc((size_t)512 * 256 * 2);
    float* pooled  = (float*)alloc((size_t)BB * 700 * 4);
    ushort_t* pooledb = (ushort_t*)alloc((size_t)MB2 * 704 * 2);
    ushort_t* t1b  = (ushort_t*)alloc((size_t)MB2 * 1536 * 2);
    float* xt      = (float*)alloc((size_t)BB * 560 * 4);
    ushort_t* xtb  = (ushort_t*)alloc((size_t)MB2 * 576 * 2);
    ushort_t* xcb  = (ushort_t*)alloc((size_t)MB2 * 256 * 2);
    float* f1      = (float*)alloc((size_t)MB2 * 512 * 4);
    ushort_t* hb   = (ushort_t*)alloc((size_t)MPAD * KPAD * 2);   // Z (GAT agg), later h2 (GCN GEMM out)
    char*  R2      = (char*)alloc((size_t)NN * FG * 4);           // 70 MB aliased region
    ushort_t* xg1b = (ushort_t*)R2;                               // [MPAD][KPAD] bf16 (38.4 MB)
    float* xg2     = (float*)R2;                                  // [NN][FG] f32, after xg1b dead
    (void)ws_size; (void)n_in; (void)in_sizes; (void)out_size;

    auto mfma = [&](const ushort_t* A, const ushort_t* Bt, void* C, const float* bias,
                    int M2, int Nv, int NP, int ldc, int KP, int act, int bf16out, int bdiag) {
        dim3 g(NP / 64, M2 / 128);
        k_mfma<<<g, 256, 0, stream>>>(A, Bt, C, M2, Nv, ldc, KP, KP / 64, bias, act, bf16out, bdiag);
    };

    // graph prep
    k_init<<<(NN + 255) / 256, 256, 0, stream>>>(deg, cur);
    k_deg<<<(EE + 255) / 256, 256, 0, stream>>>(ei, deg);
    k_scan1<<<NCHUNK, 512, 0, stream>>>(deg, part);
    k_scan2<<<1, 64, 0, stream>>>(part, pscan);
    k_scan3<<<NCHUNK, 512, 0, stream>>>(deg, pscan, offs);
    k_scatter<<<(ETOT + 255) / 256, 256, 0, stream>>>(ei, offs, cur, csr_src);
    k_dinv<<<(NN + 255) / 256, 256, 0, stream>>>(deg, dinv);

    // prep (x copy, fused attention weights, block-diag W_gat, W_gcn, FC weights)
    k_prep_xf<<<(NN * 40 + 255) / 256, 256, 0, stream>>>(x, xf);
    k_prep_att<<<2, 256, 0, stream>>>(W_gat, att_s, att_d, wS, wD);
    k_prep_wbd<<<(KPAD * KPAD + 255) / 256, 256, 0, stream>>>(W_gat, WtBD);
    k_prep_wgcn<<<(KPAD * KPAD + 255) / 256, 256, 0, stream>>>(W_gcn, WtGC);
    k_prep_w<<<(704 * 1536 + 255) / 256, 256, 0, stream>>>(W_fcg1, WtF1, 700, 1500, 704, 1536);
    k_prep_w<<<(1536 * 128 + 255) / 256, 256, 0, stream>>>(W_fcg2, WtF2, 1500, 128, 1536, 128);
    k_prep_w<<<(576 * 128 + 255) / 256, 256, 0, stream>>>(W_fcxt, WtFX, 560, 128, 576, 128);
    k_prep_w<<<(256 * 512 + 255) / 256, 256, 0, stream>>>(W_fc1, WtFC, 256, 512, 256, 512);

    // GAT: logits -> aggregate x -> alpha -> block-diag GEMM (applies W_gat after aggregation)
    k_att2<<<(NN * NHEAD + 255) / 256, 256, 0, stream>>>(x, wS, wD, a_s, a_d);
    k_gat_agg<<<(NN + 3) / 4, 256, 0, stream>>>(xf, a_s, a_d, csr_src, offs, deg, hb, denArr);   // Z -> hb
    k_alpha<<<(ETOT * NHEAD + 255) / 256, 256, 0, stream>>>(ei, a_s, a_d, denArr, alphaOut);
    mfma(hb, WtBD, xg1b, b_gat, MPAD, FG, KPAD, KPAD, KPAD, 1, 1, 1);        // xg1 = relu(Z@W_bd+b)

    // GCN: h2 = xg1 @ W_gcn (overwrites hb), then aggregate
    mfma(xg1b, WtGC, hb, nullptr, MPAD, KPAD, KPAD, KPAD, KPAD, 0, 1, 0);
    k_gcn_agg<<<(NN + 3) / 4, 256, 0, stream>>>(hb, csr_src, offs, deg, dinv, b_gcn, xg2);

    // pool + FC stacks (all FC layers via bf16 MFMA)
    k_pool<<<BB, 384, 0, stream>>>(xg2, batch, pooled);
    k_cast_pad<<<(MB2 * 704 + 255) / 256, 256, 0, stream>>>(pooled, pooledb, BB, 700, MB2, 704);
    mfma(pooledb, WtF1, t1b, b_fcg1, MB2, 1500, 1536, 1536, 704, 1, 1, 0);
    mfma(t1b, WtF2, xcb, b_fcg2, MB2, 128, 128, 256, 1536, 0, 1, 0);
    k_conv<<<250, 256, 0, stream>>>(target, embxt, W_conv, b_conv, xt);
    k_cast_pad<<<(MB2 * 576 + 255) / 256, 256, 0, stream>>>(xt, xtb, BB, 560, MB2, 576);
    mfma(xtb, WtFX, xcb + 128, b_fcxt, MB2, 128, 128, 256, 576, 0, 1, 0);
    mfma(xcb, WtFC, f1, b_fc1, MB2, 512, 512, 512, 256, 1, 0, 0);
    k_out<<<(BB + 3) / 4, 256, 0, stream>>>(f1, W_out, b_out, out_sig);
}

// Round 8
// 637.346 us; speedup vs baseline: 1.0128x; 1.0128x over previous
//
#include <hip/hip_runtime.h>
#include <math.h>

#define NN 50000
#define EE 800000
#define BB 500
#define LL 42
#define NHEAD 10
#define FH 35
#define FG 350
#define ETOT (EE + NN)
#define NCHUNK ((NN + 511) / 512)

#define KPAD 384         // bf16 row stride for Z / xg1 / h2
#define MPAD 50048       // M padded to multiple of 128
#define MB2  512         // padded batch rows for FC MFMA

typedef unsigned short ushort_t;
typedef __attribute__((ext_vector_type(8))) short short8v;
typedef __attribute__((ext_vector_type(4))) float float4v;

__device__ __forceinline__ float lrelu(float x) { return x > 0.f ? x : 0.2f * x; }

__device__ __forceinline__ ushort_t f2bf(float f) {
    unsigned int u = __float_as_uint(f);
    u += 0x7fffu + ((u >> 16) & 1u);      // round-to-nearest-even
    return (ushort_t)(u >> 16);
}
__device__ __forceinline__ float bflo(unsigned u) { return __uint_as_float(u << 16); }
__device__ __forceinline__ float bfhi(unsigned u) { return __uint_as_float(u & 0xffff0000u); }
__device__ __forceinline__ float bfu(ushort_t u) { return __uint_as_float(((unsigned)u) << 16); }

__device__ __forceinline__ void async_cp16(const void* g, void* l) {
    __builtin_amdgcn_global_load_lds((const __attribute__((address_space(1))) unsigned int*)g,
                                     (__attribute__((address_space(3))) unsigned int*)l, 16, 0, 0);
}

// ---------------- graph prep ----------------
__global__ __launch_bounds__(256) void k_init(int* deg, int* cur) {
    int i = blockIdx.x * 256 + threadIdx.x;
    if (i < NN) { deg[i] = 1; cur[i] = 0; }   // deg=1 accounts for the self-loop
}

__global__ __launch_bounds__(256) void k_deg(const int* __restrict__ ei, int* deg) {
    int i = blockIdx.x * 256 + threadIdx.x;
    if (i < EE) atomicAdd(&deg[ei[EE + i]], 1);
}

__global__ __launch_bounds__(512) void k_scan1(const int* __restrict__ deg, int* part) {
    int i = blockIdx.x * 512 + threadIdx.x;
    int lane = threadIdx.x & 63, wv = threadIdx.x >> 6;
    int x = (i < NN) ? deg[i] : 0;
    #pragma unroll
    for (int d = 32; d; d >>= 1) x += __shfl_xor(x, d);
    __shared__ int wsum[8];
    if (lane == 0) wsum[wv] = x;
    __syncthreads();
    if (threadIdx.x == 0) {
        int s = 0;
        #pragma unroll
        for (int w = 0; w < 8; w++) s += wsum[w];
        part[blockIdx.x] = s;
    }
}

__global__ __launch_bounds__(64) void k_scan2(const int* __restrict__ part, int* pscan) {
    int l = threadIdx.x;
    int v0 = (l < NCHUNK) ? part[l] : 0;
    #pragma unroll
    for (int d = 1; d < 64; d <<= 1) { int t = __shfl_up(v0, d); if (l >= d) v0 += t; }
    int tot0 = __shfl(v0, 63);
    int v1 = (64 + l < NCHUNK) ? part[64 + l] : 0;
    #pragma unroll
    for (int d = 1; d < 64; d <<= 1) { int t = __shfl_up(v1, d); if (l >= d) v1 += t; }
    v1 += tot0;
    if (l < NCHUNK) pscan[l] = v0;
    if (64 + l < NCHUNK) pscan[64 + l] = v1;
}

__global__ __launch_bounds__(512) void k_scan3(const int* __restrict__ deg, const int* __restrict__ pscan,
                                               int* offs) {
    int i = blockIdx.x * 512 + threadIdx.x;
    int lane = threadIdx.x & 63, wv = threadIdx.x >> 6;
    int x = (i < NN) ? deg[i] : 0;
    int incl = x;
    #pragma unroll
    for (int d = 1; d < 64; d <<= 1) { int t = __shfl_up(incl, d); if (lane >= d) incl += t; }
    __shared__ int wtot[8];
    if (lane == 63) wtot[wv] = incl;
    __syncthreads();
    int woff = 0;
    for (int w = 0; w < wv; w++) woff += wtot[w];
    int base = (blockIdx.x == 0) ? 0 : pscan[blockIdx.x - 1];
    if (i < NN) offs[i] = base + woff + incl - x;   // exclusive prefix
}

__global__ __launch_bounds__(256) void k_scatter(const int* __restrict__ ei, const int* __restrict__ offs,
                                                 int* cur, int* csr_src) {
    int i = blockIdx.x * 256 + threadIdx.x;
    if (i < EE) {
        int s = ei[i], d = ei[EE + i];
        int slot = atomicAdd(&cur[d], 1);
        csr_src[offs[d] + slot] = s;
    } else if (i < ETOT) {
        int v = i - EE;
        int slot = atomicAdd(&cur[v], 1);
        csr_src[offs[v] + slot] = v;
    }
}

__global__ __launch_bounds__(256) void k_dinv(const int* __restrict__ deg, float* dinv) {
    int i = blockIdx.x * 256 + threadIdx.x;
    if (i < NN) dinv[i] = rsqrtf((float)deg[i]);
}

// ---------------- prep kernels ----------------
// xfb[n][40] bf16: padded copy of x rows (gather target for GAT aggregate) — 4.0 MB, fits XCD L2
__global__ __launch_bounds__(256) void k_prep_xf(const float* __restrict__ x, ushort_t* __restrict__ xfb) {
    int i = blockIdx.x * 256 + threadIdx.x;
    if (i >= NN * 40) return;
    int n = i / 40, c = i % 40;
    xfb[i] = (c < 35) ? f2bf(x[n * 35 + c]) : (ushort_t)0;
}

// w~_s[hd,c] = sum_cc W_gat[c, hd*35+cc] * att_s[hd,cc]  (and same for d)
__global__ __launch_bounds__(256) void k_prep_att(const float* __restrict__ W_gat, const float* __restrict__ att_s,
                                                  const float* __restrict__ att_d,
                                                  float* __restrict__ wS, float* __restrict__ wD) {
    int i = blockIdx.x * 256 + threadIdx.x;
    if (i >= FG) return;
    int hd = i / 35, c = i % 35;
    float ss = 0.f, dd = 0.f;
    for (int cc = 0; cc < 35; cc++) {
        float w = W_gat[c * FG + hd * 35 + cc];
        ss += w * att_s[hd * 35 + cc];
        dd += w * att_d[hd * 35 + cc];
    }
    wS[i] = ss;
    wD[i] = dd;
}

// block-diagonal W_gat as n-major bf16 [384][384]: Wt[n][k] = (k/35==n/35) ? W_gat[k%35, n] : 0
__global__ __launch_bounds__(256) void k_prep_wbd(const float* __restrict__ W_gat, ushort_t* __restrict__ Wt) {
    int i = blockIdx.x * 256 + threadIdx.x;
    if (i >= KPAD * KPAD) return;
    int n = i / KPAD, k = i % KPAD;
    float v = 0.f;
    if (n < FG && k < FG && (k / 35) == (n / 35)) v = W_gat[(k % 35) * FG + n];
    Wt[i] = f2bf(v);
}

__global__ __launch_bounds__(256) void k_prep_wgcn(const float* __restrict__ W, ushort_t* __restrict__ Wt) {
    int i = blockIdx.x * 256 + threadIdx.x;
    if (i >= KPAD * KPAD) return;
    int n = i / KPAD, k = i % KPAD;
    float v = (n < FG && k < FG) ? W[k * FG + n] : 0.f;
    Wt[i] = f2bf(v);
}

// generic: Wt[n*KP+k] = bf16(W[k*N+n]), zero-padded
__global__ __launch_bounds__(256) void k_prep_w(const float* __restrict__ W, ushort_t* __restrict__ Wt,
                                                int K, int N, int KP, int NP) {
    int i = blockIdx.x * 256 + threadIdx.x;
    if (i >= KP * NP) return;
    int k = i / NP, n = i % NP;
    float v = (k < K && n < N) ? W[(size_t)k * N + n] : 0.f;
    Wt[(size_t)n * KP + k] = f2bf(v);
}

// generic: dst[r*KP+k] = bf16(src[r*K+k]), zero-padded
__global__ __launch_bounds__(256) void k_cast_pad(const float* __restrict__ src, ushort_t* __restrict__ dst,
                                                  int M, int K, int MP, int KP) {
    int i = blockIdx.x * 256 + threadIdx.x;
    if (i >= MP * KP) return;
    int r = i / KP, k = i % KP;
    dst[i] = (r < M && k < K) ? f2bf(src[(size_t)r * K + k]) : (ushort_t)0;
}

// ---------------- bf16 MFMA GEMM: C = act(A[Mp,lda] @ Bt[Np,lda] + bias) ----------------
// tile 128x64, BK=64, 4 waves 2x2. bdiag=1: K-window limited to heads overlapping this col-tile.
__global__ __launch_bounds__(256) void k_mfma(const ushort_t* __restrict__ A, const ushort_t* __restrict__ Bt,
                                              void* __restrict__ C, int M, int Nv, int ldc, int lda,
                                              int ksteps, const float* __restrict__ bias, int act, int bf16out,
                                              int bdiag) {
    __shared__ ushort_t As[128 * 64];
    __shared__ ushort_t Bs[64 * 64];
    int tid = threadIdx.x;
    int wid = tid >> 6, lane = tid & 63;
    int m0 = blockIdx.y * 128, n0 = blockIdx.x * 64;
    int wm0 = (wid >> 1) * 64, wn0 = (wid & 1) * 32;
    int srow = tid >> 3;              // staging: 8 lanes x 16B per row(128B)
    int scol = (tid & 7) * 8;
    float4v acc[4][2] = {{{0.f,0.f,0.f,0.f},{0.f,0.f,0.f,0.f}},
                         {{0.f,0.f,0.f,0.f},{0.f,0.f,0.f,0.f}},
                         {{0.f,0.f,0.f,0.f},{0.f,0.f,0.f,0.f}},
                         {{0.f,0.f,0.f,0.f},{0.f,0.f,0.f,0.f}}};
    int a_off = (wm0 + (lane & 15)) * 64 + (lane >> 4) * 8;
    int b_off = (wn0 + (lane & 15)) * 64 + (lane >> 4) * 8;
    int ks0 = 0, ks1 = ksteps;
    if (bdiag) {
        int hlo = n0 / 35;
        int hhi = (n0 + 63) / 35; if (hhi > 9) hhi = 9;
        ks0 = (hlo * 35) >> 6;
        ks1 = ((hhi + 1) * 35 + 63) >> 6;
    }
    for (int ks = ks0; ks < ks1; ks++) {
        int k0 = ks * 64;
        #pragma unroll
        for (int r = 0; r < 4; r++) {
            const ushort_t* g = A + (size_t)(m0 + r * 32 + srow) * lda + k0 + scol;
            async_cp16(g, As + (r * 256 + tid) * 8);
        }
        #pragma unroll
        for (int r = 0; r < 2; r++) {
            const ushort_t* g = Bt + (size_t)(n0 + r * 32 + srow) * lda + k0 + scol;
            async_cp16(g, Bs + (r * 256 + tid) * 8);
        }
        __syncthreads();
        #pragma unroll
        for (int kh = 0; kh < 2; kh++) {
            short8v b0 = *(const short8v*)&Bs[b_off + kh * 32];
            short8v b1 = *(const short8v*)&Bs[b_off + 16 * 64 + kh * 32];
            #pragma unroll
            for (int mi = 0; mi < 4; mi++) {
                short8v a = *(const short8v*)&As[a_off + mi * 16 * 64 + kh * 32];
                acc[mi][0] = __builtin_amdgcn_mfma_f32_16x16x32_bf16(a, b0, acc[mi][0], 0, 0, 0);
                acc[mi][1] = __builtin_amdgcn_mfma_f32_16x16x32_bf16(a, b1, acc[mi][1], 0, 0, 0);
            }
        }
        __syncthreads();
    }
    int lm = m0 + wm0 + (lane >> 4) * 4;
    int lc = n0 + wn0 + (lane & 15);
    #pragma unroll
    for (int mi = 0; mi < 4; mi++) {
        #pragma unroll
        for (int ni = 0; ni < 2; ni++) {
            int col = lc + ni * 16;
            float bv = (bias != nullptr && col < Nv) ? bias[col] : 0.f;
            #pragma unroll
            for (int r = 0; r < 4; r++) {
                int row = lm + mi * 16 + r;
                if (row >= M) continue;
                float v = acc[mi][ni][r] + bv;
                if (act) v = fmaxf(v, 0.f);
                if (col >= Nv) v = 0.f;
                if (bf16out) ((ushort_t*)C)[(size_t)row * ldc + col] = f2bf(v);
                else         ((float*)C)[(size_t)row * ldc + col] = v;
            }
        }
    }
}

// ---------------- GAT attention logits from x directly: a = x @ w~ ----------------
__global__ __launch_bounds__(256) void k_att2(const float* __restrict__ x, const float* __restrict__ wS,
                                              const float* __restrict__ wD, float* __restrict__ a_s,
                                              float* __restrict__ a_d) {
    int tid = blockIdx.x * 256 + threadIdx.x;
    if (tid >= NN * NHEAD) return;
    int n = tid / NHEAD, hd = tid % NHEAD;
    const float* xr = x + (size_t)n * 35;
    const float* ws = wS + hd * 35;
    const float* wd = wD + hd * 35;
    float as = 0.f, ad = 0.f;
    #pragma unroll
    for (int c = 0; c < 35; c++) { float v = xr[c]; as += v * ws[c]; ad += v * wd[c]; }
    a_s[tid] = as;
    a_d[tid] = ad;
}

// ---------------- GAT aggregate on x (bf16, L2-resident): Z[dst, hd*35+c] = sum_e alpha * x[src,c] ----------------
// wave per node; lane owns features f = lane + 64j; Z written with non-temporal stores (keep L2 for xfb)
__global__ __launch_bounds__(256) void k_gat_agg(const ushort_t* __restrict__ xfb, const float* __restrict__ a_s,
                                                 const float* __restrict__ a_d,
                                                 const int* __restrict__ csr_src,
                                                 const int* __restrict__ offs, const int* __restrict__ deg,
                                                 ushort_t* __restrict__ Zb, float* __restrict__ denArr) {
    int wid = (blockIdx.x * blockDim.x + threadIdx.x) >> 6;
    int lane = threadIdx.x & 63;
    if (wid >= NN) return;
    int o0 = offs[wid], d = deg[wid];
    bool mine = (lane < NHEAD);
    float adv = mine ? a_d[wid * NHEAD + lane] : 0.f;
    int f0 = lane, f1 = lane + 64, f2 = lane + 128, f3 = lane + 192, f4 = lane + 256, f5 = lane + 320;
    int h0 = f0 / 35, h1 = f1 / 35, h2 = f2 / 35, h3 = f3 / 35, h4 = f4 / 35;
    int h5 = (f5 < FG) ? f5 / 35 : 0;
    int c0 = f0 % 35, c1 = f1 % 35, c2 = f2 % 35, c3 = f3 % 35, c4 = f4 % 35;
    int c5 = (f5 < FG) ? f5 % 35 : 0;
    float den = 0.f;
    float ac0 = 0.f, ac1 = 0.f, ac2 = 0.f, ac3 = 0.f, ac4 = 0.f, ac5 = 0.f;
    int i = 0;
    for (; i + 2 <= d; i += 2) {
        int s0 = csr_src[o0 + i], s1 = csr_src[o0 + i + 1];
        const ushort_t* x0 = xfb + (size_t)s0 * 40;
        const ushort_t* x1 = xfb + (size_t)s1 * 40;
        float as0 = mine ? a_s[s0 * NHEAD + lane] : 0.f;
        float as1 = mine ? a_s[s1 * NHEAD + lane] : 0.f;
        ushort_t v00 = x0[c0], v01 = x0[c1], v02 = x0[c2], v03 = x0[c3], v04 = x0[c4], v05 = x0[c5];
        ushort_t v10 = x1[c0], v11 = x1[c1], v12 = x1[c2], v13 = x1[c3], v14 = x1[c4], v15 = x1[c5];
        float ex0 = __expf(lrelu(as0 + adv));
        float ex1 = __expf(lrelu(as1 + adv));
        den += ex0 + ex1;
        ac0 += __shfl(ex0, h0) * bfu(v00) + __shfl(ex1, h0) * bfu(v10);
        ac1 += __shfl(ex0, h1) * bfu(v01) + __shfl(ex1, h1) * bfu(v11);
        ac2 += __shfl(ex0, h2) * bfu(v02) + __shfl(ex1, h2) * bfu(v12);
        ac3 += __shfl(ex0, h3) * bfu(v03) + __shfl(ex1, h3) * bfu(v13);
        ac4 += __shfl(ex0, h4) * bfu(v04) + __shfl(ex1, h4) * bfu(v14);
        ac5 += __shfl(ex0, h5) * bfu(v05) + __shfl(ex1, h5) * bfu(v15);
    }
    for (; i < d; i++) {
        int s = csr_src[o0 + i];
        const ushort_t* xr = xfb + (size_t)s * 40;
        float asv = mine ? a_s[s * NHEAD + lane] : 0.f;
        float ex = __expf(lrelu(asv + adv));
        den += ex;
        ac0 += __shfl(ex, h0) * bfu(xr[c0]);
        ac1 += __shfl(ex, h1) * bfu(xr[c1]);
        ac2 += __shfl(ex, h2) * bfu(xr[c2]);
        ac3 += __shfl(ex, h3) * bfu(xr[c3]);
        ac4 += __shfl(ex, h4) * bfu(xr[c4]);
        ac5 += __shfl(ex, h5) * bfu(xr[c5]);
    }
    float rden = 1.f / (den + 1e-16f);
    if (mine) denArr[wid * NHEAD + lane] = den;
    ushort_t* zr = Zb + (size_t)wid * KPAD;
    __builtin_nontemporal_store(f2bf(ac0 * __shfl(rden, h0)), &zr[f0]);
    __builtin_nontemporal_store(f2bf(ac1 * __shfl(rden, h1)), &zr[f1]);
    __builtin_nontemporal_store(f2bf(ac2 * __shfl(rden, h2)), &zr[f2]);
    __builtin_nontemporal_store(f2bf(ac3 * __shfl(rden, h3)), &zr[f3]);
    __builtin_nontemporal_store(f2bf(ac4 * __shfl(rden, h4)), &zr[f4]);
    __builtin_nontemporal_store((f5 < FG) ? f2bf(ac5 * __shfl(rden, h5)) : (ushort_t)0, &zr[f5]);
}

// ---------------- alpha in original edge order (coalesced writes; inputs L2-resident) ----------------
__global__ __launch_bounds__(256) void k_alpha(const int* __restrict__ ei, const float* __restrict__ a_s,
                                               const float* __restrict__ a_d, const float* __restrict__ den,
                                               float* __restrict__ alphaOut) {
    int i = blockIdx.x * 256 + threadIdx.x;
    if (i >= ETOT * NHEAD) return;
    int e = i / NHEAD, hd = i % NHEAD;
    int s, dst;
    if (e < EE) { s = ei[e]; dst = ei[EE + e]; }
    else { s = dst = e - EE; }
    float ex = __expf(lrelu(a_s[s * NHEAD + hd] + a_d[dst * NHEAD + hd]));
    __builtin_nontemporal_store(ex / (den[dst * NHEAD + hd] + 1e-16f), &alphaOut[i]);
}

// ---------------- GCN aggregate: wave per node (bf16 h2 gathers), unrolled x2 ----------------
__global__ __launch_bounds__(256) void k_gcn_agg(const ushort_t* __restrict__ h2b,
                                                 const int* __restrict__ csr_src,
                                                 const int* __restrict__ offs, const int* __restrict__ deg,
                                                 const float* __restrict__ dinv, const float* __restrict__ b_gcn,
                                                 float* __restrict__ xg2) {
    int wid = (blockIdx.x * blockDim.x + threadIdx.x) >> 6;
    int lane = threadIdx.x & 63;
    if (wid >= NN) return;
    int o0 = offs[wid], d = deg[wid];
    float wv = dinv[wid];
    float aL0 = 0.f, aH0 = 0.f, aL1 = 0.f, aH1 = 0.f, aL2 = 0.f, aH2 = 0.f;
    const unsigned* h32 = (const unsigned*)h2b;
    int i = 0;
    for (; i + 2 <= d; i += 2) {
        int s0 = csr_src[o0 + i], s1 = csr_src[o0 + i + 1];
        float w0 = dinv[s0], w1 = dinv[s1];
        const unsigned* h0 = h32 + (size_t)s0 * (KPAD / 2);
        const unsigned* h1 = h32 + (size_t)s1 * (KPAD / 2);
        unsigned u00 = h0[lane], u01 = h0[lane + 64], u02 = h0[lane + 128];
        unsigned u10 = h1[lane], u11 = h1[lane + 64], u12 = h1[lane + 128];
        aL0 += w0 * bflo(u00) + w1 * bflo(u10);
        aH0 += w0 * bfhi(u00) + w1 * bfhi(u10);
        aL1 += w0 * bflo(u01) + w1 * bflo(u11);
        aH1 += w0 * bfhi(u01) + w1 * bfhi(u11);
        aL2 += w0 * bflo(u02) + w1 * bflo(u12);
        aH2 += w0 * bfhi(u02) + w1 * bfhi(u12);
    }
    for (; i < d; i++) {
        int s = csr_src[o0 + i];
        float ws = dinv[s];
        const unsigned* hr = h32 + (size_t)s * (KPAD / 2);
        unsigned u0 = hr[lane], u1 = hr[lane + 64], u2 = hr[lane + 128];
        aL0 += ws * bflo(u0);  aH0 += ws * bfhi(u0);
        aL1 += ws * bflo(u1);  aH1 += ws * bfhi(u1);
        aL2 += ws * bflo(u2);  aH2 += ws * bfhi(u2);
    }
    float* orow = xg2 + (size_t)wid * FG;
    {
        int f = 2 * lane;
        __builtin_nontemporal_store(fmaxf(wv * aL0 + b_gcn[f], 0.f), &orow[f]);
        __builtin_nontemporal_store(fmaxf(wv * aH0 + b_gcn[f + 1], 0.f), &orow[f + 1]);
    }
    {
        int f = 128 + 2 * lane;
        __builtin_nontemporal_store(fmaxf(wv * aL1 + b_gcn[f], 0.f), &orow[f]);
        __builtin_nontemporal_store(fmaxf(wv * aH1 + b_gcn[f + 1], 0.f), &orow[f + 1]);
    }
    {
        int f = 256 + 2 * lane;
        if (f < FG) {
            __builtin_nontemporal_store(fmaxf(wv * aL2 + b_gcn[f], 0.f), &orow[f]);
            __builtin_nontemporal_store(fmaxf(wv * aH2 + b_gcn[f + 1], 0.f), &orow[f + 1]);
        }
    }
}

// ---------------- per-graph max+mean pool ----------------
__device__ __forceinline__ int lowerB(const int* a, int n, int key) {
    int lo = 0, hi = n;
    while (lo < hi) { int mid = (lo + hi) >> 1; if (a[mid] < key) lo = mid + 1; else hi = mid; }
    return lo;
}

__global__ __launch_bounds__(384) void k_pool(const float* __restrict__ xg2, const int* __restrict__ batch,
                                              float* __restrict__ pooled) {
    int g = blockIdx.x;
    int f = threadIdx.x;
    int s = lowerB(batch, NN, g);
    int e = lowerB(batch, NN, g + 1);
    if (f >= FG) return;
    float mx = -INFINITY, sm = 0.f;
    int n = s;
    for (; n + 4 <= e; n += 4) {
        float v0 = xg2[(size_t)(n + 0) * FG + f];
        float v1 = xg2[(size_t)(n + 1) * FG + f];
        float v2 = xg2[(size_t)(n + 2) * FG + f];
        float v3 = xg2[(size_t)(n + 3) * FG + f];
        mx = fmaxf(fmaxf(mx, v0), fmaxf(fmaxf(v1, v2), v3));
        sm += v0 + v1 + v2 + v3;
    }
    for (; n < e; n++) {
        float v = xg2[(size_t)n * FG + f];
        mx = fmaxf(mx, v);
        sm += v;
    }
    int cnt = e - s;
    pooled[g * 700 + f] = mx;
    pooled[g * 700 + FG + f] = sm / fmaxf((float)cnt, 1.f);
}

// ---------------- protein conv branch: LDS-resident, 2 proteins per block ----------------
__global__ __launch_bounds__(256) void k_conv(const int* __restrict__ target, const float* __restrict__ emb,
                                              const float* __restrict__ Wc, const float* __restrict__ bc,
                                              float* __restrict__ xt) {
    __shared__ float embL[26 * 132];        // rows padded to 132 floats
    __shared__ float WL[16 * 8 * 128];      // WL[f][k][e] = Wc[f][e][k]
    __shared__ int   tgL[2 * LL];
    int tid = threadIdx.x;
    int b0 = blockIdx.x * 2;
    for (int i = tid; i < 26 * 128; i += 256) {
        int r = i >> 7, e = i & 127;
        embL[r * 132 + e] = emb[i];
    }
    for (int i = tid; i < 16384; i += 256) {
        int f = i >> 10, rem = i & 1023, k = rem >> 7, e = rem & 127;
        WL[i] = Wc[f * 1024 + e * 8 + k];
    }
    if (tid < 2 * LL) tgL[tid] = target[b0 * LL + tid];
    __syncthreads();
    #pragma unroll
    for (int pass = 0; pass < 2; pass++) {
        int r = tid + pass * 256;
        if (r >= 280) break;
        int bl = r / 140, rem = r % 140;
        int fq = rem / 35, t = rem % 35;
        const int* tg = &tgL[bl * LL];
        float ac0 = 0.f, ac1 = 0.f, ac2 = 0.f, ac3 = 0.f;
        for (int k = 0; k < 8; k++) {
            const float* er = &embL[tg[t + k] * 132];
            const float* w0 = &WL[((fq * 4 + 0) * 8 + k) * 128];
            const float* w1 = &WL[((fq * 4 + 1) * 8 + k) * 128];
            const float* w2 = &WL[((fq * 4 + 2) * 8 + k) * 128];
            const float* w3 = &WL[((fq * 4 + 3) * 8 + k) * 128];
            #pragma unroll 8
            for (int e = 0; e < 128; e += 4) {
                float4 a = *(const float4*)&er[e];
                float4 q0 = *(const float4*)&w0[e];
                float4 q1 = *(const float4*)&w1[e];
                float4 q2 = *(const float4*)&w2[e];
                float4 q3 = *(const float4*)&w3[e];
                ac0 += a.x * q0.x + a.y * q0.y + a.z * q0.z + a.w * q0.w;
                ac1 += a.x * q1.x + a.y * q1.y + a.z * q1.z + a.w * q1.w;
                ac2 += a.x * q2.x + a.y * q2.y + a.z * q2.z + a.w * q2.w;
                ac3 += a.x * q3.x + a.y * q3.y + a.z * q3.z + a.w * q3.w;
            }
        }
        int b = b0 + bl, fb = fq * 4;
        xt[b * 560 + (fb + 0) * 35 + t] = ac0 + bc[fb + 0];
        xt[b * 560 + (fb + 1) * 35 + t] = ac1 + bc[fb + 1];
        xt[b * 560 + (fb + 2) * 35 + t] = ac2 + bc[fb + 2];
        xt[b * 560 + (fb + 3) * 35 + t] = ac3 + bc[fb + 3];
    }
}

// ---------------- final dot + sigmoid ----------------
__global__ __launch_bounds__(256) void k_out(const float* __restrict__ f1, const float* __restrict__ W_out,
                                             const float* __restrict__ b_out, float* __restrict__ out) {
    int wid = (blockIdx.x * blockDim.x + threadIdx.x) >> 6;
    int lane = threadIdx.x & 63;
    if (wid >= BB) return;
    const float* xr = f1 + (size_t)wid * 512;
    float acc = 0.f;
    #pragma unroll
    for (int k = 0; k < 8; k++) acc += xr[lane + k * 64] * W_out[lane + k * 64];
    #pragma unroll
    for (int d = 32; d; d >>= 1) acc += __shfl_xor(acc, d);
    if (lane == 0) out[wid] = 1.f / (1.f + __expf(-(acc + b_out[0])));
}

// ---------------- host launcher ----------------
extern "C" void kernel_launch(void* const* d_in, const int* in_sizes, int n_in,
                              void* d_out, int out_size, void* d_ws, size_t ws_size,
                              hipStream_t stream) {
    const float* x      = (const float*)d_in[0];
    const int*   ei     = (const int*)d_in[1];
    const int*   batch  = (const int*)d_in[2];
    const int*   target = (const int*)d_in[3];
    const float* W_gat  = (const float*)d_in[4];
    const float* att_s  = (const float*)d_in[5];
    const float* att_d  = (const float*)d_in[6];
    const float* b_gat  = (const float*)d_in[7];
    const float* W_gcn  = (const float*)d_in[8];
    const float* b_gcn  = (const float*)d_in[9];
    const float* W_fcg1 = (const float*)d_in[10];
    const float* b_fcg1 = (const float*)d_in[11];
    const float* W_fcg2 = (const float*)d_in[12];
    const float* b_fcg2 = (const float*)d_in[13];
    const float* embxt  = (const float*)d_in[14];
    const float* W_conv = (const float*)d_in[15];
    const float* b_conv = (const float*)d_in[16];
    const float* W_fcxt = (const float*)d_in[17];
    const float* b_fcxt = (const float*)d_in[18];
    const float* W_fc1  = (const float*)d_in[19];
    const float* b_fc1  = (const float*)d_in[20];
    const float* W_out  = (const float*)d_in[21];
    const float* b_out  = (const float*)d_in[22];

    float* out_sig  = (float*)d_out;          // [500]
    float* alphaOut = (float*)d_out + BB;     // [850000 * 10]

    size_t o = 0;
    auto alloc = [&](size_t bytes) -> void* {
        o = (o + 255) & ~(size_t)255;
        void* p = (char*)d_ws + o;
        o += bytes;
        return p;
    };
    int*   deg     = (int*)alloc((size_t)NN * 4);
    int*   cur     = (int*)alloc((size_t)NN * 4);
    int*   offs    = (int*)alloc((size_t)NN * 4);
    int*   part    = (int*)alloc(128 * 4);
    int*   pscan   = (int*)alloc(128 * 4);
    int*   csr_src = (int*)alloc((size_t)ETOT * 4);
    float* dinv    = (float*)alloc((size_t)NN * 4);
    float* a_s     = (float*)alloc((size_t)NN * NHEAD * 4);
    float* a_d     = (float*)alloc((size_t)NN * NHEAD * 4);
    float* denArr  = (float*)alloc((size_t)NN * NHEAD * 4);
    ushort_t* xfb  = (ushort_t*)alloc((size_t)NN * 40 * 2);       // bf16 x rows (4 MB, L2-resident)
    float* wS      = (float*)alloc((size_t)FG * 4);
    float* wD      = (float*)alloc((size_t)FG * 4);
    ushort_t* WtBD = (ushort_t*)alloc((size_t)KPAD * KPAD * 2);   // block-diag W_gat^T
    ushort_t* WtGC = (ushort_t*)alloc((size_t)KPAD * KPAD * 2);
    ushort_t* WtF1 = (ushort_t*)alloc((size_t)1536 * 704 * 2);
    ushort_t* WtF2 = (ushort_t*)alloc((size_t)128 * 1536 * 2);
    ushort_t* WtFX = (ushort_t*)alloc((size_t)128 * 576 * 2);
    ushort_t* WtFC = (ushort_t*)alloc((size_t)512 * 256 * 2);
    float* pooled  = (float*)alloc((size_t)BB * 700 * 4);
    ushort_t* pooledb = (ushort_t*)alloc((size_t)MB2 * 704 * 2);
    ushort_t* t1b  = (ushort_t*)alloc((size_t)MB2 * 1536 * 2);
    float* xt      = (float*)alloc((size_t)BB * 560 * 4);
    ushort_t* xtb  = (ushort_t*)alloc((size_t)MB2 * 576 * 2);
    ushort_t* xcb  = (ushort_t*)alloc((size_t)MB2 * 256 * 2);
    float* f1      = (float*)alloc((size_t)MB2 * 512 * 4);
    ushort_t* hb   = (ushort_t*)alloc((size_t)MPAD * KPAD * 2);   // Z (GAT agg), later h2 (GCN GEMM out)
    char*  R2      = (char*)alloc((size_t)NN * FG * 4);           // 70 MB aliased region
    ushort_t* xg1b = (ushort_t*)R2;                               // [MPAD][KPAD] bf16 (38.4 MB)
    float* xg2     = (float*)R2;                                  // [NN][FG] f32, after xg1b dead
    (void)ws_size; (void)n_in; (void)in_sizes; (void)out_size;

    auto mfma = [&](const ushort_t* A, const ushort_t* Bt, void* C, const float* bias,
                    int M2, int Nv, int NP, int ldc, int KP, int act, int bf16out, int bdiag) {
        dim3 g(NP / 64, M2 / 128);
        k_mfma<<<g, 256, 0, stream>>>(A, Bt, C, M2, Nv, ldc, KP, KP / 64, bias, act, bf16out, bdiag);
    };

    // graph prep
    k_init<<<(NN + 255) / 256, 256, 0, stream>>>(deg, cur);
    k_deg<<<(EE + 255) / 256, 256, 0, stream>>>(ei, deg);
    k_scan1<<<NCHUNK, 512, 0, stream>>>(deg, part);
    k_scan2<<<1, 64, 0, stream>>>(part, pscan);
    k_scan3<<<NCHUNK, 512, 0, stream>>>(deg, pscan, offs);
    k_scatter<<<(ETOT + 255) / 256, 256, 0, stream>>>(ei, offs, cur, csr_src);
    k_dinv<<<(NN + 255) / 256, 256, 0, stream>>>(deg, dinv);

    // prep (bf16 x copy, fused attention weights, block-diag W_gat, W_gcn, FC weights)
    k_prep_xf<<<(NN * 40 + 255) / 256, 256, 0, stream>>>(x, xfb);
    k_prep_att<<<2, 256, 0, stream>>>(W_gat, att_s, att_d, wS, wD);
    k_prep_wbd<<<(KPAD * KPAD + 255) / 256, 256, 0, stream>>>(W_gat, WtBD);
    k_prep_wgcn<<<(KPAD * KPAD + 255) / 256, 256, 0, stream>>>(W_gcn, WtGC);
    k_prep_w<<<(704 * 1536 + 255) / 256, 256, 0, stream>>>(W_fcg1, WtF1, 700, 1500, 704, 1536);
    k_prep_w<<<(1536 * 128 + 255) / 256, 256, 0, stream>>>(W_fcg2, WtF2, 1500, 128, 1536, 128);
    k_prep_w<<<(576 * 128 + 255) / 256, 256, 0, stream>>>(W_fcxt, WtFX, 560, 128, 576, 128);
    k_prep_w<<<(256 * 512 + 255) / 256, 256, 0, stream>>>(W_fc1, WtFC, 256, 512, 256, 512);

    // GAT: logits -> aggregate x -> alpha -> block-diag GEMM (applies W_gat after aggregation)
    k_att2<<<(NN * NHEAD + 255) / 256, 256, 0, stream>>>(x, wS, wD, a_s, a_d);
    k_gat_agg<<<(NN + 3) / 4, 256, 0, stream>>>(xfb, a_s, a_d, csr_src, offs, deg, hb, denArr);   // Z -> hb
    k_alpha<<<(ETOT * NHEAD + 255) / 256, 256, 0, stream>>>(ei, a_s, a_d, denArr, alphaOut);
    mfma(hb, WtBD, xg1b, b_gat, MPAD, FG, KPAD, KPAD, KPAD, 1, 1, 1);        // xg1 = relu(Z@W_bd+b)

    // GCN: h2 = xg1 @ W_gcn (overwrites hb), then aggregate
    mfma(xg1b, WtGC, hb, nullptr, MPAD, KPAD, KPAD, KPAD, KPAD, 0, 1, 0);
    k_gcn_agg<<<(NN + 3) / 4, 256, 0, stream>>>(hb, csr_src, offs, deg, dinv, b_gcn, xg2);

    // pool + FC stacks (all FC layers via bf16 MFMA)
    k_pool<<<BB, 384, 0, stream>>>(xg2, batch, pooled);
    k_cast_pad<<<(MB2 * 704 + 255) / 256, 256, 0, stream>>>(pooled, pooledb, BB, 700, MB2, 704);
    mfma(pooledb, WtF1, t1b, b_fcg1, MB2, 1500, 1536, 1536, 704, 1, 1, 0);
    mfma(t1b, WtF2, xcb, b_fcg2, MB2, 128, 128, 256, 1536, 0, 1, 0);
    k_conv<<<250, 256, 0, stream>>>(target, embxt, W_conv, b_conv, xt);
    k_cast_pad<<<(MB2 * 576 + 255) / 256, 256, 0, stream>>>(xt, xtb, BB, 560, MB2, 576);
    mfma(xtb, WtFX, xcb + 128, b_fcxt, MB2, 128, 128, 256, 576, 0, 1, 0);
    mfma(xcb, WtFC, f1, b_fc1, MB2, 512, 512, 512, 256, 1, 0, 0);
    k_out<<<(BB + 3) / 4, 256, 0, stream>>>(f1, W_out, b_out, out_sig);
}

// Round 9
// 604.988 us; speedup vs baseline: 1.0669x; 1.0535x over previous
//
#include <hip/hip_runtime.h>
#include <math.h>

#define NN 50000
#define EE 800000
#define BB 500
#define LL 42
#define NHEAD 10
#define FH 35
#define FG 350
#define ETOT (EE + NN)
#define NCHUNK ((NN + 511) / 512)

#define KPAD 384         // bf16 row stride for Z / xg1
#define LDH2 352         // bf16 row stride for h2 (tight)
#define MPAD 50048       // M padded to multiple of 128
#define MB2  512         // padded batch rows for FC MFMA

typedef unsigned short ushort_t;
typedef __attribute__((ext_vector_type(8))) short short8v;
typedef __attribute__((ext_vector_type(4))) float float4v;

__device__ __forceinline__ float lrelu(float x) { return x > 0.f ? x : 0.2f * x; }

__device__ __forceinline__ ushort_t f2bf(float f) {
    unsigned int u = __float_as_uint(f);
    u += 0x7fffu + ((u >> 16) & 1u);      // round-to-nearest-even
    return (ushort_t)(u >> 16);
}
__device__ __forceinline__ float bflo(unsigned u) { return __uint_as_float(u << 16); }
__device__ __forceinline__ float bfhi(unsigned u) { return __uint_as_float(u & 0xffff0000u); }
__device__ __forceinline__ unsigned packbf(float a, float b) {
    return (unsigned)f2bf(a) | ((unsigned)f2bf(b) << 16);
}

__device__ __forceinline__ void async_cp16(const void* g, void* l) {
    __builtin_amdgcn_global_load_lds((const __attribute__((address_space(1))) unsigned int*)g,
                                     (__attribute__((address_space(3))) unsigned int*)l, 16, 0, 0);
}

// ---------------- graph prep ----------------
__global__ __launch_bounds__(256) void k_init(int* deg, int* cur) {
    int i = blockIdx.x * 256 + threadIdx.x;
    if (i < NN) { deg[i] = 1; cur[i] = 0; }   // deg=1 accounts for the self-loop
}

__global__ __launch_bounds__(256) void k_deg(const int* __restrict__ ei, int* deg) {
    int i = blockIdx.x * 256 + threadIdx.x;
    if (i < EE) atomicAdd(&deg[ei[EE + i]], 1);
}

__global__ __launch_bounds__(512) void k_scan1(const int* __restrict__ deg, int* part) {
    int i = blockIdx.x * 512 + threadIdx.x;
    int lane = threadIdx.x & 63, wv = threadIdx.x >> 6;
    int x = (i < NN) ? deg[i] : 0;
    #pragma unroll
    for (int d = 32; d; d >>= 1) x += __shfl_xor(x, d);
    __shared__ int wsum[8];
    if (lane == 0) wsum[wv] = x;
    __syncthreads();
    if (threadIdx.x == 0) {
        int s = 0;
        #pragma unroll
        for (int w = 0; w < 8; w++) s += wsum[w];
        part[blockIdx.x] = s;
    }
}

__global__ __launch_bounds__(64) void k_scan2(const int* __restrict__ part, int* pscan) {
    int l = threadIdx.x;
    int v0 = (l < NCHUNK) ? part[l] : 0;
    #pragma unroll
    for (int d = 1; d < 64; d <<= 1) { int t = __shfl_up(v0, d); if (l >= d) v0 += t; }
    int tot0 = __shfl(v0, 63);
    int v1 = (64 + l < NCHUNK) ? part[64 + l] : 0;
    #pragma unroll
    for (int d = 1; d < 64; d <<= 1) { int t = __shfl_up(v1, d); if (l >= d) v1 += t; }
    v1 += tot0;
    if (l < NCHUNK) pscan[l] = v0;
    if (64 + l < NCHUNK) pscan[64 + l] = v1;
}

__global__ __launch_bounds__(512) void k_scan3(const int* __restrict__ deg, const int* __restrict__ pscan,
                                               int* offs) {
    int i = blockIdx.x * 512 + threadIdx.x;
    int lane = threadIdx.x & 63, wv = threadIdx.x >> 6;
    int x = (i < NN) ? deg[i] : 0;
    int incl = x;
    #pragma unroll
    for (int d = 1; d < 64; d <<= 1) { int t = __shfl_up(incl, d); if (lane >= d) incl += t; }
    __shared__ int wtot[8];
    if (lane == 63) wtot[wv] = incl;
    __syncthreads();
    int woff = 0;
    for (int w = 0; w < wv; w++) woff += wtot[w];
    int base = (blockIdx.x == 0) ? 0 : pscan[blockIdx.x - 1];
    if (i < NN) offs[i] = base + woff + incl - x;   // exclusive prefix
}

__global__ __launch_bounds__(256) void k_scatter(const int* __restrict__ ei, const int* __restrict__ offs,
                                                 int* cur, int* csr_src) {
    int i = blockIdx.x * 256 + threadIdx.x;
    if (i < EE) {
        int s = ei[i], d = ei[EE + i];
        int slot = atomicAdd(&cur[d], 1);
        csr_src[offs[d] + slot] = s;
    } else if (i < ETOT) {
        int v = i - EE;
        int slot = atomicAdd(&cur[v], 1);
        csr_src[offs[v] + slot] = v;
    }
}

__global__ __launch_bounds__(256) void k_dinv(const int* __restrict__ deg, float* dinv) {
    int i = blockIdx.x * 256 + threadIdx.x;
    if (i < NN) dinv[i] = rsqrtf((float)deg[i]);
}

// ---------------- prep kernels ----------------
// xfb[n][40] bf16: padded copy of x rows (gather target for GAT aggregate) — 4.0 MB, fits XCD L2
__global__ __launch_bounds__(256) void k_prep_xf(const float* __restrict__ x, ushort_t* __restrict__ xfb) {
    int i = blockIdx.x * 256 + threadIdx.x;
    if (i >= NN * 40) return;
    int n = i / 40, c = i % 40;
    xfb[i] = (c < 35) ? f2bf(x[n * 35 + c]) : (ushort_t)0;
}

// w~_s[hd,c] = sum_cc W_gat[c, hd*35+cc] * att_s[hd,cc]  (and same for d)
__global__ __launch_bounds__(256) void k_prep_att(const float* __restrict__ W_gat, const float* __restrict__ att_s,
                                                  const float* __restrict__ att_d,
                                                  float* __restrict__ wS, float* __restrict__ wD) {
    int i = blockIdx.x * 256 + threadIdx.x;
    if (i >= FG) return;
    int hd = i / 35, c = i % 35;
    float ss = 0.f, dd = 0.f;
    for (int cc = 0; cc < 35; cc++) {
        float w = W_gat[c * FG + hd * 35 + cc];
        ss += w * att_s[hd * 35 + cc];
        dd += w * att_d[hd * 35 + cc];
    }
    wS[i] = ss;
    wD[i] = dd;
}

// block-diag W_gat, K in head-stride-36 space: Wt[n*KPAD + k], k=hd*36+cc
__global__ __launch_bounds__(256) void k_prep_wbd(const float* __restrict__ W_gat, ushort_t* __restrict__ Wt) {
    int i = blockIdx.x * 256 + threadIdx.x;
    if (i >= KPAD * KPAD) return;
    int n = i / KPAD, k = i % KPAD;
    int hd = k / 36, cc = k % 36;
    float v = 0.f;
    if (n < FG && cc < 35 && hd == n / 35) v = W_gat[cc * FG + n];
    Wt[i] = f2bf(v);
}

__global__ __launch_bounds__(256) void k_prep_wgcn(const float* __restrict__ W, ushort_t* __restrict__ Wt) {
    int i = blockIdx.x * 256 + threadIdx.x;
    if (i >= KPAD * KPAD) return;
    int n = i / KPAD, k = i % KPAD;
    float v = (n < FG && k < FG) ? W[k * FG + n] : 0.f;
    Wt[i] = f2bf(v);
}

// generic: Wt[n*KP+k] = bf16(W[k*N+n]), zero-padded
__global__ __launch_bounds__(256) void k_prep_w(const float* __restrict__ W, ushort_t* __restrict__ Wt,
                                                int K, int N, int KP, int NP) {
    int i = blockIdx.x * 256 + threadIdx.x;
    if (i >= KP * NP) return;
    int k = i / NP, n = i % NP;
    float v = (k < K && n < N) ? W[(size_t)k * N + n] : 0.f;
    Wt[(size_t)n * KP + k] = f2bf(v);
}

// generic: dst[r*KP+k] = bf16(src[r*K+k]), zero-padded
__global__ __launch_bounds__(256) void k_cast_pad(const float* __restrict__ src, ushort_t* __restrict__ dst,
                                                  int M, int K, int MP, int KP) {
    int i = blockIdx.x * 256 + threadIdx.x;
    if (i >= MP * KP) return;
    int r = i / KP, k = i % KP;
    dst[i] = (r < M && k < K) ? f2bf(src[(size_t)r * K + k]) : (ushort_t)0;
}

// zero pad rows 50000..50047 of a bf16 [MPAD][KPAD] buffer
__global__ __launch_bounds__(256) void k_zero_tail(ushort_t* buf) {
    int i = blockIdx.x * 256 + threadIdx.x;
    int total = (MPAD - NN) * KPAD;
    if (i < total) buf[(size_t)NN * KPAD + i] = 0;
}

// ---------------- bf16 MFMA GEMM: C = act(A[Mp,lda] @ Bt[Np,lda] + bias) ----------------
// tile 128x64, BK=64, 4 waves 2x2. bdiag=1: K-window (head-stride-36) limited per col-tile.
// nst: store-column clamp (cols >= nst not written; cols in [Nv, nst) written as 0)
__global__ __launch_bounds__(256) void k_mfma(const ushort_t* __restrict__ A, const ushort_t* __restrict__ Bt,
                                              void* __restrict__ C, int M, int Nv, int ldc, int lda,
                                              int ksteps, const float* __restrict__ bias, int act, int bf16out,
                                              int bdiag, int nst) {
    __shared__ ushort_t As[128 * 64];
    __shared__ ushort_t Bs[64 * 64];
    int tid = threadIdx.x;
    int wid = tid >> 6, lane = tid & 63;
    int m0 = blockIdx.y * 128, n0 = blockIdx.x * 64;
    int wm0 = (wid >> 1) * 64, wn0 = (wid & 1) * 32;
    int srow = tid >> 3;              // staging: 8 lanes x 16B per row(128B)
    int scol = (tid & 7) * 8;
    float4v acc[4][2] = {{{0.f,0.f,0.f,0.f},{0.f,0.f,0.f,0.f}},
                         {{0.f,0.f,0.f,0.f},{0.f,0.f,0.f,0.f}},
                         {{0.f,0.f,0.f,0.f},{0.f,0.f,0.f,0.f}},
                         {{0.f,0.f,0.f,0.f},{0.f,0.f,0.f,0.f}}};
    int a_off = (wm0 + (lane & 15)) * 64 + (lane >> 4) * 8;
    int b_off = (wn0 + (lane & 15)) * 64 + (lane >> 4) * 8;
    int ks0 = 0, ks1 = ksteps;
    if (bdiag) {
        int hlo = n0 / 35;
        int hhi = (n0 + 63) / 35; if (hhi > 9) hhi = 9;
        ks0 = (hlo * 36) >> 6;
        ks1 = (hhi * 36 + 36 + 63) >> 6;
    }
    for (int ks = ks0; ks < ks1; ks++) {
        int k0 = ks * 64;
        #pragma unroll
        for (int r = 0; r < 4; r++) {
            const ushort_t* g = A + (size_t)(m0 + r * 32 + srow) * lda + k0 + scol;
            async_cp16(g, As + (r * 256 + tid) * 8);
        }
        #pragma unroll
        for (int r = 0; r < 2; r++) {
            const ushort_t* g = Bt + (size_t)(n0 + r * 32 + srow) * lda + k0 + scol;
            async_cp16(g, Bs + (r * 256 + tid) * 8);
        }
        __syncthreads();
        #pragma unroll
        for (int kh = 0; kh < 2; kh++) {
            short8v b0 = *(const short8v*)&Bs[b_off + kh * 32];
            short8v b1 = *(const short8v*)&Bs[b_off + 16 * 64 + kh * 32];
            #pragma unroll
            for (int mi = 0; mi < 4; mi++) {
                short8v a = *(const short8v*)&As[a_off + mi * 16 * 64 + kh * 32];
                acc[mi][0] = __builtin_amdgcn_mfma_f32_16x16x32_bf16(a, b0, acc[mi][0], 0, 0, 0);
                acc[mi][1] = __builtin_amdgcn_mfma_f32_16x16x32_bf16(a, b1, acc[mi][1], 0, 0, 0);
            }
        }
        __syncthreads();
    }
    int lm = m0 + wm0 + (lane >> 4) * 4;
    int lc = n0 + wn0 + (lane & 15);
    #pragma unroll
    for (int mi = 0; mi < 4; mi++) {
        #pragma unroll
        for (int ni = 0; ni < 2; ni++) {
            int col = lc + ni * 16;
            if (col >= nst) continue;
            float bv = (bias != nullptr && col < Nv) ? bias[col] : 0.f;
            #pragma unroll
            for (int r = 0; r < 4; r++) {
                int row = lm + mi * 16 + r;
                if (row >= M) continue;
                float v = acc[mi][ni][r] + bv;
                if (act) v = fmaxf(v, 0.f);
                if (col >= Nv) v = 0.f;
                if (bf16out) ((ushort_t*)C)[(size_t)row * ldc + col] = f2bf(v);
                else         ((float*)C)[(size_t)row * ldc + col] = v;
            }
        }
    }
}

// ---------------- GAT attention logits from x directly: a = x @ w~ ----------------
__global__ __launch_bounds__(256) void k_att2(const float* __restrict__ x, const float* __restrict__ wS,
                                              const float* __restrict__ wD, float* __restrict__ a_s,
                                              float* __restrict__ a_d) {
    int tid = blockIdx.x * 256 + threadIdx.x;
    if (tid >= NN * NHEAD) return;
    int n = tid / NHEAD, hd = tid % NHEAD;
    const float* xr = x + (size_t)n * 35;
    const float* ws = wS + hd * 35;
    const float* wd = wD + hd * 35;
    float as = 0.f, ad = 0.f;
    #pragma unroll
    for (int c = 0; c < 35; c++) { float v = xr[c]; as += v * ws[c]; ad += v * wd[c]; }
    a_s[tid] = as;
    a_d[tid] = ad;
}

// ---------------- GAT aggregate on x (bf16, L2-resident), head-stride-36 Z layout ----------------
// Z[dst, hd*36+cc] = (1/den[hd]) * sum_e ex_e[hd] * x[src_e, cc]  (cc<36; cc=35 & cols>=360 are 0)
// lane owns u32 words w = lane, lane+64, lane+128(<180); head = w/18, x-col(u32) = w%18
__global__ __launch_bounds__(256) void k_gat_agg(const ushort_t* __restrict__ xfb, const float* __restrict__ a_s,
                                                 const float* __restrict__ a_d,
                                                 const int* __restrict__ csr_src,
                                                 const int* __restrict__ offs, const int* __restrict__ deg,
                                                 ushort_t* __restrict__ Zb, float* __restrict__ denArr) {
    int wid = (blockIdx.x * blockDim.x + threadIdx.x) >> 6;
    int lane = threadIdx.x & 63;
    if (wid >= NN) return;
    int o0 = offs[wid], d = deg[wid];
    bool mine = (lane < NHEAD);
    float adv = mine ? a_d[wid * NHEAD + lane] : 0.f;
    int h1 = lane / 18,          c1 = lane % 18;
    int h2 = (lane + 64) / 18,   c2 = (lane + 64) % 18;
    bool g3 = lane < 52;
    int h3 = g3 ? (lane + 128) / 18 : 0;
    int c3 = g3 ? (lane + 128) % 18 : 0;
    float den = 0.f;
    float a1l = 0.f, a1h = 0.f, a2l = 0.f, a2h = 0.f, a3l = 0.f, a3h = 0.f;
    const unsigned* x32 = (const unsigned*)xfb;
    int i = 0;
    for (; i + 2 <= d; i += 2) {
        int s0 = csr_src[o0 + i], s1 = csr_src[o0 + i + 1];
        const unsigned* x0 = x32 + (size_t)s0 * 20;
        const unsigned* x1 = x32 + (size_t)s1 * 20;
        float as0 = mine ? a_s[s0 * NHEAD + lane] : 0.f;
        float as1 = mine ? a_s[s1 * NHEAD + lane] : 0.f;
        unsigned u01 = x0[c1], u02 = x0[c2], u03 = x0[c3];
        unsigned u11 = x1[c1], u12 = x1[c2], u13 = x1[c3];
        float ex0 = __expf(lrelu(as0 + adv));
        float ex1 = __expf(lrelu(as1 + adv));
        den += ex0 + ex1;
        float e01 = __shfl(ex0, h1), e02 = __shfl(ex0, h2), e03 = __shfl(ex0, h3);
        float e11 = __shfl(ex1, h1), e12 = __shfl(ex1, h2), e13 = __shfl(ex1, h3);
        a1l += e01 * bflo(u01) + e11 * bflo(u11);
        a1h += e01 * bfhi(u01) + e11 * bfhi(u11);
        a2l += e02 * bflo(u02) + e12 * bflo(u12);
        a2h += e02 * bfhi(u02) + e12 * bfhi(u12);
        a3l += e03 * bflo(u03) + e13 * bflo(u13);
        a3h += e03 * bfhi(u03) + e13 * bfhi(u13);
    }
    for (; i < d; i++) {
        int s = csr_src[o0 + i];
        const unsigned* x0 = x32 + (size_t)s * 20;
        float as0 = mine ? a_s[s * NHEAD + lane] : 0.f;
        unsigned u01 = x0[c1], u02 = x0[c2], u03 = x0[c3];
        float ex0 = __expf(lrelu(as0 + adv));
        den += ex0;
        float e01 = __shfl(ex0, h1), e02 = __shfl(ex0, h2), e03 = __shfl(ex0, h3);
        a1l += e01 * bflo(u01);  a1h += e01 * bfhi(u01);
        a2l += e02 * bflo(u02);  a2h += e02 * bfhi(u02);
        a3l += e03 * bflo(u03);  a3h += e03 * bfhi(u03);
    }
    float rden = 1.f / (den + 1e-16f);
    if (mine) denArr[wid * NHEAD + lane] = den;
    float r1 = __shfl(rden, h1), r2 = __shfl(rden, h2), r3 = __shfl(rden, h3);
    unsigned* zr = (unsigned*)(Zb + (size_t)wid * KPAD);
    __builtin_nontemporal_store(packbf(a1l * r1, a1h * r1), &zr[lane]);
    __builtin_nontemporal_store(packbf(a2l * r2, a2h * r2), &zr[lane + 64]);
    __builtin_nontemporal_store(g3 ? packbf(a3l * r3, a3h * r3) : 0u, &zr[lane + 128]);
}

// ---------------- alpha in original edge order (coalesced writes; inputs L2-resident) ----------------
__global__ __launch_bounds__(256) void k_alpha(const int* __restrict__ ei, const float* __restrict__ a_s,
                                               const float* __restrict__ a_d, const float* __restrict__ den,
                                               float* __restrict__ alphaOut) {
    int i = blockIdx.x * 256 + threadIdx.x;
    if (i >= ETOT * NHEAD) return;
    int e = i / NHEAD, hd = i % NHEAD;
    int s, dst;
    if (e < EE) { s = ei[e]; dst = ei[EE + e]; }
    else { s = dst = e - EE; }
    float ex = __expf(lrelu(a_s[s * NHEAD + hd] + a_d[dst * NHEAD + hd]));
    __builtin_nontemporal_store(ex / (den[dst * NHEAD + hd] + 1e-16f), &alphaOut[i]);
}

// ---------------- GCN aggregate: wave per node (bf16 h2 gathers, row stride 352), unrolled x2 ----------------
__global__ __launch_bounds__(256) void k_gcn_agg(const ushort_t* __restrict__ h2b,
                                                 const int* __restrict__ csr_src,
                                                 const int* __restrict__ offs, const int* __restrict__ deg,
                                                 const float* __restrict__ dinv, const float* __restrict__ b_gcn,
                                                 float* __restrict__ xg2) {
    int wid = (blockIdx.x * blockDim.x + threadIdx.x) >> 6;
    int lane = threadIdx.x & 63;
    if (wid >= NN) return;
    int o0 = offs[wid], d = deg[wid];
    float wv = dinv[wid];
    bool g3 = lane < 48;                      // third u32 group valid (w = lane+128 < 176)
    int w3 = g3 ? (lane + 128) : 0;
    float aL0 = 0.f, aH0 = 0.f, aL1 = 0.f, aH1 = 0.f, aL2 = 0.f, aH2 = 0.f;
    const unsigned* h32 = (const unsigned*)h2b;
    int i = 0;
    for (; i + 2 <= d; i += 2) {
        int s0 = csr_src[o0 + i], s1 = csr_src[o0 + i + 1];
        float w0 = dinv[s0], w1 = dinv[s1];
        const unsigned* h0 = h32 + (size_t)s0 * (LDH2 / 2);
        const unsigned* h1 = h32 + (size_t)s1 * (LDH2 / 2);
        unsigned u00 = h0[lane], u01 = h0[lane + 64], u02 = h0[w3];
        unsigned u10 = h1[lane], u11 = h1[lane + 64], u12 = h1[w3];
        aL0 += w0 * bflo(u00) + w1 * bflo(u10);
        aH0 += w0 * bfhi(u00) + w1 * bfhi(u10);
        aL1 += w0 * bflo(u01) + w1 * bflo(u11);
        aH1 += w0 * bfhi(u01) + w1 * bfhi(u11);
        aL2 += w0 * bflo(u02) + w1 * bflo(u12);
        aH2 += w0 * bfhi(u02) + w1 * bfhi(u12);
    }
    for (; i < d; i++) {
        int s = csr_src[o0 + i];
        float ws = dinv[s];
        const unsigned* hr = h32 + (size_t)s * (LDH2 / 2);
        unsigned u0 = hr[lane], u1 = hr[lane + 64], u2 = hr[w3];
        aL0 += ws * bflo(u0);  aH0 += ws * bfhi(u0);
        aL1 += ws * bflo(u1);  aH1 += ws * bfhi(u1);
        aL2 += ws * bflo(u2);  aH2 += ws * bfhi(u2);
    }
    float* orow = xg2 + (size_t)wid * FG;
    {
        int f = 2 * lane;
        __builtin_nontemporal_store(fmaxf(wv * aL0 + b_gcn[f], 0.f), &orow[f]);
        __builtin_nontemporal_store(fmaxf(wv * aH0 + b_gcn[f + 1], 0.f), &orow[f + 1]);
    }
    {
        int f = 128 + 2 * lane;
        __builtin_nontemporal_store(fmaxf(wv * aL1 + b_gcn[f], 0.f), &orow[f]);
        __builtin_nontemporal_store(fmaxf(wv * aH1 + b_gcn[f + 1], 0.f), &orow[f + 1]);
    }
    {
        int f = 256 + 2 * lane;
        if (f < FG) {
            __builtin_nontemporal_store(fmaxf(wv * aL2 + b_gcn[f], 0.f), &orow[f]);
            __builtin_nontemporal_store(fmaxf(wv * aH2 + b_gcn[f + 1], 0.f), &orow[f + 1]);
        }
    }
}

// ---------------- per-graph max+mean pool ----------------
__device__ __forceinline__ int lowerB(const int* a, int n, int key) {
    int lo = 0, hi = n;
    while (lo < hi) { int mid = (lo + hi) >> 1; if (a[mid] < key) lo = mid + 1; else hi = mid; }
    return lo;
}

__global__ __launch_bounds__(384) void k_pool(const float* __restrict__ xg2, const int* __restrict__ batch,
                                              float* __restrict__ pooled) {
    int g = blockIdx.x;
    int f = threadIdx.x;
    int s = lowerB(batch, NN, g);
    int e = lowerB(batch, NN, g + 1);
    if (f >= FG) return;
    float mx = -INFINITY, sm = 0.f;
    int n = s;
    for (; n + 4 <= e; n += 4) {
        float v0 = xg2[(size_t)(n + 0) * FG + f];
        float v1 = xg2[(size_t)(n + 1) * FG + f];
        float v2 = xg2[(size_t)(n + 2) * FG + f];
        float v3 = xg2[(size_t)(n + 3) * FG + f];
        mx = fmaxf(fmaxf(mx, v0), fmaxf(fmaxf(v1, v2), v3));
        sm += v0 + v1 + v2 + v3;
    }
    for (; n < e; n++) {
        float v = xg2[(size_t)n * FG + f];
        mx = fmaxf(mx, v);
        sm += v;
    }
    int cnt = e - s;
    pooled[g * 700 + f] = mx;
    pooled[g * 700 + FG + f] = sm / fmaxf((float)cnt, 1.f);
}

// ---------------- protein conv branch: LDS-resident, 2 proteins per block ----------------
__global__ __launch_bounds__(256) void k_conv(const int* __restrict__ target, const float* __restrict__ emb,
                                              const float* __restrict__ Wc, const float* __restrict__ bc,
                                              float* __restrict__ xt) {
    __shared__ float embL[26 * 132];        // rows padded to 132 floats
    __shared__ float WL[16 * 8 * 128];      // WL[f][k][e] = Wc[f][e][k]
    __shared__ int   tgL[2 * LL];
    int tid = threadIdx.x;
    int b0 = blockIdx.x * 2;
    for (int i = tid; i < 26 * 128; i += 256) {
        int r = i >> 7, e = i & 127;
        embL[r * 132 + e] = emb[i];
    }
    for (int i = tid; i < 16384; i += 256) {
        int f = i >> 10, rem = i & 1023, k = rem >> 7, e = rem & 127;
        WL[i] = Wc[f * 1024 + e * 8 + k];
    }
    if (tid < 2 * LL) tgL[tid] = target[b0 * LL + tid];
    __syncthreads();
    #pragma unroll
    for (int pass = 0; pass < 2; pass++) {
        int r = tid + pass * 256;
        if (r >= 280) break;
        int bl = r / 140, rem = r % 140;
        int fq = rem / 35, t = rem % 35;
        const int* tg = &tgL[bl * LL];
        float ac0 = 0.f, ac1 = 0.f, ac2 = 0.f, ac3 = 0.f;
        for (int k = 0; k < 8; k++) {
            const float* er = &embL[tg[t + k] * 132];
            const float* w0 = &WL[((fq * 4 + 0) * 8 + k) * 128];
            const float* w1 = &WL[((fq * 4 + 1) * 8 + k) * 128];
            const float* w2 = &WL[((fq * 4 + 2) * 8 + k) * 128];
            const float* w3 = &WL[((fq * 4 + 3) * 8 + k) * 128];
            #pragma unroll 8
            for (int e = 0; e < 128; e += 4) {
                float4 a = *(const float4*)&er[e];
                float4 q0 = *(const float4*)&w0[e];
                float4 q1 = *(const float4*)&w1[e];
                float4 q2 = *(const float4*)&w2[e];
                float4 q3 = *(const float4*)&w3[e];
                ac0 += a.x * q0.x + a.y * q0.y + a.z * q0.z + a.w * q0.w;
                ac1 += a.x * q1.x + a.y * q1.y + a.z * q1.z + a.w * q1.w;
                ac2 += a.x * q2.x + a.y * q2.y + a.z * q2.z + a.w * q2.w;
                ac3 += a.x * q3.x + a.y * q3.y + a.z * q3.z + a.w * q3.w;
            }
        }
        int b = b0 + bl, fb = fq * 4;
        xt[b * 560 + (fb + 0) * 35 + t] = ac0 + bc[fb + 0];
        xt[b * 560 + (fb + 1) * 35 + t] = ac1 + bc[fb + 1];
        xt[b * 560 + (fb + 2) * 35 + t] = ac2 + bc[fb + 2];
        xt[b * 560 + (fb + 3) * 35 + t] = ac3 + bc[fb + 3];
    }
}

// ---------------- final dot + sigmoid ----------------
__global__ __launch_bounds__(256) void k_out(const float* __restrict__ f1, const float* __restrict__ W_out,
                                             const float* __restrict__ b_out, float* __restrict__ out) {
    int wid = (blockIdx.x * blockDim.x + threadIdx.x) >> 6;
    int lane = threadIdx.x & 63;
    if (wid >= BB) return;
    const float* xr = f1 + (size_t)wid * 512;
    float acc = 0.f;
    #pragma unroll
    for (int k = 0; k < 8; k++) acc += xr[lane + k * 64] * W_out[lane + k * 64];
    #pragma unroll
    for (int d = 32; d; d >>= 1) acc += __shfl_xor(acc, d);
    if (lane == 0) out[wid] = 1.f / (1.f + __expf(-(acc + b_out[0])));
}

// ---------------- host launcher ----------------
extern "C" void kernel_launch(void* const* d_in, const int* in_sizes, int n_in,
                              void* d_out, int out_size, void* d_ws, size_t ws_size,
                              hipStream_t stream) {
    const float* x      = (const float*)d_in[0];
    const int*   ei     = (const int*)d_in[1];
    const int*   batch  = (const int*)d_in[2];
    const int*   target = (const int*)d_in[3];
    const float* W_gat  = (const float*)d_in[4];
    const float* att_s  = (const float*)d_in[5];
    const float* att_d  = (const float*)d_in[6];
    const float* b_gat  = (const float*)d_in[7];
    const float* W_gcn  = (const float*)d_in[8];
    const float* b_gcn  = (const float*)d_in[9];
    const float* W_fcg1 = (const float*)d_in[10];
    const float* b_fcg1 = (const float*)d_in[11];
    const float* W_fcg2 = (const float*)d_in[12];
    const float* b_fcg2 = (const float*)d_in[13];
    const float* embxt  = (const float*)d_in[14];
    const float* W_conv = (const float*)d_in[15];
    const float* b_conv = (const float*)d_in[16];
    const float* W_fcxt = (const float*)d_in[17];
    const float* b_fcxt = (const float*)d_in[18];
    const float* W_fc1  = (const float*)d_in[19];
    const float* b_fc1  = (const float*)d_in[20];
    const float* W_out  = (const float*)d_in[21];
    const float* b_out  = (const float*)d_in[22];

    float* out_sig  = (float*)d_out;          // [500]
    float* alphaOut = (float*)d_out + BB;     // [850000 * 10]

    size_t o = 0;
    auto alloc = [&](size_t bytes) -> void* {
        o = (o + 255) & ~(size_t)255;
        void* p = (char*)d_ws + o;
        o += bytes;
        return p;
    };
    int*   deg     = (int*)alloc((size_t)NN * 4);
    int*   cur     = (int*)alloc((size_t)NN * 4);
    int*   offs    = (int*)alloc((size_t)NN * 4);
    int*   part    = (int*)alloc(128 * 4);
    int*   pscan   = (int*)alloc(128 * 4);
    int*   csr_src = (int*)alloc((size_t)ETOT * 4);
    float* dinv    = (float*)alloc((size_t)NN * 4);
    float* a_s     = (float*)alloc((size_t)NN * NHEAD * 4);
    float* a_d     = (float*)alloc((size_t)NN * NHEAD * 4);
    float* denArr  = (float*)alloc((size_t)NN * NHEAD * 4);
    ushort_t* xfb  = (ushort_t*)alloc((size_t)NN * 40 * 2);       // bf16 x rows (4 MB, L2-resident)
    float* wS      = (float*)alloc((size_t)FG * 4);
    float* wD      = (float*)alloc((size_t)FG * 4);
    ushort_t* WtBD = (ushort_t*)alloc((size_t)KPAD * KPAD * 2);   // block-diag W_gat^T (stride-36 K)
    ushort_t* WtGC = (ushort_t*)alloc((size_t)KPAD * KPAD * 2);
    ushort_t* WtF1 = (ushort_t*)alloc((size_t)1536 * 704 * 2);
    ushort_t* WtF2 = (ushort_t*)alloc((size_t)128 * 1536 * 2);
    ushort_t* WtFX = (ushort_t*)alloc((size_t)128 * 576 * 2);
    ushort_t* WtFC = (ushort_t*)alloc((size_t)512 * 256 * 2);
    float* pooled  = (float*)alloc((size_t)BB * 700 * 4);
    ushort_t* pooledb = (ushort_t*)alloc((size_t)MB2 * 704 * 2);
    ushort_t* t1b  = (ushort_t*)alloc((size_t)MB2 * 1536 * 2);
    float* xt      = (float*)alloc((size_t)BB * 560 * 4);
    ushort_t* xtb  = (ushort_t*)alloc((size_t)MB2 * 576 * 2);
    ushort_t* xcb  = (ushort_t*)alloc((size_t)MB2 * 256 * 2);
    float* f1      = (float*)alloc((size_t)MB2 * 512 * 4);
    ushort_t* hb   = (ushort_t*)alloc((size_t)MPAD * KPAD * 2);   // Z (GAT agg), later h2 (GCN GEMM out, ld 352)
    char*  R2      = (char*)alloc((size_t)NN * FG * 4);           // 70 MB aliased region
    ushort_t* xg1b = (ushort_t*)R2;                               // [MPAD][KPAD] bf16 (38.4 MB)
    float* xg2     = (float*)R2;                                  // [NN][FG] f32, after xg1b dead
    (void)ws_size; (void)n_in; (void)in_sizes; (void)out_size;

    auto mfma = [&](const ushort_t* A, const ushort_t* Bt, void* C, const float* bias,
                    int M2, int Nv, int NP, int ldc, int KP, int act, int bf16out, int bdiag, int nst) {
        dim3 g(NP / 64, M2 / 128);
        k_mfma<<<g, 256, 0, stream>>>(A, Bt, C, M2, Nv, ldc, KP, KP / 64, bias, act, bf16out, bdiag, nst);
    };

    // graph prep
    k_init<<<(NN + 255) / 256, 256, 0, stream>>>(deg, cur);
    k_deg<<<(EE + 255) / 256, 256, 0, stream>>>(ei, deg);
    k_scan1<<<NCHUNK, 512, 0, stream>>>(deg, part);
    k_scan2<<<1, 64, 0, stream>>>(part, pscan);
    k_scan3<<<NCHUNK, 512, 0, stream>>>(deg, pscan, offs);
    k_scatter<<<(ETOT + 255) / 256, 256, 0, stream>>>(ei, offs, cur, csr_src);
    k_dinv<<<(NN + 255) / 256, 256, 0, stream>>>(deg, dinv);

    // prep (bf16 x copy, fused attention weights, block-diag W_gat, W_gcn, FC weights)
    k_prep_xf<<<(NN * 40 + 255) / 256, 256, 0, stream>>>(x, xfb);
    k_prep_att<<<2, 256, 0, stream>>>(W_gat, att_s, att_d, wS, wD);
    k_prep_wbd<<<(KPAD * KPAD + 255) / 256, 256, 0, stream>>>(W_gat, WtBD);
    k_prep_wgcn<<<(KPAD * KPAD + 255) / 256, 256, 0, stream>>>(W_gcn, WtGC);
    k_prep_w<<<(704 * 1536 + 255) / 256, 256, 0, stream>>>(W_fcg1, WtF1, 700, 1500, 704, 1536);
    k_prep_w<<<(1536 * 128 + 255) / 256, 256, 0, stream>>>(W_fcg2, WtF2, 1500, 128, 1536, 128);
    k_prep_w<<<(576 * 128 + 255) / 256, 256, 0, stream>>>(W_fcxt, WtFX, 560, 128, 576, 128);
    k_prep_w<<<(256 * 512 + 255) / 256, 256, 0, stream>>>(W_fc1, WtFC, 256, 512, 256, 512);
    k_zero_tail<<<((MPAD - NN) * KPAD + 255) / 256, 256, 0, stream>>>(hb);   // Z tail rows

    // GAT: logits -> aggregate x (stride-36 Z) -> alpha -> block-diag GEMM
    k_att2<<<(NN * NHEAD + 255) / 256, 256, 0, stream>>>(x, wS, wD, a_s, a_d);
    k_gat_agg<<<(NN + 3) / 4, 256, 0, stream>>>(xfb, a_s, a_d, csr_src, offs, deg, hb, denArr);   // Z -> hb
    k_alpha<<<(ETOT * NHEAD + 255) / 256, 256, 0, stream>>>(ei, a_s, a_d, denArr, alphaOut);
    mfma(hb, WtBD, xg1b, b_gat, MPAD, FG, KPAD, KPAD, KPAD, 1, 1, 1, KPAD);  // xg1 = relu(Z@W_bd+b)

    // GCN: h2 = xg1 @ W_gcn (overwrites hb, row stride 352), then aggregate
    mfma(xg1b, WtGC, hb, nullptr, MPAD, FG, KPAD, LDH2, KPAD, 0, 1, 0, LDH2);
    k_gcn_agg<<<(NN + 3) / 4, 256, 0, stream>>>(hb, csr_src, offs, deg, dinv, b_gcn, xg2);

    // pool + FC stacks (all FC layers via bf16 MFMA)
    k_pool<<<BB, 384, 0, stream>>>(xg2, batch, pooled);
    k_cast_pad<<<(MB2 * 704 + 255) / 256, 256, 0, stream>>>(pooled, pooledb, BB, 700, MB2, 704);
    mfma(pooledb, WtF1, t1b, b_fcg1, MB2, 1500, 1536, 1536, 704, 1, 1, 0, 1536);
    mfma(t1b, WtF2, xcb, b_fcg2, MB2, 128, 128, 256, 1536, 0, 1, 0, 128);
    k_conv<<<250, 256, 0, stream>>>(target, embxt, W_conv, b_conv, xt);
    k_cast_pad<<<(MB2 * 576 + 255) / 256, 256, 0, stream>>>(xt, xtb, BB, 560, MB2, 576);
    mfma(xtb, WtFX, xcb + 128, b_fcxt, MB2, 128, 128, 256, 576, 0, 1, 0, 128);
    mfma(xcb, WtFC, f1, b_fc1, MB2, 512, 512, 512, 256, 1, 0, 0, 512);
    k_out<<<(BB + 3) / 4, 256, 0, stream>>>(f1, W_out, b_out, out_sig);
}

// Round 10
// 582.882 us; speedup vs baseline: 1.1074x; 1.0379x over previous
//
#include <hip/hip_runtime.h>
#include <math.h>

#define NN 50000
#define EE 800000
#define BB 500
#define LL 42
#define NHEAD 10
#define FH 35
#define FG 350
#define ETOT (EE + NN)
#define NCHUNK ((NN + 511) / 512)

#define KPAD 384         // bf16 row stride for Z / xg1
#define LDH2 352         // bf16 row stride for h2 (tight)
#define MPAD 50048       // M padded to multiple of 128
#define MB2  512         // padded batch rows for FC MFMA

typedef unsigned short ushort_t;
typedef __attribute__((ext_vector_type(8))) short short8v;
typedef __attribute__((ext_vector_type(4))) float float4v;

__device__ __forceinline__ float lrelu(float x) { return x > 0.f ? x : 0.2f * x; }

__device__ __forceinline__ ushort_t f2bf(float f) {
    unsigned int u = __float_as_uint(f);
    u += 0x7fffu + ((u >> 16) & 1u);      // round-to-nearest-even
    return (ushort_t)(u >> 16);
}
__device__ __forceinline__ float bflo(unsigned u) { return __uint_as_float(u << 16); }
__device__ __forceinline__ float bfhi(unsigned u) { return __uint_as_float(u & 0xffff0000u); }
__device__ __forceinline__ unsigned packbf(float a, float b) {
    return (unsigned)f2bf(a) | ((unsigned)f2bf(b) << 16);
}

__device__ __forceinline__ void async_cp16(const void* g, void* l) {
    __builtin_amdgcn_global_load_lds((const __attribute__((address_space(1))) unsigned int*)g,
                                     (__attribute__((address_space(3))) unsigned int*)l, 16, 0, 0);
}

// ---------------- graph prep ----------------
__global__ __launch_bounds__(256) void k_init(int* deg, int* cur) {
    int i = blockIdx.x * 256 + threadIdx.x;
    if (i < NN) { deg[i] = 1; cur[i] = 0; }   // deg=1 accounts for the self-loop
}

__global__ __launch_bounds__(256) void k_deg(const int* __restrict__ ei, int* deg) {
    int i = blockIdx.x * 256 + threadIdx.x;
    if (i < EE) atomicAdd(&deg[ei[EE + i]], 1);
}

__global__ __launch_bounds__(512) void k_scan1(const int* __restrict__ deg, int* part) {
    int i = blockIdx.x * 512 + threadIdx.x;
    int lane = threadIdx.x & 63, wv = threadIdx.x >> 6;
    int x = (i < NN) ? deg[i] : 0;
    #pragma unroll
    for (int d = 32; d; d >>= 1) x += __shfl_xor(x, d);
    __shared__ int wsum[8];
    if (lane == 0) wsum[wv] = x;
    __syncthreads();
    if (threadIdx.x == 0) {
        int s = 0;
        #pragma unroll
        for (int w = 0; w < 8; w++) s += wsum[w];
        part[blockIdx.x] = s;
    }
}

__global__ __launch_bounds__(64) void k_scan2(const int* __restrict__ part, int* pscan) {
    int l = threadIdx.x;
    int v0 = (l < NCHUNK) ? part[l] : 0;
    #pragma unroll
    for (int d = 1; d < 64; d <<= 1) { int t = __shfl_up(v0, d); if (l >= d) v0 += t; }
    int tot0 = __shfl(v0, 63);
    int v1 = (64 + l < NCHUNK) ? part[64 + l] : 0;
    #pragma unroll
    for (int d = 1; d < 64; d <<= 1) { int t = __shfl_up(v1, d); if (l >= d) v1 += t; }
    v1 += tot0;
    if (l < NCHUNK) pscan[l] = v0;
    if (64 + l < NCHUNK) pscan[64 + l] = v1;
}

__global__ __launch_bounds__(512) void k_scan3(const int* __restrict__ deg, const int* __restrict__ pscan,
                                               int* offs) {
    int i = blockIdx.x * 512 + threadIdx.x;
    int lane = threadIdx.x & 63, wv = threadIdx.x >> 6;
    int x = (i < NN) ? deg[i] : 0;
    int incl = x;
    #pragma unroll
    for (int d = 1; d < 64; d <<= 1) { int t = __shfl_up(incl, d); if (lane >= d) incl += t; }
    __shared__ int wtot[8];
    if (lane == 63) wtot[wv] = incl;
    __syncthreads();
    int woff = 0;
    for (int w = 0; w < wv; w++) woff += wtot[w];
    int base = (blockIdx.x == 0) ? 0 : pscan[blockIdx.x - 1];
    if (i < NN) offs[i] = base + woff + incl - x;   // exclusive prefix
}

__global__ __launch_bounds__(256) void k_scatter(const int* __restrict__ ei, const int* __restrict__ offs,
                                                 int* cur, int* csr_src) {
    int i = blockIdx.x * 256 + threadIdx.x;
    if (i < EE) {
        int s = ei[i], d = ei[EE + i];
        int slot = atomicAdd(&cur[d], 1);
        csr_src[offs[d] + slot] = s;
    } else if (i < ETOT) {
        int v = i - EE;
        int slot = atomicAdd(&cur[v], 1);
        csr_src[offs[v] + slot] = v;
    }
}

__global__ __launch_bounds__(256) void k_dinv(const int* __restrict__ deg, float* dinv) {
    int i = blockIdx.x * 256 + threadIdx.x;
    if (i < NN) dinv[i] = rsqrtf((float)deg[i]);
}

// ---------------- prep kernels ----------------
// w~_s[hd,c] = sum_cc W_gat[c, hd*35+cc] * att_s[hd,cc]  (and same for d)
__global__ __launch_bounds__(256) void k_prep_att(const float* __restrict__ W_gat, const float* __restrict__ att_s,
                                                  const float* __restrict__ att_d,
                                                  float* __restrict__ wS, float* __restrict__ wD) {
    int i = blockIdx.x * 256 + threadIdx.x;
    if (i >= FG) return;
    int hd = i / 35, c = i % 35;
    float ss = 0.f, dd = 0.f;
    for (int cc = 0; cc < 35; cc++) {
        float w = W_gat[c * FG + hd * 35 + cc];
        ss += w * att_s[hd * 35 + cc];
        dd += w * att_d[hd * 35 + cc];
    }
    wS[i] = ss;
    wD[i] = dd;
}

// fused node prep: xfb[n][40] bf16 + a_s/a_d[n][10] (x row read once; wS/wD LDS-staged)
__global__ __launch_bounds__(256) void k_prep_node(const float* __restrict__ x, const float* __restrict__ wS,
                                                   const float* __restrict__ wD, ushort_t* __restrict__ xfb,
                                                   float* __restrict__ a_s, float* __restrict__ a_d) {
    __shared__ float sw[FG], dw[FG];
    int tid = threadIdx.x;
    for (int i = tid; i < FG; i += 256) { sw[i] = wS[i]; dw[i] = wD[i]; }
    __syncthreads();
    int n = blockIdx.x * 256 + tid;
    if (n >= NN) return;
    float xr[35];
    #pragma unroll
    for (int c = 0; c < 35; c++) xr[c] = x[(size_t)n * 35 + c];
    unsigned* xo = (unsigned*)(xfb + (size_t)n * 40);
    #pragma unroll
    for (int w = 0; w < 17; w++) xo[w] = packbf(xr[2 * w], xr[2 * w + 1]);
    xo[17] = packbf(xr[34], 0.f);
    xo[18] = 0u; xo[19] = 0u;
    #pragma unroll
    for (int hd = 0; hd < NHEAD; hd++) {
        const float* ws = &sw[hd * 35];
        const float* wd = &dw[hd * 35];
        float as = 0.f, ad = 0.f;
        #pragma unroll
        for (int c = 0; c < 35; c++) { float v = xr[c]; as += v * ws[c]; ad += v * wd[c]; }
        a_s[n * NHEAD + hd] = as;
        a_d[n * NHEAD + hd] = ad;
    }
}

// block-diag W_gat, K in head-stride-36 space: Wt[n*KPAD + k], k=hd*36+cc
__global__ __launch_bounds__(256) void k_prep_wbd(const float* __restrict__ W_gat, ushort_t* __restrict__ Wt) {
    int i = blockIdx.x * 256 + threadIdx.x;
    if (i >= KPAD * KPAD) return;
    int n = i / KPAD, k = i % KPAD;
    int hd = k / 36, cc = k % 36;
    float v = 0.f;
    if (n < FG && cc < 35 && hd == n / 35) v = W_gat[cc * FG + n];
    Wt[i] = f2bf(v);
}

__global__ __launch_bounds__(256) void k_prep_wgcn(const float* __restrict__ W, ushort_t* __restrict__ Wt) {
    int i = blockIdx.x * 256 + threadIdx.x;
    if (i >= KPAD * KPAD) return;
    int n = i / KPAD, k = i % KPAD;
    float v = (n < FG && k < FG) ? W[k * FG + n] : 0.f;
    Wt[i] = f2bf(v);
}

// generic: Wt[n*KP+k] = bf16(W[k*N+n]), zero-padded
__global__ __launch_bounds__(256) void k_prep_w(const float* __restrict__ W, ushort_t* __restrict__ Wt,
                                                int K, int N, int KP, int NP) {
    int i = blockIdx.x * 256 + threadIdx.x;
    if (i >= KP * NP) return;
    int k = i / NP, n = i % NP;
    float v = (k < K && n < N) ? W[(size_t)k * N + n] : 0.f;
    Wt[(size_t)n * KP + k] = f2bf(v);
}

// generic: dst[r*KP+k] = bf16(src[r*K+k]), zero-padded
__global__ __launch_bounds__(256) void k_cast_pad(const float* __restrict__ src, ushort_t* __restrict__ dst,
                                                  int M, int K, int MP, int KP) {
    int i = blockIdx.x * 256 + threadIdx.x;
    if (i >= MP * KP) return;
    int r = i / KP, k = i % KP;
    dst[i] = (r < M && k < K) ? f2bf(src[(size_t)r * K + k]) : (ushort_t)0;
}

// zero pad rows 50000..50047 of a bf16 [MPAD][KPAD] buffer
__global__ __launch_bounds__(256) void k_zero_tail(ushort_t* buf) {
    int i = blockIdx.x * 256 + threadIdx.x;
    int total = (MPAD - NN) * KPAD;
    if (i < total) buf[(size_t)NN * KPAD + i] = 0;
}

// ---------------- bf16 MFMA GEMM: C = act(A[Mp,lda] @ Bt[Np,lda] + bias) ----------------
// tile 128x64, BK=64, 4 waves 2x2. bdiag=1: K-window (head-stride-36) limited per col-tile.
// nst: store-column clamp (cols >= nst not written; cols in [Nv, nst) written as 0)
__global__ __launch_bounds__(256) void k_mfma(const ushort_t* __restrict__ A, const ushort_t* __restrict__ Bt,
                                              void* __restrict__ C, int M, int Nv, int ldc, int lda,
                                              int ksteps, const float* __restrict__ bias, int act, int bf16out,
                                              int bdiag, int nst) {
    __shared__ ushort_t As[128 * 64];
    __shared__ ushort_t Bs[64 * 64];
    int tid = threadIdx.x;
    int wid = tid >> 6, lane = tid & 63;
    int m0 = blockIdx.y * 128, n0 = blockIdx.x * 64;
    int wm0 = (wid >> 1) * 64, wn0 = (wid & 1) * 32;
    int srow = tid >> 3;              // staging: 8 lanes x 16B per row(128B)
    int scol = (tid & 7) * 8;
    float4v acc[4][2] = {{{0.f,0.f,0.f,0.f},{0.f,0.f,0.f,0.f}},
                         {{0.f,0.f,0.f,0.f},{0.f,0.f,0.f,0.f}},
                         {{0.f,0.f,0.f,0.f},{0.f,0.f,0.f,0.f}},
                         {{0.f,0.f,0.f,0.f},{0.f,0.f,0.f,0.f}}};
    int a_off = (wm0 + (lane & 15)) * 64 + (lane >> 4) * 8;
    int b_off = (wn0 + (lane & 15)) * 64 + (lane >> 4) * 8;
    int ks0 = 0, ks1 = ksteps;
    if (bdiag) {
        int hlo = n0 / 35;
        int hhi = (n0 + 63) / 35; if (hhi > 9) hhi = 9;
        ks0 = (hlo * 36) >> 6;
        ks1 = (hhi * 36 + 36 + 63) >> 6;
    }
    for (int ks = ks0; ks < ks1; ks++) {
        int k0 = ks * 64;
        #pragma unroll
        for (int r = 0; r < 4; r++) {
            const ushort_t* g = A + (size_t)(m0 + r * 32 + srow) * lda + k0 + scol;
            async_cp16(g, As + (r * 256 + tid) * 8);
        }
        #pragma unroll
        for (int r = 0; r < 2; r++) {
            const ushort_t* g = Bt + (size_t)(n0 + r * 32 + srow) * lda + k0 + scol;
            async_cp16(g, Bs + (r * 256 + tid) * 8);
        }
        __syncthreads();
        #pragma unroll
        for (int kh = 0; kh < 2; kh++) {
            short8v b0 = *(const short8v*)&Bs[b_off + kh * 32];
            short8v b1 = *(const short8v*)&Bs[b_off + 16 * 64 + kh * 32];
            #pragma unroll
            for (int mi = 0; mi < 4; mi++) {
                short8v a = *(const short8v*)&As[a_off + mi * 16 * 64 + kh * 32];
                acc[mi][0] = __builtin_amdgcn_mfma_f32_16x16x32_bf16(a, b0, acc[mi][0], 0, 0, 0);
                acc[mi][1] = __builtin_amdgcn_mfma_f32_16x16x32_bf16(a, b1, acc[mi][1], 0, 0, 0);
            }
        }
        __syncthreads();
    }
    int lm = m0 + wm0 + (lane >> 4) * 4;
    int lc = n0 + wn0 + (lane & 15);
    #pragma unroll
    for (int mi = 0; mi < 4; mi++) {
        #pragma unroll
        for (int ni = 0; ni < 2; ni++) {
            int col = lc + ni * 16;
            if (col >= nst) continue;
            float bv = (bias != nullptr && col < Nv) ? bias[col] : 0.f;
            #pragma unroll
            for (int r = 0; r < 4; r++) {
                int row = lm + mi * 16 + r;
                if (row >= M) continue;
                float v = acc[mi][ni][r] + bv;
                if (act) v = fmaxf(v, 0.f);
                if (col >= Nv) v = 0.f;
                if (bf16out) ((ushort_t*)C)[(size_t)row * ldc + col] = f2bf(v);
                else         ((float*)C)[(size_t)row * ldc + col] = v;
            }
        }
    }
}

// ---------------- GAT aggregate on x (bf16, L2-resident), head-stride-36 Z layout ----------------
// 128-thread blocks (2 waves) to cut degree-imbalance waste; edge loop unrolled x4
__global__ __launch_bounds__(128) void k_gat_agg(const ushort_t* __restrict__ xfb, const float* __restrict__ a_s,
                                                 const float* __restrict__ a_d,
                                                 const int* __restrict__ csr_src,
                                                 const int* __restrict__ offs, const int* __restrict__ deg,
                                                 ushort_t* __restrict__ Zb, float* __restrict__ denArr) {
    int wid = blockIdx.x * 2 + (threadIdx.x >> 6);
    int lane = threadIdx.x & 63;
    if (wid >= NN) return;
    int o0 = offs[wid], d = deg[wid];
    bool mine = (lane < NHEAD);
    float adv = mine ? a_d[wid * NHEAD + lane] : 0.f;
    int h1 = lane / 18,          c1 = lane % 18;
    int h2 = (lane + 64) / 18,   c2 = (lane + 64) % 18;
    bool g3 = lane < 52;
    int h3 = g3 ? (lane + 128) / 18 : 0;
    int c3 = g3 ? (lane + 128) % 18 : 0;
    float den = 0.f;
    float a1l = 0.f, a1h = 0.f, a2l = 0.f, a2h = 0.f, a3l = 0.f, a3h = 0.f;
    const unsigned* x32 = (const unsigned*)xfb;
    int i = 0;
    for (; i + 4 <= d; i += 4) {
        int s0 = csr_src[o0 + i],     s1 = csr_src[o0 + i + 1];
        int s2 = csr_src[o0 + i + 2], s3 = csr_src[o0 + i + 3];
        const unsigned* x0 = x32 + (size_t)s0 * 20;
        const unsigned* x1 = x32 + (size_t)s1 * 20;
        const unsigned* x2 = x32 + (size_t)s2 * 20;
        const unsigned* x3 = x32 + (size_t)s3 * 20;
        float as0 = mine ? a_s[s0 * NHEAD + lane] : 0.f;
        float as1 = mine ? a_s[s1 * NHEAD + lane] : 0.f;
        float as2 = mine ? a_s[s2 * NHEAD + lane] : 0.f;
        float as3 = mine ? a_s[s3 * NHEAD + lane] : 0.f;
        unsigned u01 = x0[c1], u02 = x0[c2], u03 = x0[c3];
        unsigned u11 = x1[c1], u12 = x1[c2], u13 = x1[c3];
        unsigned u21 = x2[c1], u22 = x2[c2], u23 = x2[c3];
        unsigned u31 = x3[c1], u32 = x3[c2], u33 = x3[c3];
        float ex0 = __expf(lrelu(as0 + adv));
        float ex1 = __expf(lrelu(as1 + adv));
        float ex2 = __expf(lrelu(as2 + adv));
        float ex3 = __expf(lrelu(as3 + adv));
        den += (ex0 + ex1) + (ex2 + ex3);
        float e01 = __shfl(ex0, h1), e02 = __shfl(ex0, h2), e03 = __shfl(ex0, h3);
        float e11 = __shfl(ex1, h1), e12 = __shfl(ex1, h2), e13 = __shfl(ex1, h3);
        float e21 = __shfl(ex2, h1), e22 = __shfl(ex2, h2), e23 = __shfl(ex2, h3);
        float e31 = __shfl(ex3, h1), e32 = __shfl(ex3, h2), e33 = __shfl(ex3, h3);
        a1l += e01 * bflo(u01) + e11 * bflo(u11) + e21 * bflo(u21) + e31 * bflo(u31);
        a1h += e01 * bfhi(u01) + e11 * bfhi(u11) + e21 * bfhi(u21) + e31 * bfhi(u31);
        a2l += e02 * bflo(u02) + e12 * bflo(u12) + e22 * bflo(u22) + e32 * bflo(u32);
        a2h += e02 * bfhi(u02) + e12 * bfhi(u12) + e22 * bfhi(u22) + e32 * bfhi(u32);
        a3l += e03 * bflo(u03) + e13 * bflo(u13) + e23 * bflo(u23) + e33 * bflo(u33);
        a3h += e03 * bfhi(u03) + e13 * bfhi(u13) + e23 * bfhi(u23) + e33 * bfhi(u33);
    }
    for (; i < d; i++) {
        int s = csr_src[o0 + i];
        const unsigned* x0 = x32 + (size_t)s * 20;
        float as0 = mine ? a_s[s * NHEAD + lane] : 0.f;
        unsigned u01 = x0[c1], u02 = x0[c2], u03 = x0[c3];
        float ex0 = __expf(lrelu(as0 + adv));
        den += ex0;
        float e01 = __shfl(ex0, h1), e02 = __shfl(ex0, h2), e03 = __shfl(ex0, h3);
        a1l += e01 * bflo(u01);  a1h += e01 * bfhi(u01);
        a2l += e02 * bflo(u02);  a2h += e02 * bfhi(u02);
        a3l += e03 * bflo(u03);  a3h += e03 * bfhi(u03);
    }
    float rden = 1.f / (den + 1e-16f);
    if (mine) denArr[wid * NHEAD + lane] = den;
    float r1 = __shfl(rden, h1), r2 = __shfl(rden, h2), r3 = __shfl(rden, h3);
    unsigned* zr = (unsigned*)(Zb + (size_t)wid * KPAD);
    __builtin_nontemporal_store(packbf(a1l * r1, a1h * r1), &zr[lane]);
    __builtin_nontemporal_store(packbf(a2l * r2, a2h * r2), &zr[lane + 64]);
    __builtin_nontemporal_store(g3 ? packbf(a3l * r3, a3h * r3) : 0u, &zr[lane + 128]);
}

// ---------------- alpha in original edge order (coalesced writes; inputs L2-resident) ----------------
__global__ __launch_bounds__(256) void k_alpha(const int* __restrict__ ei, const float* __restrict__ a_s,
                                               const float* __restrict__ a_d, const float* __restrict__ den,
                                               float* __restrict__ alphaOut) {
    int i = blockIdx.x * 256 + threadIdx.x;
    if (i >= ETOT * NHEAD) return;
    int e = i / NHEAD, hd = i % NHEAD;
    int s, dst;
    if (e < EE) { s = ei[e]; dst = ei[EE + e]; }
    else { s = dst = e - EE; }
    float ex = __expf(lrelu(a_s[s * NHEAD + hd] + a_d[dst * NHEAD + hd]));
    __builtin_nontemporal_store(ex / (den[dst * NHEAD + hd] + 1e-16f), &alphaOut[i]);
}

// ---------------- GCN aggregate: 2-wave blocks, x4 unroll, bf16 packed output ----------------
__global__ __launch_bounds__(128) void k_gcn_agg(const ushort_t* __restrict__ h2b,
                                                 const int* __restrict__ csr_src,
                                                 const int* __restrict__ offs, const int* __restrict__ deg,
                                                 const float* __restrict__ dinv, const float* __restrict__ b_gcn,
                                                 ushort_t* __restrict__ xg2b) {
    int wid = blockIdx.x * 2 + (threadIdx.x >> 6);
    int lane = threadIdx.x & 63;
    if (wid >= NN) return;
    int o0 = offs[wid], d = deg[wid];
    float wv = dinv[wid];
    bool g3 = lane < 48;                      // third h2 u32 group valid (w = lane+128 < 176)
    int w3 = g3 ? (lane + 128) : 0;
    float aL0 = 0.f, aH0 = 0.f, aL1 = 0.f, aH1 = 0.f, aL2 = 0.f, aH2 = 0.f;
    const unsigned* h32 = (const unsigned*)h2b;
    int i = 0;
    for (; i + 4 <= d; i += 4) {
        int s0 = csr_src[o0 + i],     s1 = csr_src[o0 + i + 1];
        int s2 = csr_src[o0 + i + 2], s3 = csr_src[o0 + i + 3];
        float q0 = dinv[s0], q1 = dinv[s1], q2 = dinv[s2], q3 = dinv[s3];
        const unsigned* h0 = h32 + (size_t)s0 * (LDH2 / 2);
        const unsigned* h1 = h32 + (size_t)s1 * (LDH2 / 2);
        const unsigned* h2 = h32 + (size_t)s2 * (LDH2 / 2);
        const unsigned* h3 = h32 + (size_t)s3 * (LDH2 / 2);
        unsigned u00 = h0[lane], u01 = h0[lane + 64], u02 = h0[w3];
        unsigned u10 = h1[lane], u11 = h1[lane + 64], u12 = h1[w3];
        unsigned u20 = h2[lane], u21 = h2[lane + 64], u22 = h2[w3];
        unsigned u30 = h3[lane], u31 = h3[lane + 64], u32 = h3[w3];
        aL0 += q0 * bflo(u00) + q1 * bflo(u10) + q2 * bflo(u20) + q3 * bflo(u30);
        aH0 += q0 * bfhi(u00) + q1 * bfhi(u10) + q2 * bfhi(u20) + q3 * bfhi(u30);
        aL1 += q0 * bflo(u01) + q1 * bflo(u11) + q2 * bflo(u21) + q3 * bflo(u31);
        aH1 += q0 * bfhi(u01) + q1 * bfhi(u11) + q2 * bfhi(u21) + q3 * bfhi(u31);
        aL2 += q0 * bflo(u02) + q1 * bflo(u12) + q2 * bflo(u22) + q3 * bflo(u32);
        aH2 += q0 * bfhi(u02) + q1 * bfhi(u12) + q2 * bfhi(u22) + q3 * bfhi(u32);
    }
    for (; i < d; i++) {
        int s = csr_src[o0 + i];
        float ws = dinv[s];
        const unsigned* hr = h32 + (size_t)s * (LDH2 / 2);
        unsigned u0 = hr[lane], u1 = hr[lane + 64], u2 = hr[w3];
        aL0 += ws * bflo(u0);  aH0 += ws * bfhi(u0);
        aL1 += ws * bflo(u1);  aH1 += ws * bfhi(u1);
        aL2 += ws * bflo(u2);  aH2 += ws * bfhi(u2);
    }
    // packed bf16 output: row = 350 ushorts (175 u32 words); word w covers features 2w,2w+1
    unsigned* orow = (unsigned*)(xg2b + (size_t)wid * FG);
    {
        int f = 2 * lane;
        __builtin_nontemporal_store(packbf(fmaxf(wv * aL0 + b_gcn[f], 0.f),
                                           fmaxf(wv * aH0 + b_gcn[f + 1], 0.f)), &orow[lane]);
    }
    {
        int f = 128 + 2 * lane;
        __builtin_nontemporal_store(packbf(fmaxf(wv * aL1 + b_gcn[f], 0.f),
                                           fmaxf(wv * aH1 + b_gcn[f + 1], 0.f)), &orow[64 + lane]);
    }
    if (lane < 47) {
        int f = 256 + 2 * lane;
        __builtin_nontemporal_store(packbf(fmaxf(wv * aL2 + b_gcn[f], 0.f),
                                           fmaxf(wv * aH2 + b_gcn[f + 1], 0.f)), &orow[128 + lane]);
    }
}

// ---------------- per-graph max+mean pool (bf16 input, u32-word per thread) ----------------
__device__ __forceinline__ int lowerB(const int* a, int n, int key) {
    int lo = 0, hi = n;
    while (lo < hi) { int mid = (lo + hi) >> 1; if (a[mid] < key) lo = mid + 1; else hi = mid; }
    return lo;
}

__global__ __launch_bounds__(256) void k_pool(const ushort_t* __restrict__ xg2b, const int* __restrict__ batch,
                                              float* __restrict__ pooled) {
    int g = blockIdx.x;
    int w = threadIdx.x;
    if (w >= 175) return;
    int s = lowerB(batch, NN, g);
    int e = lowerB(batch, NN, g + 1);
    const unsigned* base = (const unsigned*)xg2b;
    float mx0 = -INFINITY, mx1 = -INFINITY, sm0 = 0.f, sm1 = 0.f;
    int n = s;
    for (; n + 2 <= e; n += 2) {
        unsigned ua = base[(size_t)n * 175 + w];
        unsigned ub = base[(size_t)(n + 1) * 175 + w];
        float a0 = bflo(ua), a1 = bfhi(ua), b0 = bflo(ub), b1 = bfhi(ub);
        mx0 = fmaxf(mx0, fmaxf(a0, b0));
        mx1 = fmaxf(mx1, fmaxf(a1, b1));
        sm0 += a0 + b0;
        sm1 += a1 + b1;
    }
    for (; n < e; n++) {
        unsigned ua = base[(size_t)n * 175 + w];
        float a0 = bflo(ua), a1 = bfhi(ua);
        mx0 = fmaxf(mx0, a0);
        mx1 = fmaxf(mx1, a1);
        sm0 += a0;
        sm1 += a1;
    }
    float rc = 1.f / fmaxf((float)(e - s), 1.f);
    pooled[g * 700 + 2 * w]       = mx0;
    pooled[g * 700 + 2 * w + 1]   = mx1;
    pooled[g * 700 + FG + 2 * w]     = sm0 * rc;
    pooled[g * 700 + FG + 2 * w + 1] = sm1 * rc;
}

// ---------------- protein conv branch: LDS-resident, 2 proteins per block ----------------
__global__ __launch_bounds__(256) void k_conv(const int* __restrict__ target, const float* __restrict__ emb,
                                              const float* __restrict__ Wc, const float* __restrict__ bc,
                                              float* __restrict__ xt) {
    __shared__ float embL[26 * 132];        // rows padded to 132 floats
    __shared__ float WL[16 * 8 * 128];      // WL[f][k][e] = Wc[f][e][k]
    __shared__ int   tgL[2 * LL];
    int tid = threadIdx.x;
    int b0 = blockIdx.x * 2;
    for (int i = tid; i < 26 * 128; i += 256) {
        int r = i >> 7, e = i & 127;
        embL[r * 132 + e] = emb[i];
    }
    for (int i = tid; i < 16384; i += 256) {
        int f = i >> 10, rem = i & 1023, k = rem >> 7, e = rem & 127;
        WL[i] = Wc[f * 1024 + e * 8 + k];
    }
    if (tid < 2 * LL) tgL[tid] = target[b0 * LL + tid];
    __syncthreads();
    #pragma unroll
    for (int pass = 0; pass < 2; pass++) {
        int r = tid + pass * 256;
        if (r >= 280) break;
        int bl = r / 140, rem = r % 140;
        int fq = rem / 35, t = rem % 35;
        const int* tg = &tgL[bl * LL];
        float ac0 = 0.f, ac1 = 0.f, ac2 = 0.f, ac3 = 0.f;
        for (int k = 0; k < 8; k++) {
            const float* er = &embL[tg[t + k] * 132];
            const float* w0 = &WL[((fq * 4 + 0) * 8 + k) * 128];
            const float* w1 = &WL[((fq * 4 + 1) * 8 + k) * 128];
            const float* w2 = &WL[((fq * 4 + 2) * 8 + k) * 128];
            const float* w3 = &WL[((fq * 4 + 3) * 8 + k) * 128];
            #pragma unroll 8
            for (int e = 0; e < 128; e += 4) {
                float4 a = *(const float4*)&er[e];
                float4 q0 = *(const float4*)&w0[e];
                float4 q1 = *(const float4*)&w1[e];
                float4 q2 = *(const float4*)&w2[e];
                float4 q3 = *(const float4*)&w3[e];
                ac0 += a.x * q0.x + a.y * q0.y + a.z * q0.z + a.w * q0.w;
                ac1 += a.x * q1.x + a.y * q1.y + a.z * q1.z + a.w * q1.w;
                ac2 += a.x * q2.x + a.y * q2.y + a.z * q2.z + a.w * q2.w;
                ac3 += a.x * q3.x + a.y * q3.y + a.z * q3.z + a.w * q3.w;
            }
        }
        int b = b0 + bl, fb = fq * 4;
        xt[b * 560 + (fb + 0) * 35 + t] = ac0 + bc[fb + 0];
        xt[b * 560 + (fb + 1) * 35 + t] = ac1 + bc[fb + 1];
        xt[b * 560 + (fb + 2) * 35 + t] = ac2 + bc[fb + 2];
        xt[b * 560 + (fb + 3) * 35 + t] = ac3 + bc[fb + 3];
    }
}

// ---------------- final dot + sigmoid ----------------
__global__ __launch_bounds__(256) void k_out(const float* __restrict__ f1, const float* __restrict__ W_out,
                                             const float* __restrict__ b_out, float* __restrict__ out) {
    int wid = (blockIdx.x * blockDim.x + threadIdx.x) >> 6;
    int lane = threadIdx.x & 63;
    if (wid >= BB) return;
    const float* xr = f1 + (size_t)wid * 512;
    float acc = 0.f;
    #pragma unroll
    for (int k = 0; k < 8; k++) acc += xr[lane + k * 64] * W_out[lane + k * 64];
    #pragma unroll
    for (int d = 32; d; d >>= 1) acc += __shfl_xor(acc, d);
    if (lane == 0) out[wid] = 1.f / (1.f + __expf(-(acc + b_out[0])));
}

// ---------------- host launcher ----------------
extern "C" void kernel_launch(void* const* d_in, const int* in_sizes, int n_in,
                              void* d_out, int out_size, void* d_ws, size_t ws_size,
                              hipStream_t stream) {
    const float* x      = (const float*)d_in[0];
    const int*   ei     = (const int*)d_in[1];
    const int*   batch  = (const int*)d_in[2];
    const int*   target = (const int*)d_in[3];
    const float* W_gat  = (const float*)d_in[4];
    const float* att_s  = (const float*)d_in[5];
    const float* att_d  = (const float*)d_in[6];
    const float* b_gat  = (const float*)d_in[7];
    const float* W_gcn  = (const float*)d_in[8];
    const float* b_gcn  = (const float*)d_in[9];
    const float* W_fcg1 = (const float*)d_in[10];
    const float* b_fcg1 = (const float*)d_in[11];
    const float* W_fcg2 = (const float*)d_in[12];
    const float* b_fcg2 = (const float*)d_in[13];
    const float* embxt  = (const float*)d_in[14];
    const float* W_conv = (const float*)d_in[15];
    const float* b_conv = (const float*)d_in[16];
    const float* W_fcxt = (const float*)d_in[17];
    const float* b_fcxt = (const float*)d_in[18];
    const float* W_fc1  = (const float*)d_in[19];
    const float* b_fc1  = (const float*)d_in[20];
    const float* W_out  = (const float*)d_in[21];
    const float* b_out  = (const float*)d_in[22];

    float* out_sig  = (float*)d_out;          // [500]
    float* alphaOut = (float*)d_out + BB;     // [850000 * 10]

    size_t o = 0;
    auto alloc = [&](size_t bytes) -> void* {
        o = (o + 255) & ~(size_t)255;
        void* p = (char*)d_ws + o;
        o += bytes;
        return p;
    };
    int*   deg     = (int*)alloc((size_t)NN * 4);
    int*   cur     = (int*)alloc((size_t)NN * 4);
    int*   offs    = (int*)alloc((size_t)NN * 4);
    int*   part    = (int*)alloc(128 * 4);
    int*   pscan   = (int*)alloc(128 * 4);
    int*   csr_src = (int*)alloc((size_t)ETOT * 4);
    float* dinv    = (float*)alloc((size_t)NN * 4);
    float* a_s     = (float*)alloc((size_t)NN * NHEAD * 4);
    float* a_d     = (float*)alloc((size_t)NN * NHEAD * 4);
    float* denArr  = (float*)alloc((size_t)NN * NHEAD * 4);
    ushort_t* xfb  = (ushort_t*)alloc((size_t)NN * 40 * 2);       // bf16 x rows (4 MB, L2-resident)
    float* wS      = (float*)alloc((size_t)FG * 4);
    float* wD      = (float*)alloc((size_t)FG * 4);
    ushort_t* WtBD = (ushort_t*)alloc((size_t)KPAD * KPAD * 2);   // block-diag W_gat^T (stride-36 K)
    ushort_t* WtGC = (ushort_t*)alloc((size_t)KPAD * KPAD * 2);
    ushort_t* WtF1 = (ushort_t*)alloc((size_t)1536 * 704 * 2);
    ushort_t* WtF2 = (ushort_t*)alloc((size_t)128 * 1536 * 2);
    ushort_t* WtFX = (ushort_t*)alloc((size_t)128 * 576 * 2);
    ushort_t* WtFC = (ushort_t*)alloc((size_t)512 * 256 * 2);
    float* pooled  = (float*)alloc((size_t)BB * 700 * 4);
    ushort_t* pooledb = (ushort_t*)alloc((size_t)MB2 * 704 * 2);
    ushort_t* t1b  = (ushort_t*)alloc((size_t)MB2 * 1536 * 2);
    float* xt      = (float*)alloc((size_t)BB * 560 * 4);
    ushort_t* xtb  = (ushort_t*)alloc((size_t)MB2 * 576 * 2);
    ushort_t* xcb  = (ushort_t*)alloc((size_t)MB2 * 256 * 2);
    float* f1      = (float*)alloc((size_t)MB2 * 512 * 4);
    ushort_t* hb   = (ushort_t*)alloc((size_t)MPAD * KPAD * 2);   // Z (GAT agg), later h2 (ld 352)
    char*  R2      = (char*)alloc((size_t)NN * FG * 4);           // aliased region
    ushort_t* xg1b = (ushort_t*)R2;                               // [MPAD][KPAD] bf16 (38.4 MB)
    ushort_t* xg2b = (ushort_t*)R2;                               // [NN][350] bf16, after xg1b dead
    (void)ws_size; (void)n_in; (void)in_sizes; (void)out_size;

    auto mfma = [&](const ushort_t* A, const ushort_t* Bt, void* C, const float* bias,
                    int M2, int Nv, int NP, int ldc, int KP, int act, int bf16out, int bdiag, int nst) {
        dim3 g(NP / 64, M2 / 128);
        k_mfma<<<g, 256, 0, stream>>>(A, Bt, C, M2, Nv, ldc, KP, KP / 64, bias, act, bf16out, bdiag, nst);
    };

    // graph prep
    k_init<<<(NN + 255) / 256, 256, 0, stream>>>(deg, cur);
    k_deg<<<(EE + 255) / 256, 256, 0, stream>>>(ei, deg);
    k_scan1<<<NCHUNK, 512, 0, stream>>>(deg, part);
    k_scan2<<<1, 64, 0, stream>>>(part, pscan);
    k_scan3<<<NCHUNK, 512, 0, stream>>>(deg, pscan, offs);
    k_scatter<<<(ETOT + 255) / 256, 256, 0, stream>>>(ei, offs, cur, csr_src);
    k_dinv<<<(NN + 255) / 256, 256, 0, stream>>>(deg, dinv);

    // prep (fused attention weights -> fused node prep; block-diag W_gat, W_gcn, FC weights)
    k_prep_att<<<2, 256, 0, stream>>>(W_gat, att_s, att_d, wS, wD);
    k_prep_node<<<(NN + 255) / 256, 256, 0, stream>>>(x, wS, wD, xfb, a_s, a_d);
    k_prep_wbd<<<(KPAD * KPAD + 255) / 256, 256, 0, stream>>>(W_gat, WtBD);
    k_prep_wgcn<<<(KPAD * KPAD + 255) / 256, 256, 0, stream>>>(W_gcn, WtGC);
    k_prep_w<<<(704 * 1536 + 255) / 256, 256, 0, stream>>>(W_fcg1, WtF1, 700, 1500, 704, 1536);
    k_prep_w<<<(1536 * 128 + 255) / 256, 256, 0, stream>>>(W_fcg2, WtF2, 1500, 128, 1536, 128);
    k_prep_w<<<(576 * 128 + 255) / 256, 256, 0, stream>>>(W_fcxt, WtFX, 560, 128, 576, 128);
    k_prep_w<<<(256 * 512 + 255) / 256, 256, 0, stream>>>(W_fc1, WtFC, 256, 512, 256, 512);
    k_zero_tail<<<((MPAD - NN) * KPAD + 255) / 256, 256, 0, stream>>>(hb);   // Z tail rows

    // GAT: aggregate x (stride-36 Z) -> alpha -> block-diag GEMM
    k_gat_agg<<<(NN + 1) / 2, 128, 0, stream>>>(xfb, a_s, a_d, csr_src, offs, deg, hb, denArr);   // Z -> hb
    k_alpha<<<(ETOT * NHEAD + 255) / 256, 256, 0, stream>>>(ei, a_s, a_d, denArr, alphaOut);
    mfma(hb, WtBD, xg1b, b_gat, MPAD, FG, KPAD, KPAD, KPAD, 1, 1, 1, KPAD);  // xg1 = relu(Z@W_bd+b)

    // GCN: h2 = xg1 @ W_gcn (overwrites hb, row stride 352), then aggregate (bf16 out)
    mfma(xg1b, WtGC, hb, nullptr, MPAD, FG, KPAD, LDH2, KPAD, 0, 1, 0, LDH2);
    k_gcn_agg<<<(NN + 1) / 2, 128, 0, stream>>>(hb, csr_src, offs, deg, dinv, b_gcn, xg2b);

    // pool + FC stacks (all FC layers via bf16 MFMA)
    k_pool<<<BB, 256, 0, stream>>>(xg2b, batch, pooled);
    k_cast_pad<<<(MB2 * 704 + 255) / 256, 256, 0, stream>>>(pooled, pooledb, BB, 700, MB2, 704);
    mfma(pooledb, WtF1, t1b, b_fcg1, MB2, 1500, 1536, 1536, 704, 1, 1, 0, 1536);
    mfma(t1b, WtF2, xcb, b_fcg2, MB2, 128, 128, 256, 1536, 0, 1, 0, 128);
    k_conv<<<250, 256, 0, stream>>>(target, embxt, W_conv, b_conv, xt);
    k_cast_pad<<<(MB2 * 576 + 255) / 256, 256, 0, stream>>>(xt, xtb, BB, 560, MB2, 576);
    mfma(xtb, WtFX, xcb + 128, b_fcxt, MB2, 128, 128, 256, 576, 0, 1, 0, 128);
    mfma(xcb, WtFC, f1, b_fc1, MB2, 512, 512, 512, 256, 1, 0, 0, 512);
    k_out<<<(BB + 3) / 4, 256, 0, stream>>>(f1, W_out, b_out, out_sig);
}

// Round 11
// 575.978 us; speedup vs baseline: 1.1207x; 1.0120x over previous
//
#include <hip/hip_runtime.h>
#include <math.h>

#define NN 50000
#define EE 800000
#define BB 500
#define LL 42
#define NHEAD 10
#define FH 35
#define FG 350
#define ETOT (EE + NN)
#define NCHUNK ((NN + 511) / 512)

#define KPAD 384         // bf16 row stride for Z / xg1
#define LDH2 352         // bf16 row stride for h2 (tight)
#define MPAD 50048       // M padded to multiple of 128
#define MB2  512         // padded batch rows for FC MFMA
#define NDW  24          // nd row width in u32 words (48 ushorts = 96 B)

typedef unsigned short ushort_t;
typedef __attribute__((ext_vector_type(8))) short short8v;
typedef __attribute__((ext_vector_type(4))) float float4v;

__device__ __forceinline__ float lrelu(float x) { return x > 0.f ? x : 0.2f * x; }

__device__ __forceinline__ ushort_t f2bf(float f) {
    unsigned int u = __float_as_uint(f);
    u += 0x7fffu + ((u >> 16) & 1u);      // round-to-nearest-even
    return (ushort_t)(u >> 16);
}
__device__ __forceinline__ float bflo(unsigned u) { return __uint_as_float(u << 16); }
__device__ __forceinline__ float bfhi(unsigned u) { return __uint_as_float(u & 0xffff0000u); }
__device__ __forceinline__ float bfu(ushort_t u) { return __uint_as_float(((unsigned)u) << 16); }
__device__ __forceinline__ unsigned packbf(float a, float b) {
    return (unsigned)f2bf(a) | ((unsigned)f2bf(b) << 16);
}

__device__ __forceinline__ void async_cp16(const void* g, void* l) {
    __builtin_amdgcn_global_load_lds((const __attribute__((address_space(1))) unsigned int*)g,
                                     (__attribute__((address_space(3))) unsigned int*)l, 16, 0, 0);
}

// ---------------- graph prep ----------------
__global__ __launch_bounds__(256) void k_init(int* deg, int* cur) {
    int i = blockIdx.x * 256 + threadIdx.x;
    if (i < NN) { deg[i] = 1; cur[i] = 0; }   // deg=1 accounts for the self-loop
}

__global__ __launch_bounds__(256) void k_deg(const int* __restrict__ ei, int* deg) {
    int i = blockIdx.x * 256 + threadIdx.x;
    if (i < EE) atomicAdd(&deg[ei[EE + i]], 1);
}

__global__ __launch_bounds__(512) void k_scan1(const int* __restrict__ deg, int* part) {
    int i = blockIdx.x * 512 + threadIdx.x;
    int lane = threadIdx.x & 63, wv = threadIdx.x >> 6;
    int x = (i < NN) ? deg[i] : 0;
    #pragma unroll
    for (int d = 32; d; d >>= 1) x += __shfl_xor(x, d);
    __shared__ int wsum[8];
    if (lane == 0) wsum[wv] = x;
    __syncthreads();
    if (threadIdx.x == 0) {
        int s = 0;
        #pragma unroll
        for (int w = 0; w < 8; w++) s += wsum[w];
        part[blockIdx.x] = s;
    }
}

__global__ __launch_bounds__(64) void k_scan2(const int* __restrict__ part, int* pscan) {
    int l = threadIdx.x;
    int v0 = (l < NCHUNK) ? part[l] : 0;
    #pragma unroll
    for (int d = 1; d < 64; d <<= 1) { int t = __shfl_up(v0, d); if (l >= d) v0 += t; }
    int tot0 = __shfl(v0, 63);
    int v1 = (64 + l < NCHUNK) ? part[64 + l] : 0;
    #pragma unroll
    for (int d = 1; d < 64; d <<= 1) { int t = __shfl_up(v1, d); if (l >= d) v1 += t; }
    v1 += tot0;
    if (l < NCHUNK) pscan[l] = v0;
    if (64 + l < NCHUNK) pscan[64 + l] = v1;
}

__global__ __launch_bounds__(512) void k_scan3(const int* __restrict__ deg, const int* __restrict__ pscan,
                                               int* offs, float* dinv) {
    int i = blockIdx.x * 512 + threadIdx.x;
    int lane = threadIdx.x & 63, wv = threadIdx.x >> 6;
    int x = (i < NN) ? deg[i] : 0;
    int incl = x;
    #pragma unroll
    for (int d = 1; d < 64; d <<= 1) { int t = __shfl_up(incl, d); if (lane >= d) incl += t; }
    __shared__ int wtot[8];
    if (lane == 63) wtot[wv] = incl;
    __syncthreads();
    int woff = 0;
    for (int w = 0; w < wv; w++) woff += wtot[w];
    int base = (blockIdx.x == 0) ? 0 : pscan[blockIdx.x - 1];
    if (i < NN) {
        offs[i] = base + woff + incl - x;   // exclusive prefix
        dinv[i] = rsqrtf((float)x);
    }
}

__global__ __launch_bounds__(256) void k_scatter(const int* __restrict__ ei, const int* __restrict__ offs,
                                                 int* cur, int* csr_src) {
    int i = blockIdx.x * 256 + threadIdx.x;
    if (i < EE) {
        int s = ei[i], d = ei[EE + i];
        int slot = atomicAdd(&cur[d], 1);
        csr_src[offs[d] + slot] = s;
    } else if (i < ETOT) {
        int v = i - EE;
        int slot = atomicAdd(&cur[v], 1);
        csr_src[offs[v] + slot] = v;
    }
}

// ---------------- prep kernels ----------------
// w~_s[hd,c] = sum_cc W_gat[c, hd*35+cc] * att_s[hd,cc]  (and same for d)
__global__ __launch_bounds__(256) void k_prep_att(const float* __restrict__ W_gat, const float* __restrict__ att_s,
                                                  const float* __restrict__ att_d,
                                                  float* __restrict__ wS, float* __restrict__ wD) {
    int i = blockIdx.x * 256 + threadIdx.x;
    if (i >= FG) return;
    int hd = i / 35, c = i % 35;
    float ss = 0.f, dd = 0.f;
    for (int cc = 0; cc < 35; cc++) {
        float w = W_gat[c * FG + hd * 35 + cc];
        ss += w * att_s[hd * 35 + cc];
        dd += w * att_d[hd * 35 + cc];
    }
    wS[i] = ss;
    wD[i] = dd;
}

// fused node prep: nd[n] = 48 ushorts {x bf16 pairs [w0..17], a_s bf16 pairs [w18..22], 0 [w23]}
// plus f32 a_s/a_d arrays (for k_alpha numerator + gat_agg adv)
__global__ __launch_bounds__(256) void k_prep_node(const float* __restrict__ x, const float* __restrict__ wS,
                                                   const float* __restrict__ wD, ushort_t* __restrict__ nd,
                                                   float* __restrict__ a_s, float* __restrict__ a_d) {
    __shared__ float sw[FG], dw[FG];
    int tid = threadIdx.x;
    for (int i = tid; i < FG; i += 256) { sw[i] = wS[i]; dw[i] = wD[i]; }
    __syncthreads();
    int n = blockIdx.x * 256 + tid;
    if (n >= NN) return;
    float xr[35];
    #pragma unroll
    for (int c = 0; c < 35; c++) xr[c] = x[(size_t)n * 35 + c];
    unsigned* xo = (unsigned*)(nd + (size_t)n * (2 * NDW));
    #pragma unroll
    for (int w = 0; w < 17; w++) xo[w] = packbf(xr[2 * w], xr[2 * w + 1]);
    xo[17] = packbf(xr[34], 0.f);
    float asv[NHEAD];
    #pragma unroll
    for (int hd = 0; hd < NHEAD; hd++) {
        const float* ws = &sw[hd * 35];
        const float* wd = &dw[hd * 35];
        float as = 0.f, ad = 0.f;
        #pragma unroll
        for (int c = 0; c < 35; c++) { float v = xr[c]; as += v * ws[c]; ad += v * wd[c]; }
        asv[hd] = as;
        a_s[n * NHEAD + hd] = as;
        a_d[n * NHEAD + hd] = ad;
    }
    #pragma unroll
    for (int j = 0; j < 5; j++) xo[18 + j] = packbf(asv[2 * j], asv[2 * j + 1]);
    xo[23] = 0u;
}

// merged weight prep: block-diag W_gat (stride-36 K), W_gcn^T, and 4 FC weights -> padded bf16
__global__ __launch_bounds__(256) void k_prep_weights(
    const float* __restrict__ Wg, const float* __restrict__ Wc,
    const float* __restrict__ W1, const float* __restrict__ W2,
    const float* __restrict__ WX, const float* __restrict__ WF,
    ushort_t* __restrict__ BD, ushort_t* __restrict__ GC,
    ushort_t* __restrict__ F1, ushort_t* __restrict__ F2,
    ushort_t* __restrict__ FX, ushort_t* __restrict__ FC) {
    int i = blockIdx.x * 256 + threadIdx.x;
    if (i < KPAD * KPAD) {                    // block-diag W_gat, k = hd*36+cc
        int n = i / KPAD, k = i % KPAD;
        int hd = k / 36, cc = k % 36;
        float v = 0.f;
        if (n < FG && cc < 35 && hd == n / 35) v = Wg[cc * FG + n];
        BD[i] = f2bf(v);
        return;
    }
    i -= KPAD * KPAD;
    if (i < KPAD * KPAD) {                    // W_gcn^T
        int n = i / KPAD, k = i % KPAD;
        float v = (n < FG && k < FG) ? Wc[k * FG + n] : 0.f;
        GC[i] = f2bf(v);
        return;
    }
    i -= KPAD * KPAD;
    if (i < 704 * 1536) {                     // W_fcg1^T [1536][704]
        int k = i / 1536, n = i % 1536;
        float v = (k < 700 && n < 1500) ? W1[(size_t)k * 1500 + n] : 0.f;
        F1[(size_t)n * 704 + k] = f2bf(v);
        return;
    }
    i -= 704 * 1536;
    if (i < 1536 * 128) {                     // W_fcg2^T [128][1536]
        int k = i / 128, n = i % 128;
        float v = (k < 1500) ? W2[(size_t)k * 128 + n] : 0.f;
        F2[(size_t)n * 1536 + k] = f2bf(v);
        return;
    }
    i -= 1536 * 128;
    if (i < 576 * 128) {                      // W_fcxt^T [128][576]
        int k = i / 128, n = i % 128;
        float v = (k < 560) ? WX[(size_t)k * 128 + n] : 0.f;
        FX[(size_t)n * 576 + k] = f2bf(v);
        return;
    }
    i -= 576 * 128;
    if (i < 256 * 512) {                      // W_fc1^T [512][256]
        int k = i / 512, n = i % 512;
        FC[(size_t)n * 256 + k] = f2bf(WF[(size_t)k * 512 + n]);
    }
}
#define PREPW_TOTAL (KPAD * KPAD * 2 + 704 * 1536 + 1536 * 128 + 576 * 128 + 256 * 512)

// generic: dst[r*KP+k] = bf16(src[r*K+k]), zero-padded
__global__ __launch_bounds__(256) void k_cast_pad(const float* __restrict__ src, ushort_t* __restrict__ dst,
                                                  int M, int K, int MP, int KP) {
    int i = blockIdx.x * 256 + threadIdx.x;
    if (i >= MP * KP) return;
    int r = i / KP, k = i % KP;
    dst[i] = (r < M && k < K) ? f2bf(src[(size_t)r * K + k]) : (ushort_t)0;
}

// ---------------- bf16 MFMA GEMM: C = act(A[Mp,lda] @ Bt[Np,lda] + bias) ----------------
// tile 128x64, BK=64, 4 waves 2x2. bdiag=1: K-window (head-stride-36) limited per col-tile.
// nst: store-column clamp (cols >= nst not written; cols in [Nv, nst) written as 0)
__global__ __launch_bounds__(256) void k_mfma(const ushort_t* __restrict__ A, const ushort_t* __restrict__ Bt,
                                              void* __restrict__ C, int M, int Nv, int ldc, int lda,
                                              int ksteps, const float* __restrict__ bias, int act, int bf16out,
                                              int bdiag, int nst) {
    __shared__ ushort_t As[128 * 64];
    __shared__ ushort_t Bs[64 * 64];
    int tid = threadIdx.x;
    int wid = tid >> 6, lane = tid & 63;
    int m0 = blockIdx.y * 128, n0 = blockIdx.x * 64;
    int wm0 = (wid >> 1) * 64, wn0 = (wid & 1) * 32;
    int srow = tid >> 3;              // staging: 8 lanes x 16B per row(128B)
    int scol = (tid & 7) * 8;
    float4v acc[4][2] = {{{0.f,0.f,0.f,0.f},{0.f,0.f,0.f,0.f}},
                         {{0.f,0.f,0.f,0.f},{0.f,0.f,0.f,0.f}},
                         {{0.f,0.f,0.f,0.f},{0.f,0.f,0.f,0.f}},
                         {{0.f,0.f,0.f,0.f},{0.f,0.f,0.f,0.f}}};
    int a_off = (wm0 + (lane & 15)) * 64 + (lane >> 4) * 8;
    int b_off = (wn0 + (lane & 15)) * 64 + (lane >> 4) * 8;
    int ks0 = 0, ks1 = ksteps;
    if (bdiag) {
        int hlo = n0 / 35;
        int hhi = (n0 + 63) / 35; if (hhi > 9) hhi = 9;
        ks0 = (hlo * 36) >> 6;
        ks1 = (hhi * 36 + 36 + 63) >> 6;
    }
    for (int ks = ks0; ks < ks1; ks++) {
        int k0 = ks * 64;
        #pragma unroll
        for (int r = 0; r < 4; r++) {
            const ushort_t* g = A + (size_t)(m0 + r * 32 + srow) * lda + k0 + scol;
            async_cp16(g, As + (r * 256 + tid) * 8);
        }
        #pragma unroll
        for (int r = 0; r < 2; r++) {
            const ushort_t* g = Bt + (size_t)(n0 + r * 32 + srow) * lda + k0 + scol;
            async_cp16(g, Bs + (r * 256 + tid) * 8);
        }
        __syncthreads();
        #pragma unroll
        for (int kh = 0; kh < 2; kh++) {
            short8v b0 = *(const short8v*)&Bs[b_off + kh * 32];
            short8v b1 = *(const short8v*)&Bs[b_off + 16 * 64 + kh * 32];
            #pragma unroll
            for (int mi = 0; mi < 4; mi++) {
                short8v a = *(const short8v*)&As[a_off + mi * 16 * 64 + kh * 32];
                acc[mi][0] = __builtin_amdgcn_mfma_f32_16x16x32_bf16(a, b0, acc[mi][0], 0, 0, 0);
                acc[mi][1] = __builtin_amdgcn_mfma_f32_16x16x32_bf16(a, b1, acc[mi][1], 0, 0, 0);
            }
        }
        __syncthreads();
    }
    int lm = m0 + wm0 + (lane >> 4) * 4;
    int lc = n0 + wn0 + (lane & 15);
    #pragma unroll
    for (int mi = 0; mi < 4; mi++) {
        #pragma unroll
        for (int ni = 0; ni < 2; ni++) {
            int col = lc + ni * 16;
            if (col >= nst) continue;
            float bv = (bias != nullptr && col < Nv) ? bias[col] : 0.f;
            #pragma unroll
            for (int r = 0; r < 4; r++) {
                int row = lm + mi * 16 + r;
                if (row >= M) continue;
                float v = acc[mi][ni][r] + bv;
                if (act) v = fmaxf(v, 0.f);
                if (col >= Nv) v = 0.f;
                if (bf16out) ((ushort_t*)C)[(size_t)row * ldc + col] = f2bf(v);
                else         ((float*)C)[(size_t)row * ldc + col] = v;
            }
        }
    }
}

// ---------------- GAT aggregate on merged nd rows (4.8 MB, L2-resident) ----------------
// nd row: 24 u32 {x pairs w0..17, a_s bf16 pairs w18..22, 0}; head-stride-36 Z layout
// 2-wave blocks, x4 unroll; tail rows (wid in [NN,MPAD)) are zero-filled here
__global__ __launch_bounds__(128) void k_gat_agg(const ushort_t* __restrict__ nd,
                                                 const float* __restrict__ a_d,
                                                 const int* __restrict__ csr_src,
                                                 const int* __restrict__ offs, const int* __restrict__ deg,
                                                 ushort_t* __restrict__ Zb, float* __restrict__ denArr) {
    int wid = blockIdx.x * 2 + (threadIdx.x >> 6);
    int lane = threadIdx.x & 63;
    if (wid >= MPAD) return;
    unsigned* zr = (unsigned*)(Zb + (size_t)wid * KPAD);
    if (wid >= NN) {                              // zero the GEMM pad rows
        __builtin_nontemporal_store(0u, &zr[lane]);
        __builtin_nontemporal_store(0u, &zr[lane + 64]);
        __builtin_nontemporal_store(0u, &zr[lane + 128]);
        return;
    }
    int o0 = offs[wid], d = deg[wid];
    bool mine = (lane < NHEAD);
    float adv = mine ? a_d[wid * NHEAD + lane] : 0.f;
    int h1 = lane / 18,          c1 = lane % 18;
    int h2 = (lane + 64) / 18,   c2 = (lane + 64) % 18;
    bool g3 = lane < 52;
    int h3 = g3 ? (lane + 128) / 18 : 0;
    int c3 = g3 ? (lane + 128) % 18 : 0;
    float den = 0.f;
    float a1l = 0.f, a1h = 0.f, a2l = 0.f, a2h = 0.f, a3l = 0.f, a3h = 0.f;
    const unsigned* x32 = (const unsigned*)nd;
    int i = 0;
    for (; i + 4 <= d; i += 4) {
        int s0 = csr_src[o0 + i],     s1 = csr_src[o0 + i + 1];
        int s2 = csr_src[o0 + i + 2], s3 = csr_src[o0 + i + 3];
        const unsigned* x0 = x32 + (size_t)s0 * NDW;
        const unsigned* x1 = x32 + (size_t)s1 * NDW;
        const unsigned* x2 = x32 + (size_t)s2 * NDW;
        const unsigned* x3 = x32 + (size_t)s3 * NDW;
        float as0 = mine ? bfu(((const ushort_t*)x0)[36 + lane]) : 0.f;
        float as1 = mine ? bfu(((const ushort_t*)x1)[36 + lane]) : 0.f;
        float as2 = mine ? bfu(((const ushort_t*)x2)[36 + lane]) : 0.f;
        float as3 = mine ? bfu(((const ushort_t*)x3)[36 + lane]) : 0.f;
        unsigned u01 = x0[c1], u02 = x0[c2], u03 = x0[c3];
        unsigned u11 = x1[c1], u12 = x1[c2], u13 = x1[c3];
        unsigned u21 = x2[c1], u22 = x2[c2], u23 = x2[c3];
        unsigned u31 = x3[c1], u32 = x3[c2], u33 = x3[c3];
        float ex0 = __expf(lrelu(as0 + adv));
        float ex1 = __expf(lrelu(as1 + adv));
        float ex2 = __expf(lrelu(as2 + adv));
        float ex3 = __expf(lrelu(as3 + adv));
        den += (ex0 + ex1) + (ex2 + ex3);
        float e01 = __shfl(ex0, h1), e02 = __shfl(ex0, h2), e03 = __shfl(ex0, h3);
        float e11 = __shfl(ex1, h1), e12 = __shfl(ex1, h2), e13 = __shfl(ex1, h3);
        float e21 = __shfl(ex2, h1), e22 = __shfl(ex2, h2), e23 = __shfl(ex2, h3);
        float e31 = __shfl(ex3, h1), e32 = __shfl(ex3, h2), e33 = __shfl(ex3, h3);
        a1l += e01 * bflo(u01) + e11 * bflo(u11) + e21 * bflo(u21) + e31 * bflo(u31);
        a1h += e01 * bfhi(u01) + e11 * bfhi(u11) + e21 * bfhi(u21) + e31 * bfhi(u31);
        a2l += e02 * bflo(u02) + e12 * bflo(u12) + e22 * bflo(u22) + e32 * bflo(u32);
        a2h += e02 * bfhi(u02) + e12 * bfhi(u12) + e22 * bfhi(u22) + e32 * bfhi(u32);
        a3l += e03 * bflo(u03) + e13 * bflo(u13) + e23 * bflo(u23) + e33 * bflo(u33);
        a3h += e03 * bfhi(u03) + e13 * bfhi(u13) + e23 * bfhi(u23) + e33 * bfhi(u33);
    }
    for (; i < d; i++) {
        int s = csr_src[o0 + i];
        const unsigned* x0 = x32 + (size_t)s * NDW;
        float as0 = mine ? bfu(((const ushort_t*)x0)[36 + lane]) : 0.f;
        unsigned u01 = x0[c1], u02 = x0[c2], u03 = x0[c3];
        float ex0 = __expf(lrelu(as0 + adv));
        den += ex0;
        float e01 = __shfl(ex0, h1), e02 = __shfl(ex0, h2), e03 = __shfl(ex0, h3);
        a1l += e01 * bflo(u01);  a1h += e01 * bfhi(u01);
        a2l += e02 * bflo(u02);  a2h += e02 * bfhi(u02);
        a3l += e03 * bflo(u03);  a3h += e03 * bfhi(u03);
    }
    float rden = 1.f / (den + 1e-16f);
    if (mine) denArr[wid * NHEAD + lane] = den;
    float r1 = __shfl(rden, h1), r2 = __shfl(rden, h2), r3 = __shfl(rden, h3);
    __builtin_nontemporal_store(packbf(a1l * r1, a1h * r1), &zr[lane]);
    __builtin_nontemporal_store(packbf(a2l * r2, a2h * r2), &zr[lane + 64]);
    __builtin_nontemporal_store(g3 ? packbf(a3l * r3, a3h * r3) : 0u, &zr[lane + 128]);
}

// ---------------- alpha in original edge order (bf16-rounded logits match den) ----------------
__global__ __launch_bounds__(256) void k_alpha(const int* __restrict__ ei, const float* __restrict__ a_s,
                                               const float* __restrict__ a_d, const float* __restrict__ den,
                                               float* __restrict__ alphaOut) {
    int i = blockIdx.x * 256 + threadIdx.x;
    if (i >= ETOT * NHEAD) return;
    int e = i / NHEAD, hd = i % NHEAD;
    int s, dst;
    if (e < EE) { s = ei[e]; dst = ei[EE + e]; }
    else { s = dst = e - EE; }
    float zs = bfu(f2bf(a_s[s * NHEAD + hd]));     // same rounding as den accumulation
    float ex = __expf(lrelu(zs + a_d[dst * NHEAD + hd]));
    __builtin_nontemporal_store(ex / (den[dst * NHEAD + hd] + 1e-16f), &alphaOut[i]);
}

// ---------------- GCN aggregate: 2-wave blocks, x4 unroll, bf16 packed output ----------------
__global__ __launch_bounds__(128) void k_gcn_agg(const ushort_t* __restrict__ h2b,
                                                 const int* __restrict__ csr_src,
                                                 const int* __restrict__ offs, const int* __restrict__ deg,
                                                 const float* __restrict__ dinv, const float* __restrict__ b_gcn,
                                                 ushort_t* __restrict__ xg2b) {
    int wid = blockIdx.x * 2 + (threadIdx.x >> 6);
    int lane = threadIdx.x & 63;
    if (wid >= NN) return;
    int o0 = offs[wid], d = deg[wid];
    float wv = dinv[wid];
    bool g3 = lane < 48;                      // third h2 u32 group valid (w = lane+128 < 176)
    int w3 = g3 ? (lane + 128) : 0;
    float aL0 = 0.f, aH0 = 0.f, aL1 = 0.f, aH1 = 0.f, aL2 = 0.f, aH2 = 0.f;
    const unsigned* h32 = (const unsigned*)h2b;
    int i = 0;
    for (; i + 4 <= d; i += 4) {
        int s0 = csr_src[o0 + i],     s1 = csr_src[o0 + i + 1];
        int s2 = csr_src[o0 + i + 2], s3 = csr_src[o0 + i + 3];
        float q0 = dinv[s0], q1 = dinv[s1], q2 = dinv[s2], q3 = dinv[s3];
        const unsigned* h0 = h32 + (size_t)s0 * (LDH2 / 2);
        const unsigned* h1 = h32 + (size_t)s1 * (LDH2 / 2);
        const unsigned* h2 = h32 + (size_t)s2 * (LDH2 / 2);
        const unsigned* h3 = h32 + (size_t)s3 * (LDH2 / 2);
        unsigned u00 = h0[lane], u01 = h0[lane + 64], u02 = h0[w3];
        unsigned u10 = h1[lane], u11 = h1[lane + 64], u12 = h1[w3];
        unsigned u20 = h2[lane], u21 = h2[lane + 64], u22 = h2[w3];
        unsigned u30 = h3[lane], u31 = h3[lane + 64], u32 = h3[w3];
        aL0 += q0 * bflo(u00) + q1 * bflo(u10) + q2 * bflo(u20) + q3 * bflo(u30);
        aH0 += q0 * bfhi(u00) + q1 * bfhi(u10) + q2 * bfhi(u20) + q3 * bfhi(u30);
        aL1 += q0 * bflo(u01) + q1 * bflo(u11) + q2 * bflo(u21) + q3 * bflo(u31);
        aH1 += q0 * bfhi(u01) + q1 * bfhi(u11) + q2 * bfhi(u21) + q3 * bfhi(u31);
        aL2 += q0 * bflo(u02) + q1 * bflo(u12) + q2 * bflo(u22) + q3 * bflo(u32);
        aH2 += q0 * bfhi(u02) + q1 * bfhi(u12) + q2 * bfhi(u22) + q3 * bfhi(u32);
    }
    for (; i < d; i++) {
        int s = csr_src[o0 + i];
        float ws = dinv[s];
        const unsigned* hr = h32 + (size_t)s * (LDH2 / 2);
        unsigned u0 = hr[lane], u1 = hr[lane + 64], u2 = hr[w3];
        aL0 += ws * bflo(u0);  aH0 += ws * bfhi(u0);
        aL1 += ws * bflo(u1);  aH1 += ws * bfhi(u1);
        aL2 += ws * bflo(u2);  aH2 += ws * bfhi(u2);
    }
    // packed bf16 output: row = 350 ushorts (175 u32 words); word w covers features 2w,2w+1
    unsigned* orow = (unsigned*)(xg2b + (size_t)wid * FG);
    {
        int f = 2 * lane;
        __builtin_nontemporal_store(packbf(fmaxf(wv * aL0 + b_gcn[f], 0.f),
                                           fmaxf(wv * aH0 + b_gcn[f + 1], 0.f)), &orow[lane]);
    }
    {
        int f = 128 + 2 * lane;
        __builtin_nontemporal_store(packbf(fmaxf(wv * aL1 + b_gcn[f], 0.f),
                                           fmaxf(wv * aH1 + b_gcn[f + 1], 0.f)), &orow[64 + lane]);
    }
    if (lane < 47) {
        int f = 256 + 2 * lane;
        __builtin_nontemporal_store(packbf(fmaxf(wv * aL2 + b_gcn[f], 0.f),
                                           fmaxf(wv * aH2 + b_gcn[f + 1], 0.f)), &orow[128 + lane]);
    }
}

// ---------------- per-graph max+mean pool (bf16 input, u32-word per thread) ----------------
__device__ __forceinline__ int lowerB(const int* a, int n, int key) {
    int lo = 0, hi = n;
    while (lo < hi) { int mid = (lo + hi) >> 1; if (a[mid] < key) lo = mid + 1; else hi = mid; }
    return lo;
}

__global__ __launch_bounds__(256) void k_pool(const ushort_t* __restrict__ xg2b, const int* __restrict__ batch,
                                              float* __restrict__ pooled) {
    int g = blockIdx.x;
    int w = threadIdx.x;
    if (w >= 175) return;
    int s = lowerB(batch, NN, g);
    int e = lowerB(batch, NN, g + 1);
    const unsigned* base = (const unsigned*)xg2b;
    float mx0 = -INFINITY, mx1 = -INFINITY, sm0 = 0.f, sm1 = 0.f;
    int n = s;
    for (; n + 2 <= e; n += 2) {
        unsigned ua = base[(size_t)n * 175 + w];
        unsigned ub = base[(size_t)(n + 1) * 175 + w];
        float a0 = bflo(ua), a1 = bfhi(ua), b0 = bflo(ub), b1 = bfhi(ub);
        mx0 = fmaxf(mx0, fmaxf(a0, b0));
        mx1 = fmaxf(mx1, fmaxf(a1, b1));
        sm0 += a0 + b0;
        sm1 += a1 + b1;
    }
    for (; n < e; n++) {
        unsigned ua = base[(size_t)n * 175 + w];
        float a0 = bflo(ua), a1 = bfhi(ua);
        mx0 = fmaxf(mx0, a0);
        mx1 = fmaxf(mx1, a1);
        sm0 += a0;
        sm1 += a1;
    }
    float rc = 1.f / fmaxf((float)(e - s), 1.f);
    pooled[g * 700 + 2 * w]       = mx0;
    pooled[g * 700 + 2 * w + 1]   = mx1;
    pooled[g * 700 + FG + 2 * w]     = sm0 * rc;
    pooled[g * 700 + FG + 2 * w + 1] = sm1 * rc;
}

// ---------------- protein conv branch: LDS-resident, 2 proteins per block ----------------
__global__ __launch_bounds__(256) void k_conv(const int* __restrict__ target, const float* __restrict__ emb,
                                              const float* __restrict__ Wc, const float* __restrict__ bc,
                                              float* __restrict__ xt) {
    __shared__ float embL[26 * 132];        // rows padded to 132 floats
    __shared__ float WL[16 * 8 * 128];      // WL[f][k][e] = Wc[f][e][k]
    __shared__ int   tgL[2 * LL];
    int tid = threadIdx.x;
    int b0 = blockIdx.x * 2;
    for (int i = tid; i < 26 * 128; i += 256) {
        int r = i >> 7, e = i & 127;
        embL[r * 132 + e] = emb[i];
    }
    for (int i = tid; i < 16384; i += 256) {
        int f = i >> 10, rem = i & 1023, k = rem >> 7, e = rem & 127;
        WL[i] = Wc[f * 1024 + e * 8 + k];
    }
    if (tid < 2 * LL) tgL[tid] = target[b0 * LL + tid];
    __syncthreads();
    #pragma unroll
    for (int pass = 0; pass < 2; pass++) {
        int r = tid + pass * 256;
        if (r >= 280) break;
        int bl = r / 140, rem = r % 140;
        int fq = rem / 35, t = rem % 35;
        const int* tg = &tgL[bl * LL];
        float ac0 = 0.f, ac1 = 0.f, ac2 = 0.f, ac3 = 0.f;
        for (int k = 0; k < 8; k++) {
            const float* er = &embL[tg[t + k] * 132];
            const float* w0 = &WL[((fq * 4 + 0) * 8 + k) * 128];
            const float* w1 = &WL[((fq * 4 + 1) * 8 + k) * 128];
            const float* w2 = &WL[((fq * 4 + 2) * 8 + k) * 128];
            const float* w3 = &WL[((fq * 4 + 3) * 8 + k) * 128];
            #pragma unroll 8
            for (int e = 0; e < 128; e += 4) {
                float4 a = *(const float4*)&er[e];
                float4 q0 = *(const float4*)&w0[e];
                float4 q1 = *(const float4*)&w1[e];
                float4 q2 = *(const float4*)&w2[e];
                float4 q3 = *(const float4*)&w3[e];
                ac0 += a.x * q0.x + a.y * q0.y + a.z * q0.z + a.w * q0.w;
                ac1 += a.x * q1.x + a.y * q1.y + a.z * q1.z + a.w * q1.w;
                ac2 += a.x * q2.x + a.y * q2.y + a.z * q2.z + a.w * q2.w;
                ac3 += a.x * q3.x + a.y * q3.y + a.z * q3.z + a.w * q3.w;
            }
        }
        int b = b0 + bl, fb = fq * 4;
        xt[b * 560 + (fb + 0) * 35 + t] = ac0 + bc[fb + 0];
        xt[b * 560 + (fb + 1) * 35 + t] = ac1 + bc[fb + 1];
        xt[b * 560 + (fb + 2) * 35 + t] = ac2 + bc[fb + 2];
        xt[b * 560 + (fb + 3) * 35 + t] = ac3 + bc[fb + 3];
    }
}

// ---------------- final dot + sigmoid ----------------
__global__ __launch_bounds__(256) void k_out(const float* __restrict__ f1, const float* __restrict__ W_out,
                                             const float* __restrict__ b_out, float* __restrict__ out) {
    int wid = (blockIdx.x * blockDim.x + threadIdx.x) >> 6;
    int lane = threadIdx.x & 63;
    if (wid >= BB) return;
    const float* xr = f1 + (size_t)wid * 512;
    float acc = 0.f;
    #pragma unroll
    for (int k = 0; k < 8; k++) acc += xr[lane + k * 64] * W_out[lane + k * 64];
    #pragma unroll
    for (int d = 32; d; d >>= 1) acc += __shfl_xor(acc, d);
    if (lane == 0) out[wid] = 1.f / (1.f + __expf(-(acc + b_out[0])));
}

// ---------------- host launcher ----------------
extern "C" void kernel_launch(void* const* d_in, const int* in_sizes, int n_in,
                              void* d_out, int out_size, void* d_ws, size_t ws_size,
                              hipStream_t stream) {
    const float* x      = (const float*)d_in[0];
    const int*   ei     = (const int*)d_in[1];
    const int*   batch  = (const int*)d_in[2];
    const int*   target = (const int*)d_in[3];
    const float* W_gat  = (const float*)d_in[4];
    const float* att_s  = (const float*)d_in[5];
    const float* att_d  = (const float*)d_in[6];
    const float* b_gat  = (const float*)d_in[7];
    const float* W_gcn  = (const float*)d_in[8];
    const float* b_gcn  = (const float*)d_in[9];
    const float* W_fcg1 = (const float*)d_in[10];
    const float* b_fcg1 = (const float*)d_in[11];
    const float* W_fcg2 = (const float*)d_in[12];
    const float* b_fcg2 = (const float*)d_in[13];
    const float* embxt  = (const float*)d_in[14];
    const float* W_conv = (const float*)d_in[15];
    const float* b_conv = (const float*)d_in[16];
    const float* W_fcxt = (const float*)d_in[17];
    const float* b_fcxt = (const float*)d_in[18];
    const float* W_fc1  = (const float*)d_in[19];
    const float* b_fc1  = (const float*)d_in[20];
    const float* W_out  = (const float*)d_in[21];
    const float* b_out  = (const float*)d_in[22];

    float* out_sig  = (float*)d_out;          // [500]
    float* alphaOut = (float*)d_out + BB;     // [850000 * 10]

    size_t o = 0;
    auto alloc = [&](size_t bytes) -> void* {
        o = (o + 255) & ~(size_t)255;
        void* p = (char*)d_ws + o;
        o += bytes;
        return p;
    };
    int*   deg     = (int*)alloc((size_t)NN * 4);
    int*   cur     = (int*)alloc((size_t)NN * 4);
    int*   offs    = (int*)alloc((size_t)NN * 4);
    int*   part    = (int*)alloc(128 * 4);
    int*   pscan   = (int*)alloc(128 * 4);
    int*   csr_src = (int*)alloc((size_t)ETOT * 4);
    float* dinv    = (float*)alloc((size_t)NN * 4);
    float* a_s     = (float*)alloc((size_t)NN * NHEAD * 4);
    float* a_d     = (float*)alloc((size_t)NN * NHEAD * 4);
    float* denArr  = (float*)alloc((size_t)NN * NHEAD * 4);
    ushort_t* nd   = (ushort_t*)alloc((size_t)NN * 48 * 2);       // merged node rows (4.8 MB)
    float* wS      = (float*)alloc((size_t)FG * 4);
    float* wD      = (float*)alloc((size_t)FG * 4);
    ushort_t* WtBD = (ushort_t*)alloc((size_t)KPAD * KPAD * 2);   // block-diag W_gat^T (stride-36 K)
    ushort_t* WtGC = (ushort_t*)alloc((size_t)KPAD * KPAD * 2);
    ushort_t* WtF1 = (ushort_t*)alloc((size_t)1536 * 704 * 2);
    ushort_t* WtF2 = (ushort_t*)alloc((size_t)128 * 1536 * 2);
    ushort_t* WtFX = (ushort_t*)alloc((size_t)128 * 576 * 2);
    ushort_t* WtFC = (ushort_t*)alloc((size_t)512 * 256 * 2);
    float* pooled  = (float*)alloc((size_t)BB * 700 * 4);
    ushort_t* pooledb = (ushort_t*)alloc((size_t)MB2 * 704 * 2);
    ushort_t* t1b  = (ushort_t*)alloc((size_t)MB2 * 1536 * 2);
    float* xt      = (float*)alloc((size_t)BB * 560 * 4);
    ushort_t* xtb  = (ushort_t*)alloc((size_t)MB2 * 576 * 2);
    ushort_t* xcb  = (ushort_t*)alloc((size_t)MB2 * 256 * 2);
    float* f1      = (float*)alloc((size_t)MB2 * 512 * 4);
    ushort_t* hb   = (ushort_t*)alloc((size_t)MPAD * KPAD * 2);   // Z (GAT agg), later h2 (ld 352)
    char*  R2      = (char*)alloc((size_t)NN * FG * 4);           // aliased region
    ushort_t* xg1b = (ushort_t*)R2;                               // [MPAD][KPAD] bf16 (38.4 MB)
    ushort_t* xg2b = (ushort_t*)R2;                               // [NN][350] bf16, after xg1b dead
    (void)ws_size; (void)n_in; (void)in_sizes; (void)out_size;

    auto mfma = [&](const ushort_t* A, const ushort_t* Bt, void* C, const float* bias,
                    int M2, int Nv, int NP, int ldc, int KP, int act, int bf16out, int bdiag, int nst) {
        dim3 g(NP / 64, M2 / 128);
        k_mfma<<<g, 256, 0, stream>>>(A, Bt, C, M2, Nv, ldc, KP, KP / 64, bias, act, bf16out, bdiag, nst);
    };

    // graph prep
    k_init<<<(NN + 255) / 256, 256, 0, stream>>>(deg, cur);
    k_deg<<<(EE + 255) / 256, 256, 0, stream>>>(ei, deg);
    k_scan1<<<NCHUNK, 512, 0, stream>>>(deg, part);
    k_scan2<<<1, 64, 0, stream>>>(part, pscan);
    k_scan3<<<NCHUNK, 512, 0, stream>>>(deg, pscan, offs, dinv);
    k_scatter<<<(ETOT + 255) / 256, 256, 0, stream>>>(ei, offs, cur, csr_src);

    // prep (fused attention weights -> merged node rows; all weights in one kernel)
    k_prep_att<<<2, 256, 0, stream>>>(W_gat, att_s, att_d, wS, wD);
    k_prep_node<<<(NN + 255) / 256, 256, 0, stream>>>(x, wS, wD, nd, a_s, a_d);
    k_prep_weights<<<(PREPW_TOTAL + 255) / 256, 256, 0, stream>>>(W_gat, W_gcn, W_fcg1, W_fcg2,
                                                                  W_fcxt, W_fc1,
                                                                  WtBD, WtGC, WtF1, WtF2, WtFX, WtFC);

    // GAT: aggregate x (stride-36 Z, tail zeroed in-kernel) -> alpha -> block-diag GEMM
    k_gat_agg<<<MPAD / 2, 128, 0, stream>>>(nd, a_d, csr_src, offs, deg, hb, denArr);   // Z -> hb
    k_alpha<<<(ETOT * NHEAD + 255) / 256, 256, 0, stream>>>(ei, a_s, a_d, denArr, alphaOut);
    mfma(hb, WtBD, xg1b, b_gat, MPAD, FG, KPAD, KPAD, KPAD, 1, 1, 1, KPAD);  // xg1 = relu(Z@W_bd+b)

    // GCN: h2 = xg1 @ W_gcn (overwrites hb, row stride 352), then aggregate (bf16 out)
    mfma(xg1b, WtGC, hb, nullptr, MPAD, FG, KPAD, LDH2, KPAD, 0, 1, 0, LDH2);
    k_gcn_agg<<<(NN + 1) / 2, 128, 0, stream>>>(hb, csr_src, offs, deg, dinv, b_gcn, xg2b);

    // pool + FC stacks (all FC layers via bf16 MFMA)
    k_pool<<<BB, 256, 0, stream>>>(xg2b, batch, pooled);
    k_cast_pad<<<(MB2 * 704 + 255) / 256, 256, 0, stream>>>(pooled, pooledb, BB, 700, MB2, 704);
    mfma(pooledb, WtF1, t1b, b_fcg1, MB2, 1500, 1536, 1536, 704, 1, 1, 0, 1536);
    mfma(t1b, WtF2, xcb, b_fcg2, MB2, 128, 128, 256, 1536, 0, 1, 0, 128);
    k_conv<<<250, 256, 0, stream>>>(target, embxt, W_conv, b_conv, xt);
    k_cast_pad<<<(MB2 * 576 + 255) / 256, 256, 0, stream>>>(xt, xtb, BB, 560, MB2, 576);
    mfma(xtb, WtFX, xcb + 128, b_fcxt, MB2, 128, 128, 256, 576, 0, 1, 0, 128);
    mfma(xcb, WtFC, f1, b_fc1, MB2, 512, 512, 512, 256, 1, 0, 0, 512);
    k_out<<<(BB + 3) / 4, 256, 0, stream>>>(f1, W_out, b_out, out_sig);
}

// Round 12
// 575.547 us; speedup vs baseline: 1.1215x; 1.0007x over previous
//
#include <hip/hip_runtime.h>
#include <math.h>

#define NN 50000
#define EE 800000
#define BB 500
#define LL 42
#define NHEAD 10
#define FH 35
#define FG 350
#define ETOT (EE + NN)
#define NCHUNK ((NN + 511) / 512)

#define KPAD 384         // bf16 row stride for Z / xg1
#define LDH2 352         // bf16 row stride for h2 (tight)
#define MPAD 50048       // M padded to multiple of 128
#define MB2  512         // padded batch rows for FC MFMA
#define NDW  24          // nd row width in u32 words (48 ushorts = 96 B)

typedef unsigned short ushort_t;
typedef __attribute__((ext_vector_type(8))) short short8v;
typedef __attribute__((ext_vector_type(4))) float float4v;

__device__ __forceinline__ float lrelu(float x) { return x > 0.f ? x : 0.2f * x; }

__device__ __forceinline__ ushort_t f2bf(float f) {
    unsigned int u = __float_as_uint(f);
    u += 0x7fffu + ((u >> 16) & 1u);      // round-to-nearest-even
    return (ushort_t)(u >> 16);
}
__device__ __forceinline__ float bflo(unsigned u) { return __uint_as_float(u << 16); }
__device__ __forceinline__ float bfhi(unsigned u) { return __uint_as_float(u & 0xffff0000u); }
__device__ __forceinline__ float bfu(ushort_t u) { return __uint_as_float(((unsigned)u) << 16); }
__device__ __forceinline__ unsigned packbf(float a, float b) {
    return (unsigned)f2bf(a) | ((unsigned)f2bf(b) << 16);
}

__device__ __forceinline__ void async_cp16(const void* g, void* l) {
    __builtin_amdgcn_global_load_lds((const __attribute__((address_space(1))) unsigned int*)g,
                                     (__attribute__((address_space(3))) unsigned int*)l, 16, 0, 0);
}

// ---------------- graph prep ----------------
__global__ __launch_bounds__(256) void k_init(int* deg, int* cur) {
    int i = blockIdx.x * 256 + threadIdx.x;
    if (i < NN) { deg[i] = 1; cur[i] = 0; }   // deg=1 accounts for the self-loop
}

__global__ __launch_bounds__(256) void k_deg(const int* __restrict__ ei, int* deg) {
    int i = blockIdx.x * 256 + threadIdx.x;
    if (i < EE) atomicAdd(&deg[ei[EE + i]], 1);
}

__global__ __launch_bounds__(512) void k_scan1(const int* __restrict__ deg, int* part) {
    int i = blockIdx.x * 512 + threadIdx.x;
    int lane = threadIdx.x & 63, wv = threadIdx.x >> 6;
    int x = (i < NN) ? deg[i] : 0;
    #pragma unroll
    for (int d = 32; d; d >>= 1) x += __shfl_xor(x, d);
    __shared__ int wsum[8];
    if (lane == 0) wsum[wv] = x;
    __syncthreads();
    if (threadIdx.x == 0) {
        int s = 0;
        #pragma unroll
        for (int w = 0; w < 8; w++) s += wsum[w];
        part[blockIdx.x] = s;
    }
}

__global__ __launch_bounds__(64) void k_scan2(const int* __restrict__ part, int* pscan) {
    int l = threadIdx.x;
    int v0 = (l < NCHUNK) ? part[l] : 0;
    #pragma unroll
    for (int d = 1; d < 64; d <<= 1) { int t = __shfl_up(v0, d); if (l >= d) v0 += t; }
    int tot0 = __shfl(v0, 63);
    int v1 = (64 + l < NCHUNK) ? part[64 + l] : 0;
    #pragma unroll
    for (int d = 1; d < 64; d <<= 1) { int t = __shfl_up(v1, d); if (l >= d) v1 += t; }
    v1 += tot0;
    if (l < NCHUNK) pscan[l] = v0;
    if (64 + l < NCHUNK) pscan[64 + l] = v1;
}

__global__ __launch_bounds__(512) void k_scan3(const int* __restrict__ deg, const int* __restrict__ pscan,
                                               int* offs, float* dinv) {
    int i = blockIdx.x * 512 + threadIdx.x;
    int lane = threadIdx.x & 63, wv = threadIdx.x >> 6;
    int x = (i < NN) ? deg[i] : 0;
    int incl = x;
    #pragma unroll
    for (int d = 1; d < 64; d <<= 1) { int t = __shfl_up(incl, d); if (lane >= d) incl += t; }
    __shared__ int wtot[8];
    if (lane == 63) wtot[wv] = incl;
    __syncthreads();
    int woff = 0;
    for (int w = 0; w < wv; w++) woff += wtot[w];
    int base = (blockIdx.x == 0) ? 0 : pscan[blockIdx.x - 1];
    if (i < NN) {
        offs[i] = base + woff + incl - x;   // exclusive prefix
        dinv[i] = rsqrtf((float)x);
    }
}

__global__ __launch_bounds__(256) void k_scatter(const int* __restrict__ ei, const int* __restrict__ offs,
                                                 int* cur, int* csr_src) {
    int i = blockIdx.x * 256 + threadIdx.x;
    if (i < EE) {
        int s = ei[i], d = ei[EE + i];
        int slot = atomicAdd(&cur[d], 1);
        csr_src[offs[d] + slot] = s;
    } else if (i < ETOT) {
        int v = i - EE;
        int slot = atomicAdd(&cur[v], 1);
        csr_src[offs[v] + slot] = v;
    }
}

// ---------------- prep kernels ----------------
// w~_s[hd,c] = sum_cc W_gat[c, hd*35+cc] * att_s[hd,cc]  (and same for d)
__global__ __launch_bounds__(256) void k_prep_att(const float* __restrict__ W_gat, const float* __restrict__ att_s,
                                                  const float* __restrict__ att_d,
                                                  float* __restrict__ wS, float* __restrict__ wD) {
    int i = blockIdx.x * 256 + threadIdx.x;
    if (i >= FG) return;
    int hd = i / 35, c = i % 35;
    float ss = 0.f, dd = 0.f;
    for (int cc = 0; cc < 35; cc++) {
        float w = W_gat[c * FG + hd * 35 + cc];
        ss += w * att_s[hd * 35 + cc];
        dd += w * att_d[hd * 35 + cc];
    }
    wS[i] = ss;
    wD[i] = dd;
}

// fused node prep: nd[n] = 48 ushorts {x bf16 pairs [w0..17], a_s bf16 pairs [w18..22], 0 [w23]}
// plus f32 a_s/a_d arrays (for k_alpha numerator + gat_agg adv)
__global__ __launch_bounds__(256) void k_prep_node(const float* __restrict__ x, const float* __restrict__ wS,
                                                   const float* __restrict__ wD, ushort_t* __restrict__ nd,
                                                   float* __restrict__ a_s, float* __restrict__ a_d) {
    __shared__ float sw[FG], dw[FG];
    int tid = threadIdx.x;
    for (int i = tid; i < FG; i += 256) { sw[i] = wS[i]; dw[i] = wD[i]; }
    __syncthreads();
    int n = blockIdx.x * 256 + tid;
    if (n >= NN) return;
    float xr[35];
    #pragma unroll
    for (int c = 0; c < 35; c++) xr[c] = x[(size_t)n * 35 + c];
    unsigned* xo = (unsigned*)(nd + (size_t)n * (2 * NDW));
    #pragma unroll
    for (int w = 0; w < 17; w++) xo[w] = packbf(xr[2 * w], xr[2 * w + 1]);
    xo[17] = packbf(xr[34], 0.f);
    float asv[NHEAD];
    #pragma unroll
    for (int hd = 0; hd < NHEAD; hd++) {
        const float* ws = &sw[hd * 35];
        const float* wd = &dw[hd * 35];
        float as = 0.f, ad = 0.f;
        #pragma unroll
        for (int c = 0; c < 35; c++) { float v = xr[c]; as += v * ws[c]; ad += v * wd[c]; }
        asv[hd] = as;
        a_s[n * NHEAD + hd] = as;
        a_d[n * NHEAD + hd] = ad;
    }
    #pragma unroll
    for (int j = 0; j < 5; j++) xo[18 + j] = packbf(asv[2 * j], asv[2 * j + 1]);
    xo[23] = 0u;
}

// merged weight prep: block-diag W_gat (stride-36 K), W_gcn^T, and 4 FC weights -> padded bf16
__global__ __launch_bounds__(256) void k_prep_weights(
    const float* __restrict__ Wg, const float* __restrict__ Wc,
    const float* __restrict__ W1, const float* __restrict__ W2,
    const float* __restrict__ WX, const float* __restrict__ WF,
    ushort_t* __restrict__ BD, ushort_t* __restrict__ GC,
    ushort_t* __restrict__ F1, ushort_t* __restrict__ F2,
    ushort_t* __restrict__ FX, ushort_t* __restrict__ FC) {
    int i = blockIdx.x * 256 + threadIdx.x;
    if (i < KPAD * KPAD) {                    // block-diag W_gat, k = hd*36+cc
        int n = i / KPAD, k = i % KPAD;
        int hd = k / 36, cc = k % 36;
        float v = 0.f;
        if (n < FG && cc < 35 && hd == n / 35) v = Wg[cc * FG + n];
        BD[i] = f2bf(v);
        return;
    }
    i -= KPAD * KPAD;
    if (i < KPAD * KPAD) {                    // W_gcn^T
        int n = i / KPAD, k = i % KPAD;
        float v = (n < FG && k < FG) ? Wc[k * FG + n] : 0.f;
        GC[i] = f2bf(v);
        return;
    }
    i -= KPAD * KPAD;
    if (i < 704 * 1536) {                     // W_fcg1^T [1536][704]
        int k = i / 1536, n = i % 1536;
        float v = (k < 700 && n < 1500) ? W1[(size_t)k * 1500 + n] : 0.f;
        F1[(size_t)n * 704 + k] = f2bf(v);
        return;
    }
    i -= 704 * 1536;
    if (i < 1536 * 128) {                     // W_fcg2^T [128][1536]
        int k = i / 128, n = i % 128;
        float v = (k < 1500) ? W2[(size_t)k * 128 + n] : 0.f;
        F2[(size_t)n * 1536 + k] = f2bf(v);
        return;
    }
    i -= 1536 * 128;
    if (i < 576 * 128) {                      // W_fcxt^T [128][576]
        int k = i / 128, n = i % 128;
        float v = (k < 560) ? WX[(size_t)k * 128 + n] : 0.f;
        FX[(size_t)n * 576 + k] = f2bf(v);
        return;
    }
    i -= 576 * 128;
    if (i < 256 * 512) {                      // W_fc1^T [512][256]
        int k = i / 512, n = i % 512;
        FC[(size_t)n * 256 + k] = f2bf(WF[(size_t)k * 512 + n]);
    }
}
#define PREPW_TOTAL (KPAD * KPAD * 2 + 704 * 1536 + 1536 * 128 + 576 * 128 + 256 * 512)

// generic: dst[r*KP+k] = bf16(src[r*K+k]), zero-padded
__global__ __launch_bounds__(256) void k_cast_pad(const float* __restrict__ src, ushort_t* __restrict__ dst,
                                                  int M, int K, int MP, int KP) {
    int i = blockIdx.x * 256 + threadIdx.x;
    if (i >= MP * KP) return;
    int r = i / KP, k = i % KP;
    dst[i] = (r < M && k < K) ? f2bf(src[(size_t)r * K + k]) : (ushort_t)0;
}

// ---------------- bf16 MFMA GEMM: C = act(A[Mp,lda] @ Bt[Np,lda] + bias) ----------------
// tile 128x64, BK=64, 4 waves 2x2. bdiag=1: K-window (head-stride-36) limited per col-tile.
// nst: store-column clamp (cols >= nst not written; cols in [Nv, nst) written as 0)
__global__ __launch_bounds__(256) void k_mfma(const ushort_t* __restrict__ A, const ushort_t* __restrict__ Bt,
                                              void* __restrict__ C, int M, int Nv, int ldc, int lda,
                                              int ksteps, const float* __restrict__ bias, int act, int bf16out,
                                              int bdiag, int nst) {
    __shared__ ushort_t As[128 * 64];
    __shared__ ushort_t Bs[64 * 64];
    int tid = threadIdx.x;
    int wid = tid >> 6, lane = tid & 63;
    int m0 = blockIdx.y * 128, n0 = blockIdx.x * 64;
    int wm0 = (wid >> 1) * 64, wn0 = (wid & 1) * 32;
    int srow = tid >> 3;              // staging: 8 lanes x 16B per row(128B)
    int scol = (tid & 7) * 8;
    float4v acc[4][2] = {{{0.f,0.f,0.f,0.f},{0.f,0.f,0.f,0.f}},
                         {{0.f,0.f,0.f,0.f},{0.f,0.f,0.f,0.f}},
                         {{0.f,0.f,0.f,0.f},{0.f,0.f,0.f,0.f}},
                         {{0.f,0.f,0.f,0.f},{0.f,0.f,0.f,0.f}}};
    int a_off = (wm0 + (lane & 15)) * 64 + (lane >> 4) * 8;
    int b_off = (wn0 + (lane & 15)) * 64 + (lane >> 4) * 8;
    int ks0 = 0, ks1 = ksteps;
    if (bdiag) {
        int hlo = n0 / 35;
        int hhi = (n0 + 63) / 35; if (hhi > 9) hhi = 9;
        ks0 = (hlo * 36) >> 6;
        ks1 = (hhi * 36 + 36 + 63) >> 6;
    }
    for (int ks = ks0; ks < ks1; ks++) {
        int k0 = ks * 64;
        #pragma unroll
        for (int r = 0; r < 4; r++) {
            const ushort_t* g = A + (size_t)(m0 + r * 32 + srow) * lda + k0 + scol;
            async_cp16(g, As + (r * 256 + tid) * 8);
        }
        #pragma unroll
        for (int r = 0; r < 2; r++) {
            const ushort_t* g = Bt + (size_t)(n0 + r * 32 + srow) * lda + k0 + scol;
            async_cp16(g, Bs + (r * 256 + tid) * 8);
        }
        __syncthreads();
        #pragma unroll
        for (int kh = 0; kh < 2; kh++) {
            short8v b0 = *(const short8v*)&Bs[b_off + kh * 32];
            short8v b1 = *(const short8v*)&Bs[b_off + 16 * 64 + kh * 32];
            #pragma unroll
            for (int mi = 0; mi < 4; mi++) {
                short8v a = *(const short8v*)&As[a_off + mi * 16 * 64 + kh * 32];
                acc[mi][0] = __builtin_amdgcn_mfma_f32_16x16x32_bf16(a, b0, acc[mi][0], 0, 0, 0);
                acc[mi][1] = __builtin_amdgcn_mfma_f32_16x16x32_bf16(a, b1, acc[mi][1], 0, 0, 0);
            }
        }
        __syncthreads();
    }
    int lm = m0 + wm0 + (lane >> 4) * 4;
    int lc = n0 + wn0 + (lane & 15);
    #pragma unroll
    for (int mi = 0; mi < 4; mi++) {
        #pragma unroll
        for (int ni = 0; ni < 2; ni++) {
            int col = lc + ni * 16;
            if (col >= nst) continue;
            float bv = (bias != nullptr && col < Nv) ? bias[col] : 0.f;
            #pragma unroll
            for (int r = 0; r < 4; r++) {
                int row = lm + mi * 16 + r;
                if (row >= M) continue;
                float v = acc[mi][ni][r] + bv;
                if (act) v = fmaxf(v, 0.f);
                if (col >= Nv) v = 0.f;
                if (bf16out) ((ushort_t*)C)[(size_t)row * ldc + col] = f2bf(v);
                else         ((float*)C)[(size_t)row * ldc + col] = v;
            }
        }
    }
}

// ---------------- GAT aggregate, shuffle-free: each lane computes its heads' exp locally ----------------
// nd row: 24 u32 {x pairs w0..17, a_s bf16 pairs w18..22, 0}; head of word w = w/18
// den per head computed redundantly (identical order -> bitwise equal); canonical lanes write denArr
__global__ __launch_bounds__(128) void k_gat_agg(const ushort_t* __restrict__ nd,
                                                 const float* __restrict__ a_d,
                                                 const int* __restrict__ csr_src,
                                                 const int* __restrict__ offs, const int* __restrict__ deg,
                                                 ushort_t* __restrict__ Zb, float* __restrict__ denArr) {
    int wid = blockIdx.x * 2 + (threadIdx.x >> 6);
    int lane = threadIdx.x & 63;
    if (wid >= MPAD) return;
    unsigned* zr = (unsigned*)(Zb + (size_t)wid * KPAD);
    if (wid >= NN) {                              // zero the GEMM pad rows
        __builtin_nontemporal_store(0u, &zr[lane]);
        __builtin_nontemporal_store(0u, &zr[lane + 64]);
        __builtin_nontemporal_store(0u, &zr[lane + 128]);
        return;
    }
    int o0 = offs[wid], d = deg[wid];
    int h1 = lane / 18,        c1 = lane % 18;
    int h2 = (lane + 64) / 18, c2 = (lane + 64) % 18;
    bool g3 = lane < 52;
    int h3 = g3 ? (lane + 128) / 18 : 7;          // clamp to a valid head for pad lanes
    int c3 = g3 ? (lane + 128) % 18 : 0;
    float adv1 = a_d[wid * NHEAD + h1];
    float adv2 = a_d[wid * NHEAD + h2];
    float adv3 = a_d[wid * NHEAD + h3];
    float den1 = 0.f, den2 = 0.f, den3 = 0.f;
    float a1l = 0.f, a1h = 0.f, a2l = 0.f, a2h = 0.f, a3l = 0.f, a3h = 0.f;
    int i = 0;
    for (; i + 4 <= d; i += 4) {
        int s[4];
        #pragma unroll
        for (int j = 0; j < 4; j++) s[j] = csr_src[o0 + i + j];
        ushort_t w1[4], w2[4], w3[4];
        unsigned u1[4], u2[4], u3[4];
        #pragma unroll
        for (int j = 0; j < 4; j++) {
            const ushort_t* r = nd + (size_t)s[j] * (2 * NDW);
            w1[j] = r[36 + h1]; w2[j] = r[36 + h2]; w3[j] = r[36 + h3];
            const unsigned* ru = (const unsigned*)r;
            u1[j] = ru[c1]; u2[j] = ru[c2]; u3[j] = ru[c3];
        }
        #pragma unroll
        for (int j = 0; j < 4; j++) {
            float e1 = __expf(lrelu(bfu(w1[j]) + adv1));
            float e2 = __expf(lrelu(bfu(w2[j]) + adv2));
            float e3 = __expf(lrelu(bfu(w3[j]) + adv3));
            den1 += e1; den2 += e2; den3 += e3;
            a1l += e1 * bflo(u1[j]); a1h += e1 * bfhi(u1[j]);
            a2l += e2 * bflo(u2[j]); a2h += e2 * bfhi(u2[j]);
            a3l += e3 * bflo(u3[j]); a3h += e3 * bfhi(u3[j]);
        }
    }
    for (; i < d; i++) {
        int s = csr_src[o0 + i];
        const ushort_t* r = nd + (size_t)s * (2 * NDW);
        const unsigned* ru = (const unsigned*)r;
        float e1 = __expf(lrelu(bfu(r[36 + h1]) + adv1));
        float e2 = __expf(lrelu(bfu(r[36 + h2]) + adv2));
        float e3 = __expf(lrelu(bfu(r[36 + h3]) + adv3));
        den1 += e1; den2 += e2; den3 += e3;
        a1l += e1 * bflo(ru[c1]); a1h += e1 * bfhi(ru[c1]);
        a2l += e2 * bflo(ru[c2]); a2h += e2 * bfhi(ru[c2]);
        a3l += e3 * bflo(ru[c3]); a3h += e3 * bfhi(ru[c3]);
    }
    // canonical den writers: heads 0-3 from group1 (lanes 0,18,36,54), 4-6 from group2 (8,26,44),
    // 7-9 from group3 (0,16,34)
    float* dw = denArr + (size_t)wid * NHEAD;
    if (lane == 0)  { dw[0] = den1; dw[7] = den3; }
    if (lane == 18) dw[1] = den1;
    if (lane == 36) dw[2] = den1;
    if (lane == 54) dw[3] = den1;
    if (lane == 8)  dw[4] = den2;
    if (lane == 26) dw[5] = den2;
    if (lane == 44) dw[6] = den2;
    if (lane == 16) dw[8] = den3;
    if (lane == 34) dw[9] = den3;
    float r1 = 1.f / (den1 + 1e-16f);
    float r2 = 1.f / (den2 + 1e-16f);
    float r3 = 1.f / (den3 + 1e-16f);
    __builtin_nontemporal_store(packbf(a1l * r1, a1h * r1), &zr[lane]);
    __builtin_nontemporal_store(packbf(a2l * r2, a2h * r2), &zr[lane + 64]);
    __builtin_nontemporal_store(g3 ? packbf(a3l * r3, a3h * r3) : 0u, &zr[lane + 128]);
}

// ---------------- alpha in original edge order (bf16-rounded logits match den) ----------------
__global__ __launch_bounds__(256) void k_alpha(const int* __restrict__ ei, const float* __restrict__ a_s,
                                               const float* __restrict__ a_d, const float* __restrict__ den,
                                               float* __restrict__ alphaOut) {
    int i = blockIdx.x * 256 + threadIdx.x;
    if (i >= ETOT * NHEAD) return;
    int e = i / NHEAD, hd = i % NHEAD;
    int s, dst;
    if (e < EE) { s = ei[e]; dst = ei[EE + e]; }
    else { s = dst = e - EE; }
    float zs = bfu(f2bf(a_s[s * NHEAD + hd]));     // same rounding as den accumulation
    float ex = __expf(lrelu(zs + a_d[dst * NHEAD + hd]));
    __builtin_nontemporal_store(ex / (den[dst * NHEAD + hd] + 1e-16f), &alphaOut[i]);
}

// ---------------- GCN aggregate: 2-wave blocks, x8 unroll, bf16 packed output ----------------
__global__ __launch_bounds__(128) void k_gcn_agg(const ushort_t* __restrict__ h2b,
                                                 const int* __restrict__ csr_src,
                                                 const int* __restrict__ offs, const int* __restrict__ deg,
                                                 const float* __restrict__ dinv, const float* __restrict__ b_gcn,
                                                 ushort_t* __restrict__ xg2b) {
    int wid = blockIdx.x * 2 + (threadIdx.x >> 6);
    int lane = threadIdx.x & 63;
    if (wid >= NN) return;
    int o0 = offs[wid], d = deg[wid];
    float wv = dinv[wid];
    bool g3 = lane < 48;                      // third h2 u32 group valid (w = lane+128 < 176)
    int w3 = g3 ? (lane + 128) : 0;
    float aL0 = 0.f, aH0 = 0.f, aL1 = 0.f, aH1 = 0.f, aL2 = 0.f, aH2 = 0.f;
    const unsigned* h32 = (const unsigned*)h2b;
    int i = 0;
    for (; i + 8 <= d; i += 8) {
        int s[8];
        #pragma unroll
        for (int j = 0; j < 8; j++) s[j] = csr_src[o0 + i + j];
        float q[8]; unsigned ua[8], ub[8], uc[8];
        #pragma unroll
        for (int j = 0; j < 8; j++) {
            q[j] = dinv[s[j]];
            const unsigned* hr = h32 + (size_t)s[j] * (LDH2 / 2);
            ua[j] = hr[lane]; ub[j] = hr[lane + 64]; uc[j] = hr[w3];
        }
        #pragma unroll
        for (int j = 0; j < 8; j++) {
            aL0 += q[j] * bflo(ua[j]); aH0 += q[j] * bfhi(ua[j]);
            aL1 += q[j] * bflo(ub[j]); aH1 += q[j] * bfhi(ub[j]);
            aL2 += q[j] * bflo(uc[j]); aH2 += q[j] * bfhi(uc[j]);
        }
    }
    for (; i < d; i++) {
        int s = csr_src[o0 + i];
        float ws = dinv[s];
        const unsigned* hr = h32 + (size_t)s * (LDH2 / 2);
        unsigned u0 = hr[lane], u1 = hr[lane + 64], u2 = hr[w3];
        aL0 += ws * bflo(u0);  aH0 += ws * bfhi(u0);
        aL1 += ws * bflo(u1);  aH1 += ws * bfhi(u1);
        aL2 += ws * bflo(u2);  aH2 += ws * bfhi(u2);
    }
    // packed bf16 output: row = 350 ushorts (175 u32 words); word w covers features 2w,2w+1
    unsigned* orow = (unsigned*)(xg2b + (size_t)wid * FG);
    {
        int f = 2 * lane;
        __builtin_nontemporal_store(packbf(fmaxf(wv * aL0 + b_gcn[f], 0.f),
                                           fmaxf(wv * aH0 + b_gcn[f + 1], 0.f)), &orow[lane]);
    }
    {
        int f = 128 + 2 * lane;
        __builtin_nontemporal_store(packbf(fmaxf(wv * aL1 + b_gcn[f], 0.f),
                                           fmaxf(wv * aH1 + b_gcn[f + 1], 0.f)), &orow[64 + lane]);
    }
    if (lane < 47) {
        int f = 256 + 2 * lane;
        __builtin_nontemporal_store(packbf(fmaxf(wv * aL2 + b_gcn[f], 0.f),
                                           fmaxf(wv * aH2 + b_gcn[f + 1], 0.f)), &orow[128 + lane]);
    }
}

// ---------------- per-graph max+mean pool (bf16 input, u32-word per thread) ----------------
__device__ __forceinline__ int lowerB(const int* a, int n, int key) {
    int lo = 0, hi = n;
    while (lo < hi) { int mid = (lo + hi) >> 1; if (a[mid] < key) lo = mid + 1; else hi = mid; }
    return lo;
}

__global__ __launch_bounds__(256) void k_pool(const ushort_t* __restrict__ xg2b, const int* __restrict__ batch,
                                              float* __restrict__ pooled) {
    int g = blockIdx.x;
    int w = threadIdx.x;
    if (w >= 175) return;
    int s = lowerB(batch, NN, g);
    int e = lowerB(batch, NN, g + 1);
    const unsigned* base = (const unsigned*)xg2b;
    float mx0 = -INFINITY, mx1 = -INFINITY, sm0 = 0.f, sm1 = 0.f;
    int n = s;
    for (; n + 2 <= e; n += 2) {
        unsigned ua = base[(size_t)n * 175 + w];
        unsigned ub = base[(size_t)(n + 1) * 175 + w];
        float a0 = bflo(ua), a1 = bfhi(ua), b0 = bflo(ub), b1 = bfhi(ub);
        mx0 = fmaxf(mx0, fmaxf(a0, b0));
        mx1 = fmaxf(mx1, fmaxf(a1, b1));
        sm0 += a0 + b0;
        sm1 += a1 + b1;
    }
    for (; n < e; n++) {
        unsigned ua = base[(size_t)n * 175 + w];
        float a0 = bflo(ua), a1 = bfhi(ua);
        mx0 = fmaxf(mx0, a0);
        mx1 = fmaxf(mx1, a1);
        sm0 += a0;
        sm1 += a1;
    }
    float rc = 1.f / fmaxf((float)(e - s), 1.f);
    pooled[g * 700 + 2 * w]       = mx0;
    pooled[g * 700 + 2 * w + 1]   = mx1;
    pooled[g * 700 + FG + 2 * w]     = sm0 * rc;
    pooled[g * 700 + FG + 2 * w + 1] = sm1 * rc;
}

// ---------------- protein conv branch: LDS-resident, 2 proteins per block ----------------
__global__ __launch_bounds__(256) void k_conv(const int* __restrict__ target, const float* __restrict__ emb,
                                              const float* __restrict__ Wc, const float* __restrict__ bc,
                                              float* __restrict__ xt) {
    __shared__ float embL[26 * 132];        // rows padded to 132 floats
    __shared__ float WL[16 * 8 * 128];      // WL[f][k][e] = Wc[f][e][k]
    __shared__ int   tgL[2 * LL];
    int tid = threadIdx.x;
    int b0 = blockIdx.x * 2;
    for (int i = tid; i < 26 * 128; i += 256) {
        int r = i >> 7, e = i & 127;
        embL[r * 132 + e] = emb[i];
    }
    for (int i = tid; i < 16384; i += 256) {
        int f = i >> 10, rem = i & 1023, k = rem >> 7, e = rem & 127;
        WL[i] = Wc[f * 1024 + e * 8 + k];
    }
    if (tid < 2 * LL) tgL[tid] = target[b0 * LL + tid];
    __syncthreads();
    #pragma unroll
    for (int pass = 0; pass < 2; pass++) {
        int r = tid + pass * 256;
        if (r >= 280) break;
        int bl = r / 140, rem = r % 140;
        int fq = rem / 35, t = rem % 35;
        const int* tg = &tgL[bl * LL];
        float ac0 = 0.f, ac1 = 0.f, ac2 = 0.f, ac3 = 0.f;
        for (int k = 0; k < 8; k++) {
            const float* er = &embL[tg[t + k] * 132];
            const float* w0 = &WL[((fq * 4 + 0) * 8 + k) * 128];
            const float* w1 = &WL[((fq * 4 + 1) * 8 + k) * 128];
            const float* w2 = &WL[((fq * 4 + 2) * 8 + k) * 128];
            const float* w3 = &WL[((fq * 4 + 3) * 8 + k) * 128];
            #pragma unroll 8
            for (int e = 0; e < 128; e += 4) {
                float4 a = *(const float4*)&er[e];
                float4 q0 = *(const float4*)&w0[e];
                float4 q1 = *(const float4*)&w1[e];
                float4 q2 = *(const float4*)&w2[e];
                float4 q3 = *(const float4*)&w3[e];
                ac0 += a.x * q0.x + a.y * q0.y + a.z * q0.z + a.w * q0.w;
                ac1 += a.x * q1.x + a.y * q1.y + a.z * q1.z + a.w * q1.w;
                ac2 += a.x * q2.x + a.y * q2.y + a.z * q2.z + a.w * q2.w;
                ac3 += a.x * q3.x + a.y * q3.y + a.z * q3.z + a.w * q3.w;
            }
        }
        int b = b0 + bl, fb = fq * 4;
        xt[b * 560 + (fb + 0) * 35 + t] = ac0 + bc[fb + 0];
        xt[b * 560 + (fb + 1) * 35 + t] = ac1 + bc[fb + 1];
        xt[b * 560 + (fb + 2) * 35 + t] = ac2 + bc[fb + 2];
        xt[b * 560 + (fb + 3) * 35 + t] = ac3 + bc[fb + 3];
    }
}

// ---------------- final dot + sigmoid ----------------
__global__ __launch_bounds__(256) void k_out(const float* __restrict__ f1, const float* __restrict__ W_out,
                                             const float* __restrict__ b_out, float* __restrict__ out) {
    int wid = (blockIdx.x * blockDim.x + threadIdx.x) >> 6;
    int lane = threadIdx.x & 63;
    if (wid >= BB) return;
    const float* xr = f1 + (size_t)wid * 512;
    float acc = 0.f;
    #pragma unroll
    for (int k = 0; k < 8; k++) acc += xr[lane + k * 64] * W_out[lane + k * 64];
    #pragma unroll
    for (int d = 32; d; d >>= 1) acc += __shfl_xor(acc, d);
    if (lane == 0) out[wid] = 1.f / (1.f + __expf(-(acc + b_out[0])));
}

// ---------------- host launcher ----------------
extern "C" void kernel_launch(void* const* d_in, const int* in_sizes, int n_in,
                              void* d_out, int out_size, void* d_ws, size_t ws_size,
                              hipStream_t stream) {
    const float* x      = (const float*)d_in[0];
    const int*   ei     = (const int*)d_in[1];
    const int*   batch  = (const int*)d_in[2];
    const int*   target = (const int*)d_in[3];
    const float* W_gat  = (const float*)d_in[4];
    const float* att_s  = (const float*)d_in[5];
    const float* att_d  = (const float*)d_in[6];
    const float* b_gat  = (const float*)d_in[7];
    const float* W_gcn  = (const float*)d_in[8];
    const float* b_gcn  = (const float*)d_in[9];
    const float* W_fcg1 = (const float*)d_in[10];
    const float* b_fcg1 = (const float*)d_in[11];
    const float* W_fcg2 = (const float*)d_in[12];
    const float* b_fcg2 = (const float*)d_in[13];
    const float* embxt  = (const float*)d_in[14];
    const float* W_conv = (const float*)d_in[15];
    const float* b_conv = (const float*)d_in[16];
    const float* W_fcxt = (const float*)d_in[17];
    const float* b_fcxt = (const float*)d_in[18];
    const float* W_fc1  = (const float*)d_in[19];
    const float* b_fc1  = (const float*)d_in[20];
    const float* W_out  = (const float*)d_in[21];
    const float* b_out  = (const float*)d_in[22];

    float* out_sig  = (float*)d_out;          // [500]
    float* alphaOut = (float*)d_out + BB;     // [850000 * 10]

    size_t o = 0;
    auto alloc = [&](size_t bytes) -> void* {
        o = (o + 255) & ~(size_t)255;
        void* p = (char*)d_ws + o;
        o += bytes;
        return p;
    };
    int*   deg     = (int*)alloc((size_t)NN * 4);
    int*   cur     = (int*)alloc((size_t)NN * 4);
    int*   offs    = (int*)alloc((size_t)NN * 4);
    int*   part    = (int*)alloc(128 * 4);
    int*   pscan   = (int*)alloc(128 * 4);
    int*   csr_src = (int*)alloc((size_t)ETOT * 4);
    float* dinv    = (float*)alloc((size_t)NN * 4);
    float* a_s     = (float*)alloc((size_t)NN * NHEAD * 4);
    float* a_d     = (float*)alloc((size_t)NN * NHEAD * 4);
    float* denArr  = (float*)alloc((size_t)NN * NHEAD * 4);
    ushort_t* nd   = (ushort_t*)alloc((size_t)NN * 48 * 2);       // merged node rows (4.8 MB)
    float* wS      = (float*)alloc((size_t)FG * 4);
    float* wD      = (float*)alloc((size_t)FG * 4);
    ushort_t* WtBD = (ushort_t*)alloc((size_t)KPAD * KPAD * 2);   // block-diag W_gat^T (stride-36 K)
    ushort_t* WtGC = (ushort_t*)alloc((size_t)KPAD * KPAD * 2);
    ushort_t* WtF1 = (ushort_t*)alloc((size_t)1536 * 704 * 2);
    ushort_t* WtF2 = (ushort_t*)alloc((size_t)128 * 1536 * 2);
    ushort_t* WtFX = (ushort_t*)alloc((size_t)128 * 576 * 2);
    ushort_t* WtFC = (ushort_t*)alloc((size_t)512 * 256 * 2);
    float* pooled  = (float*)alloc((size_t)BB * 700 * 4);
    ushort_t* pooledb = (ushort_t*)alloc((size_t)MB2 * 704 * 2);
    ushort_t* t1b  = (ushort_t*)alloc((size_t)MB2 * 1536 * 2);
    float* xt      = (float*)alloc((size_t)BB * 560 * 4);
    ushort_t* xtb  = (ushort_t*)alloc((size_t)MB2 * 576 * 2);
    ushort_t* xcb  = (ushort_t*)alloc((size_t)MB2 * 256 * 2);
    float* f1      = (float*)alloc((size_t)MB2 * 512 * 4);
    ushort_t* hb   = (ushort_t*)alloc((size_t)MPAD * KPAD * 2);   // Z (GAT agg), later h2 (ld 352)
    char*  R2      = (char*)alloc((size_t)NN * FG * 4);           // aliased region
    ushort_t* xg1b = (ushort_t*)R2;                               // [MPAD][KPAD] bf16 (38.4 MB)
    ushort_t* xg2b = (ushort_t*)R2;                               // [NN][350] bf16, after xg1b dead
    (void)ws_size; (void)n_in; (void)in_sizes; (void)out_size;

    auto mfma = [&](const ushort_t* A, const ushort_t* Bt, void* C, const float* bias,
                    int M2, int Nv, int NP, int ldc, int KP, int act, int bf16out, int bdiag, int nst) {
        dim3 g(NP / 64, M2 / 128);
        k_mfma<<<g, 256, 0, stream>>>(A, Bt, C, M2, Nv, ldc, KP, KP / 64, bias, act, bf16out, bdiag, nst);
    };

    // graph prep
    k_init<<<(NN + 255) / 256, 256, 0, stream>>>(deg, cur);
    k_deg<<<(EE + 255) / 256, 256, 0, stream>>>(ei, deg);
    k_scan1<<<NCHUNK, 512, 0, stream>>>(deg, part);
    k_scan2<<<1, 64, 0, stream>>>(part, pscan);
    k_scan3<<<NCHUNK, 512, 0, stream>>>(deg, pscan, offs, dinv);
    k_scatter<<<(ETOT + 255) / 256, 256, 0, stream>>>(ei, offs, cur, csr_src);

    // prep (fused attention weights -> merged node rows; all weights in one kernel)
    k_prep_att<<<2, 256, 0, stream>>>(W_gat, att_s, att_d, wS, wD);
    k_prep_node<<<(NN + 255) / 256, 256, 0, stream>>>(x, wS, wD, nd, a_s, a_d);
    k_prep_weights<<<(PREPW_TOTAL + 255) / 256, 256, 0, stream>>>(W_gat, W_gcn, W_fcg1, W_fcg2,
                                                                  W_fcxt, W_fc1,
                                                                  WtBD, WtGC, WtF1, WtF2, WtFX, WtFC);

    // GAT: aggregate x (stride-36 Z, tail zeroed in-kernel) -> alpha -> block-diag GEMM
    k_gat_agg<<<MPAD / 2, 128, 0, stream>>>(nd, a_d, csr_src, offs, deg, hb, denArr);   // Z -> hb
    k_alpha<<<(ETOT * NHEAD + 255) / 256, 256, 0, stream>>>(ei, a_s, a_d, denArr, alphaOut);
    mfma(hb, WtBD, xg1b, b_gat, MPAD, FG, KPAD, KPAD, KPAD, 1, 1, 1, KPAD);  // xg1 = relu(Z@W_bd+b)

    // GCN: h2 = xg1 @ W_gcn (overwrites hb, row stride 352), then aggregate (bf16 out)
    mfma(xg1b, WtGC, hb, nullptr, MPAD, FG, KPAD, LDH2, KPAD, 0, 1, 0, LDH2);
    k_gcn_agg<<<(NN + 1) / 2, 128, 0, stream>>>(hb, csr_src, offs, deg, dinv, b_gcn, xg2b);

    // pool + FC stacks (all FC layers via bf16 MFMA)
    k_pool<<<BB, 256, 0, stream>>>(xg2b, batch, pooled);
    k_cast_pad<<<(MB2 * 704 + 255) / 256, 256, 0, stream>>>(pooled, pooledb, BB, 700, MB2, 704);
    mfma(pooledb, WtF1, t1b, b_fcg1, MB2, 1500, 1536, 1536, 704, 1, 1, 0, 1536);
    mfma(t1b, WtF2, xcb, b_fcg2, MB2, 128, 128, 256, 1536, 0, 1, 0, 128);
    k_conv<<<250, 256, 0, stream>>>(target, embxt, W_conv, b_conv, xt);
    k_cast_pad<<<(MB2 * 576 + 255) / 256, 256, 0, stream>>>(xt, xtb, BB, 560, MB2, 576);
    mfma(xtb, WtFX, xcb + 128, b_fcxt, MB2, 128, 128, 256, 576, 0, 1, 0, 128);
    mfma(xcb, WtFC, f1, b_fc1, MB2, 512, 512, 512, 256, 1, 0, 0, 512);
    k_out<<<(BB + 3) / 4, 256, 0, stream>>>(f1, W_out, b_out, out_sig);
}